// Round 5
// baseline (363.047 us; speedup 1.0000x reference)
//
#include <hip/hip_runtime.h>
#include <hip/hip_bf16.h>
#include <math.h>

#define CIN 96
#define D2 192
#define D4 768
#define LL 9216
#define NN 16
#define NCH 192      /* chunks per direction */
#define CLEN 48      /* steps per chunk */

typedef float v2f __attribute__((ext_vector_type(2)));

// ---- workspace layout (float-slot offsets) ----
#define SZ_Y4SLOT (2u*2u*9216u*192u)     //  7,077,888 float slots (bf16 x2)
#define SZ_BL    (2u*9216u*192u)         //  3,538,944
#define SZ_XDBL  (2u*9216u*38u)          //    700,416
#define SZ_S     (2u*4u*192u*192u)       //    294,912
#define SZ_H     (2u*4u*192u*192u*16u)   //  4,718,592
#define F_Y4     0u
#define F_XX     0u                       /* alias: xx dead before y4 written */
#define F_ZS     (F_Y4 + SZ_Y4SLOT)
#define F_XT     (F_ZS + SZ_BL)
#define F_XDBLA  (F_XT + SZ_BL)
#define F_XDBLB  (F_XDBLA + SZ_XDBL)
#define F_SBUF   (F_XDBLB + SZ_XDBL)
#define F_HBUF   (F_SBUF + SZ_S)
#define F_WSUM   (F_HBUF + SZ_H)         /* 2 x 8192 slots (7296 used each) */

__device__ __forceinline__ float silu_f(float z) {
    return z / (1.0f + __expf(-z));
}

// pairs p[k] = {e1^(2k+1), e1^(2k+2)}, depth <= 4
__device__ __forceinline__ void pow_pairs(float e1, v2f p[8]) {
    float e2 = e1 * e1;
    v2f p01; p01.x = e1; p01.y = e2;
    v2f e2v; e2v.x = e2; e2v.y = e2;
    v2f e4v = e2v * e2v;
    v2f e8v = e4v * e4v;
    p[0] = p01;
    p[1] = p01 * e2v;
    p[2] = p01 * e4v;
    p[3] = p[1] * e4v;
    p[4] = p01 * e8v;
    p[5] = p[1] * e8v;
    p[6] = p[2] * e8v;
    p[7] = p[3] * e8v;
}

// K0: fold Wx over the duplicated channel halves: wsa = Wx[0:192]+Wx[192:384], wsb = Wx[384:576]+Wx[576:768]
__global__ __launch_bounds__(256) void k0_foldw(
    const float* __restrict__ Wx, float* __restrict__ wsa, float* __restrict__ wsb)
{
    int i = blockIdx.x * 256 + threadIdx.x;
    if (i >= 192 * 38) return;
    int d = i / 38, j = i % 38;
    wsa[i] = Wx[d * 38 + j] + Wx[(d + 192) * 38 + j];
    wsb[i] = Wx[(d + 384) * 38 + j] + Wx[(d + 576) * 38 + j];
}

// K1: xz = x @ W_in + b_in; first half -> xx (b,192,L), silu(second half) -> zs (b,L,192)
__global__ __launch_bounds__(256) void k1_inproj(
    const float* __restrict__ x, const float* __restrict__ Win,
    const float* __restrict__ bin, float* __restrict__ xx, float* __restrict__ zs)
{
    __shared__ float xs[96][68];
    __shared__ float wsm[96][68];
    int tid = threadIdx.x;
    int gl0 = blockIdx.x * 64;
    int b = gl0 / LL;
    int l0 = gl0 % LL;

    for (int i = tid; i < 96 * 64; i += 256) {
        int k = i >> 6, li = i & 63;
        xs[k][li] = x[(size_t)(b * 96 + k) * LL + l0 + li];
    }
    int lg = tid >> 4;
    int eg = tid & 15;
    for (int ech = 0; ech < 384; ech += 64) {
        __syncthreads();
        for (int i = tid; i < 96 * 64; i += 256) {
            int k = i >> 6, e = i & 63;
            wsm[k][e] = Win[k * 384 + ech + e];
        }
        __syncthreads();
        v2f acc2[4][2];
#pragma unroll
        for (int i = 0; i < 4; i++)
#pragma unroll
            for (int p = 0; p < 2; p++) { acc2[i][p].x = 0.f; acc2[i][p].y = 0.f; }
        for (int k = 0; k < 96; k++) {
            float4 xv = *(const float4*)&xs[k][lg * 4];
            float4 wv = *(const float4*)&wsm[k][eg * 4];
            v2f w0; w0.x = wv.x; w0.y = wv.y;
            v2f w1; w1.x = wv.z; w1.y = wv.w;
            float xa[4] = {xv.x, xv.y, xv.z, xv.w};
#pragma unroll
            for (int i = 0; i < 4; i++) {
                v2f xsp; xsp.x = xa[i]; xsp.y = xa[i];
                acc2[i][0] += xsp * w0;
                acc2[i][1] += xsp * w1;
            }
        }
        int e0 = ech + eg * 4;
        if (e0 < 192) {
#pragma unroll
            for (int j = 0; j < 4; j++) {
                int e = e0 + j;
                float bb = bin[e];
                float4 v = {acc2[0][j >> 1][j & 1] + bb, acc2[1][j >> 1][j & 1] + bb,
                            acc2[2][j >> 1][j & 1] + bb, acc2[3][j >> 1][j & 1] + bb};
                *(float4*)&xx[(size_t)(b * 192 + e) * LL + l0 + lg * 4] = v;
            }
        } else {
#pragma unroll
            for (int i = 0; i < 4; i++) {
                int l = l0 + lg * 4 + i;
                float4 v;
                v.x = silu_f(acc2[i][0][0] + bin[e0 + 0]);
                v.y = silu_f(acc2[i][0][1] + bin[e0 + 1]);
                v.z = silu_f(acc2[i][1][0] + bin[e0 + 2]);
                v.w = silu_f(acc2[i][1][1] + bin[e0 + 3]);
                *(float4*)&zs[((size_t)b * LL + l) * 192 + (e0 - 192)] = v;
            }
        }
    }
}

// K2: depthwise 3x3 conv + bias + silu, fused transpose: xx (b,192,96,96) -> xt (b,L,192)
__global__ __launch_bounds__(192) void k2_conv(
    const float* __restrict__ xx, const float* __restrict__ wdw,
    const float* __restrict__ bdw, float* __restrict__ xt)
{
    __shared__ float tile[32][97];
    __shared__ float wsm[32][9];
    __shared__ float bs[32];
    int tid = threadIdx.x;
    int bid = blockIdx.x;
    int h = bid % 96;
    int r = bid / 96;
    int dg = r % 6;
    int b = r / 6;

    for (int i = tid; i < 288; i += 192) wsm[i / 9][i % 9] = wdw[(dg * 32 + i / 9) * 9 + (i % 9)];
    if (tid < 32) bs[tid] = bdw[dg * 32 + tid];
    __syncthreads();

    int w = tid % 96;
    int dhalf = tid / 96;
    for (int p = 0; p < 16; p++) {
        int dsub = 2 * p + dhalf;
        const float* base = xx + (size_t)(b * 192 + dg * 32 + dsub) * LL;
        float acc = bs[dsub];
#pragma unroll
        for (int kh = 0; kh < 3; kh++) {
            int hh = h + kh - 1;
            if (hh < 0 || hh >= 96) continue;
            const float* row = base + hh * 96;
#pragma unroll
            for (int kw = 0; kw < 3; kw++) {
                int ww = w + kw - 1;
                if (ww < 0 || ww >= 96) continue;
                acc += row[ww] * wsm[dsub][kh * 3 + kw];
            }
        }
        tile[dsub][w] = silu_f(acc);
    }
    __syncthreads();
    for (int i = tid; i < 768; i += 192) {
        int q = i & 7, ls = i >> 3;
        float4 v = {tile[q * 4 + 0][ls], tile[q * 4 + 1][ls], tile[q * 4 + 2][ls], tile[q * 4 + 3][ls]};
        *(float4*)&xt[((size_t)b * LL + h * 96 + ls) * 192 + dg * 32 + q * 4] = v;
    }
}

// K3: one 16-row xt tile per block. Computes fwd part (tile rows -> xdbl_a[same rows])
// and rev part (tile rows -> xdbl_b[mirror rows]) so xt is read exactly once.
__global__ __launch_bounds__(256) void k3_xdbl(
    const float* __restrict__ xt, const float* __restrict__ wsa,
    const float* __restrict__ wsb, float* __restrict__ xa, float* __restrict__ xb)
{
    __shared__ float xs[16][194];
    int tid = threadIdx.x;
    int b = blockIdx.x / 576;
    int p0 = (blockIdx.x % 576) * 16;
    for (int i = tid; i < 16 * 192; i += 256) {
        int li = i / 192, d = i - li * 192;
        xs[li][d] = xt[((size_t)b * LL + p0 + li) * 192 + d];
    }
    __syncthreads();
    int lig = tid >> 4, jg = tid & 15;
    int j0 = jg * 3;
    float a0 = 0.f, a1 = 0.f, a2 = 0.f;
    float b0 = 0.f, b1 = 0.f, b2 = 0.f;
    const float* xr = &xs[lig][0];
    const float* wap = wsa + j0;
    const float* wbp = wsb + j0;
    for (int d = 0; d < 192; d++) {
        float xv = xr[d];
        a0 += xv * wap[0]; a1 += xv * wap[1]; a2 += xv * wap[2];
        b0 += xv * wbp[0]; b1 += xv * wbp[1]; b2 += xv * wbp[2];
        wap += 38; wbp += 38;
    }
    int la = p0 + lig;
    int lb = LL - 1 - la;
    size_t ra = ((size_t)b * LL + la) * 38 + j0;
    size_t rb = ((size_t)b * LL + lb) * 38 + j0;
    float av[3] = {a0, a1, a2};
    float bv[3] = {b0, b1, b2};
#pragma unroll
    for (int jj = 0; jj < 3; jj++) {
        if (j0 + jj < 38) {
            xa[ra + jj] = av[jj];
            xb[rb + jj] = bv[jj];
        }
    }
}

// K4 pass1: per-chunk local scan, SINGLE direction per block, h from 0. v2f core.
__global__ __launch_bounds__(192, 4) void k4_pass1(
    const float* __restrict__ xt, const float* __restrict__ xa,
    const float* __restrict__ xb, const float* __restrict__ Wd,
    const float* __restrict__ bdl, const float* __restrict__ Alog,
    float* __restrict__ Sbuf, float* __restrict__ Hbuf)
{
    __shared__ float Bt[CLEN][16];
    __shared__ float Dt[CLEN][6];
    int tid = threadIdx.x;
    int bid = blockIdx.x;
    int k = bid % NCH;
    int r = bid / NCH;
    int dir = r & 3;
    int b = r >> 2;
    int l0 = k * CLEN;
    for (int i = tid; i < CLEN * 16; i += 192) {
        int t = i >> 4, n = i & 15;
        size_t rb = ((size_t)b * LL + l0 + t) * 38 + 6 + n;
        Bt[t][n] = xa[rb] + xb[rb];
    }
    for (int i = tid; i < CLEN * 6; i += 192) {
        int t = i / 6, rr = i - 6 * t;
        size_t rb = ((size_t)b * LL + l0 + t) * 38 + rr;
        Dt[t][rr] = xa[rb] + xb[rb];
    }
    __syncthreads();
    int c = tid;
    int d4 = dir * 192 + c;
    float a0 = -__expf(Alog[d4 * 16]);
    bool fast = true;
    for (int n = 1; n < 16; n++) {
        float an = -__expf(Alog[d4 * 16 + n]);
        float tgt = (n + 1) * a0;
        fast = fast && (fabsf(an - tgt) <= 1e-5f * fabsf(tgt));
    }
    float wd[6];
#pragma unroll
    for (int rr = 0; rr < 6; rr++) wd[rr] = Wd[rr * 768 + d4];
    float bde = bdl[d4];
    float S = 0.f;
    const float* xtp = xt + (size_t)b * LL * 192 + c;
    int bd = b * 4 + dir;
    size_t base = (((size_t)bd * NCH + k) * 192 + c) * 16;
    if (fast) {
        v2f h2[8];
#pragma unroll
        for (int n = 0; n < 8; n++) { h2[n].x = 0.f; h2[n].y = 0.f; }
        for (int t = 0; t < CLEN; t++) {
            float s = bde;
#pragma unroll
            for (int rr = 0; rr < 6; rr++) s += Dt[t][rr] * wd[rr];
            float dt = (s > 20.f) ? s : __logf(1.f + __expf(s));
            S += dt;
            int lp = (dir < 2) ? (l0 + t) : (LL - 1 - (l0 + t));
            float u = xtp[(size_t)lp * 192];
            float du = dt * u;
            float4 q0 = *(const float4*)&Bt[t][0];
            float4 q1 = *(const float4*)&Bt[t][4];
            float4 q2 = *(const float4*)&Bt[t][8];
            float4 q3 = *(const float4*)&Bt[t][12];
            v2f B2[8];
            B2[0].x = q0.x; B2[0].y = q0.y; B2[1].x = q0.z; B2[1].y = q0.w;
            B2[2].x = q1.x; B2[2].y = q1.y; B2[3].x = q1.z; B2[3].y = q1.w;
            B2[4].x = q2.x; B2[4].y = q2.y; B2[5].x = q2.z; B2[5].y = q2.w;
            B2[6].x = q3.x; B2[6].y = q3.y; B2[7].x = q3.z; B2[7].y = q3.w;
            v2f p2[8];
            pow_pairs(__expf(dt * a0), p2);
            v2f du2; du2.x = du; du2.y = du;
#pragma unroll
            for (int n = 0; n < 8; n++) h2[n] = p2[n] * h2[n] + du2 * B2[n];
        }
        v2f* hb = (v2f*)&Hbuf[base];
#pragma unroll
        for (int n = 0; n < 8; n++) hb[n] = h2[n];
    } else {
        float h[16];
#pragma unroll
        for (int n = 0; n < 16; n++) h[n] = 0.f;
        for (int t = 0; t < CLEN; t++) {
            float s = bde;
#pragma unroll
            for (int rr = 0; rr < 6; rr++) s += Dt[t][rr] * wd[rr];
            float dt = (s > 20.f) ? s : __logf(1.f + __expf(s));
            S += dt;
            int lp = (dir < 2) ? (l0 + t) : (LL - 1 - (l0 + t));
            float u = xtp[(size_t)lp * 192];
            float du = dt * u;
#pragma unroll
            for (int n = 0; n < 16; n++) {
                float e = __expf(dt * (-__expf(Alog[d4 * 16 + n])));
                h[n] = e * h[n] + du * Bt[t][n];
            }
        }
#pragma unroll
        for (int n = 0; n < 16; n++) Hbuf[base + n] = h[n];
    }
    Sbuf[((size_t)bd * NCH + k) * 192 + c] = S;
}

// K4 pass2: scan over chunk summaries; Hbuf[k] := h_start; P = exp(a*S) on the fly
__global__ __launch_bounds__(256) void k4_pass2(
    const float* __restrict__ Sbuf, const float* __restrict__ Alog,
    float* __restrict__ Hbuf)
{
    int lane = blockIdx.x * 256 + threadIdx.x;  // 24576
    int bd = lane / 3072;
    int cn = lane % 3072;
    int c = cn >> 4, n = cn & 15;
    int dir = bd & 3;
    float an = -__expf(Alog[(dir * 192 + c) * 16 + n]);
    float h = 0.f;
#pragma unroll 8
    for (int k = 0; k < NCH; k++) {
        size_t sidx = ((size_t)bd * NCH + k) * 192 + c;
        float S = Sbuf[sidx];
        size_t idx = sidx * 16 + n;
        float hl = Hbuf[idx];
        float P = __expf(an * S);
        Hbuf[idx] = h;
        h = P * h + hl;
    }
}

// K4 pass3: replay chunk from h_start, SINGLE direction per block; y -> bf16 slab. v2f core.
__global__ __launch_bounds__(192, 4) void k4_pass3(
    const float* __restrict__ xt, const float* __restrict__ xa,
    const float* __restrict__ xb, const float* __restrict__ Wd,
    const float* __restrict__ bdl, const float* __restrict__ Alog,
    const float* __restrict__ Dp, const float* __restrict__ Hbuf,
    __hip_bfloat16* __restrict__ y4)
{
    __shared__ float Bt[CLEN][16];
    __shared__ float Ct[CLEN][16];
    __shared__ float Dt[CLEN][6];
    int tid = threadIdx.x;
    int bid = blockIdx.x;
    int k = bid % NCH;
    int r = bid / NCH;
    int dir = r & 3;
    int b = r >> 2;
    int l0 = k * CLEN;
    for (int i = tid; i < CLEN * 16; i += 192) {
        int t = i >> 4, n = i & 15;
        size_t rb = ((size_t)b * LL + l0 + t) * 38;
        Bt[t][n] = xa[rb + 6 + n] + xb[rb + 6 + n];
        Ct[t][n] = xa[rb + 22 + n] + xb[rb + 22 + n];
    }
    for (int i = tid; i < CLEN * 6; i += 192) {
        int t = i / 6, rr = i - 6 * t;
        size_t rb = ((size_t)b * LL + l0 + t) * 38 + rr;
        Dt[t][rr] = xa[rb] + xb[rb];
    }
    __syncthreads();
    int c = tid;
    int d4 = dir * 192 + c;
    float a0 = -__expf(Alog[d4 * 16]);
    bool fast = true;
    for (int n = 1; n < 16; n++) {
        float an = -__expf(Alog[d4 * 16 + n]);
        float tgt = (n + 1) * a0;
        fast = fast && (fabsf(an - tgt) <= 1e-5f * fabsf(tgt));
    }
    float wd[6];
#pragma unroll
    for (int rr = 0; rr < 6; rr++) wd[rr] = Wd[rr * 768 + d4];
    float bde = bdl[d4];
    float Dv = Dp[d4];
    int bd = b * 4 + dir;
    size_t base = (((size_t)bd * NCH + k) * 192 + c) * 16;
    const float* xtp = xt + (size_t)b * LL * 192 + c;
    __hip_bfloat16* yp = y4 + (size_t)bd * LL * 192 + c;
    if (fast) {
        v2f h2[8];
        const v2f* hb = (const v2f*)&Hbuf[base];
#pragma unroll
        for (int n = 0; n < 8; n++) h2[n] = hb[n];
        for (int t = 0; t < CLEN; t++) {
            float s = bde;
#pragma unroll
            for (int rr = 0; rr < 6; rr++) s += Dt[t][rr] * wd[rr];
            float dt = (s > 20.f) ? s : __logf(1.f + __expf(s));
            int lp = (dir < 2) ? (l0 + t) : (LL - 1 - (l0 + t));
            float u = xtp[(size_t)lp * 192];
            float du = dt * u;
            float4 q0 = *(const float4*)&Bt[t][0];
            float4 q1 = *(const float4*)&Bt[t][4];
            float4 q2 = *(const float4*)&Bt[t][8];
            float4 q3 = *(const float4*)&Bt[t][12];
            v2f B2[8];
            B2[0].x = q0.x; B2[0].y = q0.y; B2[1].x = q0.z; B2[1].y = q0.w;
            B2[2].x = q1.x; B2[2].y = q1.y; B2[3].x = q1.z; B2[3].y = q1.w;
            B2[4].x = q2.x; B2[4].y = q2.y; B2[5].x = q2.z; B2[5].y = q2.w;
            B2[6].x = q3.x; B2[6].y = q3.y; B2[7].x = q3.z; B2[7].y = q3.w;
            float4 r0 = *(const float4*)&Ct[t][0];
            float4 r1 = *(const float4*)&Ct[t][4];
            float4 r2 = *(const float4*)&Ct[t][8];
            float4 r3 = *(const float4*)&Ct[t][12];
            v2f C2[8];
            C2[0].x = r0.x; C2[0].y = r0.y; C2[1].x = r0.z; C2[1].y = r0.w;
            C2[2].x = r1.x; C2[2].y = r1.y; C2[3].x = r1.z; C2[3].y = r1.w;
            C2[4].x = r2.x; C2[4].y = r2.y; C2[5].x = r2.z; C2[5].y = r2.w;
            C2[6].x = r3.x; C2[6].y = r3.y; C2[7].x = r3.z; C2[7].y = r3.w;
            v2f p2[8];
            pow_pairs(__expf(dt * a0), p2);
            v2f du2; du2.x = du; du2.y = du;
            v2f ya; ya.x = 0.f; ya.y = 0.f;
            v2f yb; yb.x = 0.f; yb.y = 0.f;
#pragma unroll
            for (int n = 0; n < 8; n += 2) {
                h2[n] = p2[n] * h2[n] + du2 * B2[n];
                ya += h2[n] * C2[n];
                h2[n + 1] = p2[n + 1] * h2[n + 1] + du2 * B2[n + 1];
                yb += h2[n + 1] * C2[n + 1];
            }
            float yv = (ya.x + ya.y) + (yb.x + yb.y) + Dv * u;
            yp[(size_t)lp * 192] = __float2bfloat16(yv);
        }
    } else {
        float h[16];
#pragma unroll
        for (int n = 0; n < 16; n++) h[n] = Hbuf[base + n];
        for (int t = 0; t < CLEN; t++) {
            float s = bde;
#pragma unroll
            for (int rr = 0; rr < 6; rr++) s += Dt[t][rr] * wd[rr];
            float dt = (s > 20.f) ? s : __logf(1.f + __expf(s));
            int lp = (dir < 2) ? (l0 + t) : (LL - 1 - (l0 + t));
            float u = xtp[(size_t)lp * 192];
            float du = dt * u;
            float yv = Dv * u;
#pragma unroll
            for (int n = 0; n < 16; n++) {
                float e = __expf(dt * (-__expf(Alog[d4 * 16 + n])));
                h[n] = e * h[n] + du * Bt[t][n];
                yv += h[n] * Ct[t][n];
            }
            yp[(size_t)lp * 192] = __float2bfloat16(yv);
        }
    }
}

// K5: yh = sum of 4 bf16 slabs; LayerNorm(192); * silu(z); @ W_out -> out (b,96,H,W)
__global__ __launch_bounds__(256) void k5_out(
    const __hip_bfloat16* __restrict__ y4, const float* __restrict__ zs,
    const float* __restrict__ lng, const float* __restrict__ lnb,
    const float* __restrict__ Wout, float* __restrict__ out)
{
    __shared__ float acts[64][194];
    __shared__ float wsh[32][100];
    int tid = threadIdx.x;
    int wv = tid >> 6;
    int lane = tid & 63;
    int gl0 = blockIdx.x * 64;
    int b = gl0 / LL;
    int l0 = gl0 % LL;
    const size_t ds = (size_t)LL * 192;

    for (int i = 0; i < 16; i++) {
        int rrow = wv * 16 + i;
        int l = l0 + rrow;
        float yv[3], zv[3];
        float s1 = 0.f, s2 = 0.f;
#pragma unroll
        for (int kk = 0; kk < 3; kk++) {
            int c = lane + kk * 64;
            size_t off = ((size_t)(b * 4) * LL + l) * 192 + c;
            float y = __bfloat162float(y4[off]) + __bfloat162float(y4[off + ds])
                    + __bfloat162float(y4[off + 2 * ds]) + __bfloat162float(y4[off + 3 * ds]);
            yv[kk] = y;
            zv[kk] = zs[((size_t)b * LL + l) * 192 + c];
            s1 += y; s2 += y * y;
        }
#pragma unroll
        for (int o = 32; o; o >>= 1) {
            s1 += __shfl_xor(s1, o, 64);
            s2 += __shfl_xor(s2, o, 64);
        }
        float mean = s1 * (1.f / 192.f);
        float var = s2 * (1.f / 192.f) - mean * mean;
        float rs = rsqrtf(var + 1e-5f);
#pragma unroll
        for (int kk = 0; kk < 3; kk++) {
            int c = lane + kk * 64;
            float yn = (yv[kk] - mean) * rs * lng[c] + lnb[c];
            acts[rrow][c] = yn * zv[kk];
        }
    }

    int ty = tid >> 4;
    int tx = tid & 15;
    v2f o2[4][3];
#pragma unroll
    for (int i = 0; i < 4; i++)
#pragma unroll
        for (int p = 0; p < 3; p++) { o2[i][p].x = 0.f; o2[i][p].y = 0.f; }

    for (int kc = 0; kc < 192; kc += 32) {
        __syncthreads();
        for (int i = tid; i < 3072; i += 256)
            wsh[i / 96][i % 96] = Wout[(kc + i / 96) * 96 + i % 96];
        __syncthreads();
        for (int kk = 0; kk < 32; kk++) {
            float av[4];
#pragma unroll
            for (int i = 0; i < 4; i++) av[i] = acts[ty * 4 + i][kc + kk];
            const v2f* wp = (const v2f*)&wsh[kk][tx * 6];
            v2f w0 = wp[0], w1 = wp[1], w2 = wp[2];
#pragma unroll
            for (int i = 0; i < 4; i++) {
                v2f sp; sp.x = av[i]; sp.y = av[i];
                o2[i][0] += sp * w0;
                o2[i][1] += sp * w1;
                o2[i][2] += sp * w2;
            }
        }
    }
#pragma unroll
    for (int i = 0; i < 4; i++) {
        int l = l0 + ty * 4 + i;
#pragma unroll
        for (int j = 0; j < 6; j++) {
            int n = tx * 6 + j;
            out[((size_t)(b * 96) + n) * LL + l] = o2[i][j >> 1][j & 1];
        }
    }
}

extern "C" void kernel_launch(void* const* d_in, const int* in_sizes, int n_in,
                              void* d_out, int out_size, void* d_ws, size_t ws_size,
                              hipStream_t stream)
{
    const float* x    = (const float*)d_in[0];
    const float* Win  = (const float*)d_in[1];
    const float* bin  = (const float*)d_in[2];
    const float* wdw  = (const float*)d_in[3];
    const float* bdw  = (const float*)d_in[4];
    const float* Alog = (const float*)d_in[5];
    const float* Dp   = (const float*)d_in[6];
    const float* Wx   = (const float*)d_in[7];
    const float* Wd   = (const float*)d_in[8];
    const float* bdl  = (const float*)d_in[9];
    const float* lng  = (const float*)d_in[10];
    const float* lnb  = (const float*)d_in[11];
    const float* Wout = (const float*)d_in[12];
    float* out = (float*)d_out;

    float* ws    = (float*)d_ws;
    __hip_bfloat16* y4 = (__hip_bfloat16*)(ws + F_Y4);
    float* xx    = ws + F_XX;    // aliases y4 slab region (dead before y4 written)
    float* zs    = ws + F_ZS;
    float* xt    = ws + F_XT;
    float* xda   = ws + F_XDBLA;
    float* xdb   = ws + F_XDBLB;
    float* Sbuf  = ws + F_SBUF;
    float* Hbuf  = ws + F_HBUF;
    float* wsa   = ws + F_WSUM;
    float* wsb   = ws + F_WSUM + 8192;

    k0_foldw<<<29, 256, 0, stream>>>(Wx, wsa, wsb);
    k1_inproj<<<288, 256, 0, stream>>>(x, Win, bin, xx, zs);
    k2_conv<<<1152, 192, 0, stream>>>(xx, wdw, bdw, xt);
    k3_xdbl<<<1152, 256, 0, stream>>>(xt, wsa, wsb, xda, xdb);
    k4_pass1<<<1536, 192, 0, stream>>>(xt, xda, xdb, Wd, bdl, Alog, Sbuf, Hbuf);
    k4_pass2<<<96, 256, 0, stream>>>(Sbuf, Alog, Hbuf);
    k4_pass3<<<1536, 192, 0, stream>>>(xt, xda, xdb, Wd, bdl, Alog, Dp, Hbuf, y4);
    k5_out<<<288, 256, 0, stream>>>(y4, zs, lng, lnb, Wout, out);
}

// Round 6
// 322.543 us; speedup vs baseline: 1.1256x; 1.1256x over previous
//
#include <hip/hip_runtime.h>
#include <hip/hip_bf16.h>
#include <math.h>

#define CIN 96
#define D2 192
#define D4 768
#define LL 9216
#define NN 16
#define NCH 192      /* chunks per direction */
#define CLEN 48      /* steps per chunk */

typedef float v2f __attribute__((ext_vector_type(2)));

// ---- workspace layout (float-slot offsets) ----
#define SZ_Y4SLOT (2u*2u*9216u*192u)     //  7,077,888 float slots (bf16 x2)
#define SZ_BL    (2u*9216u*192u)         //  3,538,944
#define SZ_XDBL  (2u*9216u*38u)          //    700,416
#define SZ_S     (2u*4u*192u*192u)       //    294,912
#define SZ_H     (2u*4u*192u*192u*16u)   //  4,718,592
#define F_Y4     0u
#define F_XX     0u                       /* alias: xx dead before y4 written */
#define F_ZS     (F_Y4 + SZ_Y4SLOT)
#define F_XT     (F_ZS + SZ_BL)
#define F_XD0    (F_XT + SZ_BL)
#define F_XD1    (F_XD0 + SZ_XDBL)
#define F_XD2    (F_XD1 + SZ_XDBL)
#define F_XD3    (F_XD2 + SZ_XDBL)
#define F_SBUF   (F_XD3 + SZ_XDBL)
#define F_HBUF   (F_SBUF + SZ_S)
#define F_WCOMB  (F_HBUF + SZ_H)         /* 192*80 floats */

__device__ __forceinline__ float silu_f(float z) {
    return z / (1.0f + __expf(-z));
}

// pairs p[k] = {e1^(2k+1), e1^(2k+2)}, depth <= 4
__device__ __forceinline__ void pow_pairs(float e1, v2f p[8]) {
    float e2 = e1 * e1;
    v2f p01; p01.x = e1; p01.y = e2;
    v2f e2v; e2v.x = e2; e2v.y = e2;
    v2f e4v = e2v * e2v;
    v2f e8v = e4v * e4v;
    p[0] = p01;
    p[1] = p01 * e2v;
    p[2] = p01 * e4v;
    p[3] = p[1] * e4v;
    p[4] = p01 * e8v;
    p[5] = p[1] * e8v;
    p[6] = p[2] * e8v;
    p[7] = p[3] * e8v;
}

// K0: fold Wx into combined padded weight: wcomb[d][j<38]=fwd fold, wcomb[d][40+j]=rev fold
__global__ __launch_bounds__(256) void k0_foldw(
    const float* __restrict__ Wx, float* __restrict__ wcomb)
{
    int i = blockIdx.x * 256 + threadIdx.x;
    if (i >= 192 * 80) return;
    int d = i / 80, j = i % 80;
    float v = 0.f;
    if (j < 38) v = Wx[d * 38 + j] + Wx[(d + 192) * 38 + j];
    else if (j >= 40 && j < 78) {
        int jj = j - 40;
        v = Wx[(d + 384) * 38 + jj] + Wx[(d + 576) * 38 + jj];
    }
    wcomb[i] = v;
}

// K1: xz = x @ W_in + b_in; first half -> xx (b,192,L), silu(second half) -> zs (b,L,192)
__global__ __launch_bounds__(256) void k1_inproj(
    const float* __restrict__ x, const float* __restrict__ Win,
    const float* __restrict__ bin, float* __restrict__ xx, float* __restrict__ zs)
{
    __shared__ float xs[96][68];
    __shared__ float wsm[96][68];
    int tid = threadIdx.x;
    int gl0 = blockIdx.x * 64;
    int b = gl0 / LL;
    int l0 = gl0 % LL;

    for (int i = tid; i < 96 * 64; i += 256) {
        int k = i >> 6, li = i & 63;
        xs[k][li] = x[(size_t)(b * 96 + k) * LL + l0 + li];
    }
    int lg = tid >> 4;
    int eg = tid & 15;
    for (int ech = 0; ech < 384; ech += 64) {
        __syncthreads();
        for (int i = tid; i < 96 * 64; i += 256) {
            int k = i >> 6, e = i & 63;
            wsm[k][e] = Win[k * 384 + ech + e];
        }
        __syncthreads();
        v2f acc2[4][2];
#pragma unroll
        for (int i = 0; i < 4; i++)
#pragma unroll
            for (int p = 0; p < 2; p++) { acc2[i][p].x = 0.f; acc2[i][p].y = 0.f; }
        for (int k = 0; k < 96; k++) {
            float4 xv = *(const float4*)&xs[k][lg * 4];
            float4 wv = *(const float4*)&wsm[k][eg * 4];
            v2f w0; w0.x = wv.x; w0.y = wv.y;
            v2f w1; w1.x = wv.z; w1.y = wv.w;
            float xa[4] = {xv.x, xv.y, xv.z, xv.w};
#pragma unroll
            for (int i = 0; i < 4; i++) {
                v2f xsp; xsp.x = xa[i]; xsp.y = xa[i];
                acc2[i][0] += xsp * w0;
                acc2[i][1] += xsp * w1;
            }
        }
        int e0 = ech + eg * 4;
        if (e0 < 192) {
#pragma unroll
            for (int j = 0; j < 4; j++) {
                int e = e0 + j;
                float bb = bin[e];
                float4 v = {acc2[0][j >> 1][j & 1] + bb, acc2[1][j >> 1][j & 1] + bb,
                            acc2[2][j >> 1][j & 1] + bb, acc2[3][j >> 1][j & 1] + bb};
                *(float4*)&xx[(size_t)(b * 192 + e) * LL + l0 + lg * 4] = v;
            }
        } else {
#pragma unroll
            for (int i = 0; i < 4; i++) {
                int l = l0 + lg * 4 + i;
                float4 v;
                v.x = silu_f(acc2[i][0][0] + bin[e0 + 0]);
                v.y = silu_f(acc2[i][0][1] + bin[e0 + 1]);
                v.z = silu_f(acc2[i][1][0] + bin[e0 + 2]);
                v.w = silu_f(acc2[i][1][1] + bin[e0 + 3]);
                *(float4*)&zs[((size_t)b * LL + l) * 192 + (e0 - 192)] = v;
            }
        }
    }
}

// K2: depthwise 3x3 conv + bias + silu, fused transpose: xx (b,192,96,96) -> xt (b,L,192)
__global__ __launch_bounds__(192) void k2_conv(
    const float* __restrict__ xx, const float* __restrict__ wdw,
    const float* __restrict__ bdw, float* __restrict__ xt)
{
    __shared__ float tile[32][97];
    __shared__ float wsm[32][9];
    __shared__ float bs[32];
    int tid = threadIdx.x;
    int bid = blockIdx.x;
    int h = bid % 96;
    int r = bid / 96;
    int dg = r % 6;
    int b = r / 6;

    for (int i = tid; i < 288; i += 192) wsm[i / 9][i % 9] = wdw[(dg * 32 + i / 9) * 9 + (i % 9)];
    if (tid < 32) bs[tid] = bdw[dg * 32 + tid];
    __syncthreads();

    int w = tid % 96;
    int dhalf = tid / 96;
    for (int p = 0; p < 16; p++) {
        int dsub = 2 * p + dhalf;
        const float* base = xx + (size_t)(b * 192 + dg * 32 + dsub) * LL;
        float acc = bs[dsub];
#pragma unroll
        for (int kh = 0; kh < 3; kh++) {
            int hh = h + kh - 1;
            if (hh < 0 || hh >= 96) continue;
            const float* row = base + hh * 96;
#pragma unroll
            for (int kw = 0; kw < 3; kw++) {
                int ww = w + kw - 1;
                if (ww < 0 || ww >= 96) continue;
                acc += row[ww] * wsm[dsub][kh * 3 + kw];
            }
        }
        tile[dsub][w] = silu_f(acc);
    }
    __syncthreads();
    for (int i = tid; i < 768; i += 192) {
        int q = i & 7, ls = i >> 3;
        float4 v = {tile[q * 4 + 0][ls], tile[q * 4 + 1][ls], tile[q * 4 + 2][ls], tile[q * 4 + 3][ls]};
        *(float4*)&xt[((size_t)b * LL + h * 96 + ls) * 192 + dg * 32 + q * 4] = v;
    }
}

// K3: GEMM  out[64 rows x 80 cols] = X[64x96(khalf)] @ Wcomb[96x80], K-split over 2 blocks.
// Thread tile 4 rows x 4 cols; X tile staged transposed in LDS; W tile in LDS.
__global__ __launch_bounds__(320) void k3_xdbl(
    const float* __restrict__ xt, const float* __restrict__ wcomb,
    float* __restrict__ xa0, float* __restrict__ xa1,
    float* __restrict__ xb0, float* __restrict__ xb1)
{
    __shared__ float xs[16][68];   // [d][row], row-stride 272B (16B aligned)
    __shared__ float wsh[16][80];  // [d][col], row-stride 320B (16B aligned)
    int tid = threadIdx.x;
    int bid = blockIdx.x;
    int kh = bid & 1;
    int rt = (bid >> 1) % 144;
    int b = bid / 288;
    int r0 = rt * 64;
    int k0 = kh * 96;
    float* __restrict__ xa = kh ? xa1 : xa0;
    float* __restrict__ xb = kh ? xb1 : xb0;

    int rg = tid / 20;   // 0..15 -> rows rg*4..+3
    int cg = tid % 20;   // 0..19 -> cols cg*4..+3
    v2f acc[4][2];
#pragma unroll
    for (int i = 0; i < 4; i++)
#pragma unroll
        for (int p = 0; p < 2; p++) { acc[i][p].x = 0.f; acc[i][p].y = 0.f; }

    for (int kc = 0; kc < 96; kc += 16) {
        __syncthreads();
        if (tid < 256) {
            int row = tid >> 2, dq = tid & 3;
            float4 v = *(const float4*)&xt[((size_t)b * LL + r0 + row) * 192 + k0 + kc + dq * 4];
            xs[dq * 4 + 0][row] = v.x;
            xs[dq * 4 + 1][row] = v.y;
            xs[dq * 4 + 2][row] = v.z;
            xs[dq * 4 + 3][row] = v.w;
        }
        for (int i = tid; i < 16 * 80; i += 320) {
            int d = i / 80, j = i - d * 80;
            wsh[d][j] = wcomb[(k0 + kc + d) * 80 + j];
        }
        __syncthreads();
#pragma unroll
        for (int d = 0; d < 16; d++) {
            float4 xv = *(const float4*)&xs[d][rg * 4];
            float4 wv = *(const float4*)&wsh[d][cg * 4];
            v2f w01; w01.x = wv.x; w01.y = wv.y;
            v2f w23; w23.x = wv.z; w23.y = wv.w;
            float xr[4] = {xv.x, xv.y, xv.z, xv.w};
#pragma unroll
            for (int i = 0; i < 4; i++) {
                v2f xi; xi.x = xr[i]; xi.y = xr[i];
                acc[i][0] += xi * w01;
                acc[i][1] += xi * w23;
            }
        }
    }
    int c0 = cg * 4;
#pragma unroll
    for (int i = 0; i < 4; i++) {
        int la = r0 + rg * 4 + i;
#pragma unroll
        for (int j = 0; j < 4; j++) {
            int col = c0 + j;
            float v = acc[i][j >> 1][j & 1];
            if (col < 38) {
                xa[((size_t)b * LL + la) * 38 + col] = v;
            } else if (col >= 40 && col < 78) {
                int lb = LL - 1 - la;
                xb[((size_t)b * LL + lb) * 38 + (col - 40)] = v;
            }
        }
    }
}

// K4 pass1: per-chunk local scan, SINGLE direction per block, h from 0. v2f core.
__global__ __launch_bounds__(192, 4) void k4_pass1(
    const float* __restrict__ xt,
    const float* __restrict__ xa0, const float* __restrict__ xa1,
    const float* __restrict__ xb0, const float* __restrict__ xb1,
    const float* __restrict__ Wd, const float* __restrict__ bdl,
    const float* __restrict__ Alog,
    float* __restrict__ Sbuf, float* __restrict__ Hbuf)
{
    __shared__ float Bt[CLEN][16];
    __shared__ float Dt[CLEN][6];
    int tid = threadIdx.x;
    int bid = blockIdx.x;
    int k = bid % NCH;
    int r = bid / NCH;
    int dir = r & 3;
    int b = r >> 2;
    int l0 = k * CLEN;
    for (int i = tid; i < CLEN * 16; i += 192) {
        int t = i >> 4, n = i & 15;
        size_t rb = ((size_t)b * LL + l0 + t) * 38 + 6 + n;
        Bt[t][n] = (xa0[rb] + xa1[rb]) + (xb0[rb] + xb1[rb]);
    }
    for (int i = tid; i < CLEN * 6; i += 192) {
        int t = i / 6, rr = i - 6 * t;
        size_t rb = ((size_t)b * LL + l0 + t) * 38 + rr;
        Dt[t][rr] = (xa0[rb] + xa1[rb]) + (xb0[rb] + xb1[rb]);
    }
    __syncthreads();
    int c = tid;
    int d4 = dir * 192 + c;
    float a0 = -__expf(Alog[d4 * 16]);
    bool fast = true;
    for (int n = 1; n < 16; n++) {
        float an = -__expf(Alog[d4 * 16 + n]);
        float tgt = (n + 1) * a0;
        fast = fast && (fabsf(an - tgt) <= 1e-5f * fabsf(tgt));
    }
    float wd[6];
#pragma unroll
    for (int rr = 0; rr < 6; rr++) wd[rr] = Wd[rr * 768 + d4];
    float bde = bdl[d4];
    float S = 0.f;
    const float* xtp = xt + (size_t)b * LL * 192 + c;
    int bd = b * 4 + dir;
    size_t base = (((size_t)bd * NCH + k) * 192 + c) * 16;
    if (fast) {
        v2f h2[8];
#pragma unroll
        for (int n = 0; n < 8; n++) { h2[n].x = 0.f; h2[n].y = 0.f; }
        for (int t = 0; t < CLEN; t++) {
            float s = bde;
#pragma unroll
            for (int rr = 0; rr < 6; rr++) s += Dt[t][rr] * wd[rr];
            float dt = (s > 20.f) ? s : __logf(1.f + __expf(s));
            S += dt;
            int lp = (dir < 2) ? (l0 + t) : (LL - 1 - (l0 + t));
            float u = xtp[(size_t)lp * 192];
            float du = dt * u;
            float4 q0 = *(const float4*)&Bt[t][0];
            float4 q1 = *(const float4*)&Bt[t][4];
            float4 q2 = *(const float4*)&Bt[t][8];
            float4 q3 = *(const float4*)&Bt[t][12];
            v2f B2[8];
            B2[0].x = q0.x; B2[0].y = q0.y; B2[1].x = q0.z; B2[1].y = q0.w;
            B2[2].x = q1.x; B2[2].y = q1.y; B2[3].x = q1.z; B2[3].y = q1.w;
            B2[4].x = q2.x; B2[4].y = q2.y; B2[5].x = q2.z; B2[5].y = q2.w;
            B2[6].x = q3.x; B2[6].y = q3.y; B2[7].x = q3.z; B2[7].y = q3.w;
            v2f p2[8];
            pow_pairs(__expf(dt * a0), p2);
            v2f du2; du2.x = du; du2.y = du;
#pragma unroll
            for (int n = 0; n < 8; n++) h2[n] = p2[n] * h2[n] + du2 * B2[n];
        }
        v2f* hb = (v2f*)&Hbuf[base];
#pragma unroll
        for (int n = 0; n < 8; n++) hb[n] = h2[n];
    } else {
        float h[16];
#pragma unroll
        for (int n = 0; n < 16; n++) h[n] = 0.f;
        for (int t = 0; t < CLEN; t++) {
            float s = bde;
#pragma unroll
            for (int rr = 0; rr < 6; rr++) s += Dt[t][rr] * wd[rr];
            float dt = (s > 20.f) ? s : __logf(1.f + __expf(s));
            S += dt;
            int lp = (dir < 2) ? (l0 + t) : (LL - 1 - (l0 + t));
            float u = xtp[(size_t)lp * 192];
            float du = dt * u;
#pragma unroll
            for (int n = 0; n < 16; n++) {
                float e = __expf(dt * (-__expf(Alog[d4 * 16 + n])));
                h[n] = e * h[n] + du * Bt[t][n];
            }
        }
#pragma unroll
        for (int n = 0; n < 16; n++) Hbuf[base + n] = h[n];
    }
    Sbuf[((size_t)bd * NCH + k) * 192 + c] = S;
}

// K4 pass2: scan over chunk summaries; Hbuf[k] := h_start; P = exp(a*S) on the fly
__global__ __launch_bounds__(256) void k4_pass2(
    const float* __restrict__ Sbuf, const float* __restrict__ Alog,
    float* __restrict__ Hbuf)
{
    int lane = blockIdx.x * 256 + threadIdx.x;  // 24576
    int bd = lane / 3072;
    int cn = lane % 3072;
    int c = cn >> 4, n = cn & 15;
    int dir = bd & 3;
    float an = -__expf(Alog[(dir * 192 + c) * 16 + n]);
    float h = 0.f;
#pragma unroll 8
    for (int k = 0; k < NCH; k++) {
        size_t sidx = ((size_t)bd * NCH + k) * 192 + c;
        float S = Sbuf[sidx];
        size_t idx = sidx * 16 + n;
        float hl = Hbuf[idx];
        float P = __expf(an * S);
        Hbuf[idx] = h;
        h = P * h + hl;
    }
}

// K4 pass3: replay chunk from h_start, SINGLE direction per block; y -> bf16 slab. v2f core.
__global__ __launch_bounds__(192, 4) void k4_pass3(
    const float* __restrict__ xt,
    const float* __restrict__ xa0, const float* __restrict__ xa1,
    const float* __restrict__ xb0, const float* __restrict__ xb1,
    const float* __restrict__ Wd, const float* __restrict__ bdl,
    const float* __restrict__ Alog, const float* __restrict__ Dp,
    const float* __restrict__ Hbuf, __hip_bfloat16* __restrict__ y4)
{
    __shared__ float Bt[CLEN][16];
    __shared__ float Ct[CLEN][16];
    __shared__ float Dt[CLEN][6];
    int tid = threadIdx.x;
    int bid = blockIdx.x;
    int k = bid % NCH;
    int r = bid / NCH;
    int dir = r & 3;
    int b = r >> 2;
    int l0 = k * CLEN;
    for (int i = tid; i < CLEN * 16; i += 192) {
        int t = i >> 4, n = i & 15;
        size_t rb = ((size_t)b * LL + l0 + t) * 38;
        size_t r1 = rb + 6 + n, r2 = rb + 22 + n;
        Bt[t][n] = (xa0[r1] + xa1[r1]) + (xb0[r1] + xb1[r1]);
        Ct[t][n] = (xa0[r2] + xa1[r2]) + (xb0[r2] + xb1[r2]);
    }
    for (int i = tid; i < CLEN * 6; i += 192) {
        int t = i / 6, rr = i - 6 * t;
        size_t rb = ((size_t)b * LL + l0 + t) * 38 + rr;
        Dt[t][rr] = (xa0[rb] + xa1[rb]) + (xb0[rb] + xb1[rb]);
    }
    __syncthreads();
    int c = tid;
    int d4 = dir * 192 + c;
    float a0 = -__expf(Alog[d4 * 16]);
    bool fast = true;
    for (int n = 1; n < 16; n++) {
        float an = -__expf(Alog[d4 * 16 + n]);
        float tgt = (n + 1) * a0;
        fast = fast && (fabsf(an - tgt) <= 1e-5f * fabsf(tgt));
    }
    float wd[6];
#pragma unroll
    for (int rr = 0; rr < 6; rr++) wd[rr] = Wd[rr * 768 + d4];
    float bde = bdl[d4];
    float Dv = Dp[d4];
    int bd = b * 4 + dir;
    size_t base = (((size_t)bd * NCH + k) * 192 + c) * 16;
    const float* xtp = xt + (size_t)b * LL * 192 + c;
    __hip_bfloat16* yp = y4 + (size_t)bd * LL * 192 + c;
    if (fast) {
        v2f h2[8];
        const v2f* hb = (const v2f*)&Hbuf[base];
#pragma unroll
        for (int n = 0; n < 8; n++) h2[n] = hb[n];
        for (int t = 0; t < CLEN; t++) {
            float s = bde;
#pragma unroll
            for (int rr = 0; rr < 6; rr++) s += Dt[t][rr] * wd[rr];
            float dt = (s > 20.f) ? s : __logf(1.f + __expf(s));
            int lp = (dir < 2) ? (l0 + t) : (LL - 1 - (l0 + t));
            float u = xtp[(size_t)lp * 192];
            float du = dt * u;
            float4 q0 = *(const float4*)&Bt[t][0];
            float4 q1 = *(const float4*)&Bt[t][4];
            float4 q2 = *(const float4*)&Bt[t][8];
            float4 q3 = *(const float4*)&Bt[t][12];
            v2f B2[8];
            B2[0].x = q0.x; B2[0].y = q0.y; B2[1].x = q0.z; B2[1].y = q0.w;
            B2[2].x = q1.x; B2[2].y = q1.y; B2[3].x = q1.z; B2[3].y = q1.w;
            B2[4].x = q2.x; B2[4].y = q2.y; B2[5].x = q2.z; B2[5].y = q2.w;
            B2[6].x = q3.x; B2[6].y = q3.y; B2[7].x = q3.z; B2[7].y = q3.w;
            float4 r0 = *(const float4*)&Ct[t][0];
            float4 r1 = *(const float4*)&Ct[t][4];
            float4 r2 = *(const float4*)&Ct[t][8];
            float4 r3 = *(const float4*)&Ct[t][12];
            v2f C2[8];
            C2[0].x = r0.x; C2[0].y = r0.y; C2[1].x = r0.z; C2[1].y = r0.w;
            C2[2].x = r1.x; C2[2].y = r1.y; C2[3].x = r1.z; C2[3].y = r1.w;
            C2[4].x = r2.x; C2[4].y = r2.y; C2[5].x = r2.z; C2[5].y = r2.w;
            C2[6].x = r3.x; C2[6].y = r3.y; C2[7].x = r3.z; C2[7].y = r3.w;
            v2f p2[8];
            pow_pairs(__expf(dt * a0), p2);
            v2f du2; du2.x = du; du2.y = du;
            v2f ya; ya.x = 0.f; ya.y = 0.f;
            v2f yb; yb.x = 0.f; yb.y = 0.f;
#pragma unroll
            for (int n = 0; n < 8; n += 2) {
                h2[n] = p2[n] * h2[n] + du2 * B2[n];
                ya += h2[n] * C2[n];
                h2[n + 1] = p2[n + 1] * h2[n + 1] + du2 * B2[n + 1];
                yb += h2[n + 1] * C2[n + 1];
            }
            float yv = (ya.x + ya.y) + (yb.x + yb.y) + Dv * u;
            yp[(size_t)lp * 192] = __float2bfloat16(yv);
        }
    } else {
        float h[16];
#pragma unroll
        for (int n = 0; n < 16; n++) h[n] = Hbuf[base + n];
        for (int t = 0; t < CLEN; t++) {
            float s = bde;
#pragma unroll
            for (int rr = 0; rr < 6; rr++) s += Dt[t][rr] * wd[rr];
            float dt = (s > 20.f) ? s : __logf(1.f + __expf(s));
            int lp = (dir < 2) ? (l0 + t) : (LL - 1 - (l0 + t));
            float u = xtp[(size_t)lp * 192];
            float du = dt * u;
            float yv = Dv * u;
#pragma unroll
            for (int n = 0; n < 16; n++) {
                float e = __expf(dt * (-__expf(Alog[d4 * 16 + n])));
                h[n] = e * h[n] + du * Bt[t][n];
                yv += h[n] * Ct[t][n];
            }
            yp[(size_t)lp * 192] = __float2bfloat16(yv);
        }
    }
}

// K5: yh = sum of 4 bf16 slabs; LayerNorm(192); * silu(z); @ W_out -> out (b,96,H,W)
__global__ __launch_bounds__(256) void k5_out(
    const __hip_bfloat16* __restrict__ y4, const float* __restrict__ zs,
    const float* __restrict__ lng, const float* __restrict__ lnb,
    const float* __restrict__ Wout, float* __restrict__ out)
{
    __shared__ float acts[64][194];
    __shared__ float wsh[32][100];
    int tid = threadIdx.x;
    int wv = tid >> 6;
    int lane = tid & 63;
    int gl0 = blockIdx.x * 64;
    int b = gl0 / LL;
    int l0 = gl0 % LL;
    const size_t ds = (size_t)LL * 192;

    for (int i = 0; i < 16; i++) {
        int rrow = wv * 16 + i;
        int l = l0 + rrow;
        float yv[3], zv[3];
        float s1 = 0.f, s2 = 0.f;
#pragma unroll
        for (int kk = 0; kk < 3; kk++) {
            int c = lane + kk * 64;
            size_t off = ((size_t)(b * 4) * LL + l) * 192 + c;
            float y = __bfloat162float(y4[off]) + __bfloat162float(y4[off + ds])
                    + __bfloat162float(y4[off + 2 * ds]) + __bfloat162float(y4[off + 3 * ds]);
            yv[kk] = y;
            zv[kk] = zs[((size_t)b * LL + l) * 192 + c];
            s1 += y; s2 += y * y;
        }
#pragma unroll
        for (int o = 32; o; o >>= 1) {
            s1 += __shfl_xor(s1, o, 64);
            s2 += __shfl_xor(s2, o, 64);
        }
        float mean = s1 * (1.f / 192.f);
        float var = s2 * (1.f / 192.f) - mean * mean;
        float rs = rsqrtf(var + 1e-5f);
#pragma unroll
        for (int kk = 0; kk < 3; kk++) {
            int c = lane + kk * 64;
            float yn = (yv[kk] - mean) * rs * lng[c] + lnb[c];
            acts[rrow][c] = yn * zv[kk];
        }
    }

    int ty = tid >> 4;
    int tx = tid & 15;
    v2f o2[4][3];
#pragma unroll
    for (int i = 0; i < 4; i++)
#pragma unroll
        for (int p = 0; p < 3; p++) { o2[i][p].x = 0.f; o2[i][p].y = 0.f; }

    for (int kc = 0; kc < 192; kc += 32) {
        __syncthreads();
        for (int i = tid; i < 3072; i += 256)
            wsh[i / 96][i % 96] = Wout[(kc + i / 96) * 96 + i % 96];
        __syncthreads();
        for (int kk = 0; kk < 32; kk++) {
            float av[4];
#pragma unroll
            for (int i = 0; i < 4; i++) av[i] = acts[ty * 4 + i][kc + kk];
            const v2f* wp = (const v2f*)&wsh[kk][tx * 6];
            v2f w0 = wp[0], w1 = wp[1], w2 = wp[2];
#pragma unroll
            for (int i = 0; i < 4; i++) {
                v2f sp; sp.x = av[i]; sp.y = av[i];
                o2[i][0] += sp * w0;
                o2[i][1] += sp * w1;
                o2[i][2] += sp * w2;
            }
        }
    }
#pragma unroll
    for (int i = 0; i < 4; i++) {
        int l = l0 + ty * 4 + i;
#pragma unroll
        for (int j = 0; j < 6; j++) {
            int n = tx * 6 + j;
            out[((size_t)(b * 96) + n) * LL + l] = o2[i][j >> 1][j & 1];
        }
    }
}

extern "C" void kernel_launch(void* const* d_in, const int* in_sizes, int n_in,
                              void* d_out, int out_size, void* d_ws, size_t ws_size,
                              hipStream_t stream)
{
    const float* x    = (const float*)d_in[0];
    const float* Win  = (const float*)d_in[1];
    const float* bin  = (const float*)d_in[2];
    const float* wdw  = (const float*)d_in[3];
    const float* bdw  = (const float*)d_in[4];
    const float* Alog = (const float*)d_in[5];
    const float* Dp   = (const float*)d_in[6];
    const float* Wx   = (const float*)d_in[7];
    const float* Wd   = (const float*)d_in[8];
    const float* bdl  = (const float*)d_in[9];
    const float* lng  = (const float*)d_in[10];
    const float* lnb  = (const float*)d_in[11];
    const float* Wout = (const float*)d_in[12];
    float* out = (float*)d_out;

    float* ws    = (float*)d_ws;
    __hip_bfloat16* y4 = (__hip_bfloat16*)(ws + F_Y4);
    float* xx    = ws + F_XX;    // aliases y4 slab region (dead before y4 written)
    float* zs    = ws + F_ZS;
    float* xt    = ws + F_XT;
    float* xd0   = ws + F_XD0;
    float* xd1   = ws + F_XD1;
    float* xd2   = ws + F_XD2;
    float* xd3   = ws + F_XD3;
    float* Sbuf  = ws + F_SBUF;
    float* Hbuf  = ws + F_HBUF;
    float* wcomb = ws + F_WCOMB;

    k0_foldw<<<60, 256, 0, stream>>>(Wx, wcomb);
    k1_inproj<<<288, 256, 0, stream>>>(x, Win, bin, xx, zs);
    k2_conv<<<1152, 192, 0, stream>>>(xx, wdw, bdw, xt);
    k3_xdbl<<<576, 320, 0, stream>>>(xt, wcomb, xd0, xd1, xd2, xd3);
    k4_pass1<<<1536, 192, 0, stream>>>(xt, xd0, xd1, xd2, xd3, Wd, bdl, Alog, Sbuf, Hbuf);
    k4_pass2<<<96, 256, 0, stream>>>(Sbuf, Alog, Hbuf);
    k4_pass3<<<1536, 192, 0, stream>>>(xt, xd0, xd1, xd2, xd3, Wd, bdl, Alog, Dp, Hbuf, y4);
    k5_out<<<288, 256, 0, stream>>>(y4, zs, lng, lnb, Wout, out);
}

// Round 7
// 306.723 us; speedup vs baseline: 1.1836x; 1.0516x over previous
//
#include <hip/hip_runtime.h>
#include <hip/hip_bf16.h>
#include <math.h>

#define CIN 96
#define D2 192
#define D4 768
#define LL 9216
#define NN 16
#define NCH 288      /* chunks per direction */
#define CLEN 32      /* steps per chunk */

typedef float v2f __attribute__((ext_vector_type(2)));

// ---- workspace layout (float-slot offsets) ----
#define SZ_Y4SLOT (2u*2u*9216u*192u)     //  7,077,888 float slots (bf16 x2)
#define SZ_BL    (2u*9216u*192u)         //  3,538,944
#define SZ_XDBL  (2u*9216u*38u)          //    700,416
#define SZ_S     (2u*4u*288u*192u)       //    442,368
#define SZ_HSLOT (2u*4u*288u*192u*8u)    //  3,538,944 float slots (bf16 x2)
#define F_Y4     0u
#define F_XX     0u                       /* alias: xx dead before y4 written */
#define F_ZS     (F_Y4 + SZ_Y4SLOT)
#define F_XT     (F_ZS + SZ_BL)
#define F_XD0    (F_XT + SZ_BL)
#define F_XD1    (F_XD0 + SZ_XDBL)
#define F_XD2    (F_XD1 + SZ_XDBL)
#define F_XD3    (F_XD2 + SZ_XDBL)
#define F_SBUF   (F_XD3 + SZ_XDBL)
#define F_HBUF   (F_SBUF + SZ_S)
#define F_WCOMB  (F_HBUF + SZ_HSLOT)     /* 192*80 floats */

__device__ __forceinline__ float silu_f(float z) {
    return z / (1.0f + __expf(-z));
}

// pairs p[k] = {e1^(2k+1), e1^(2k+2)}, depth <= 4
__device__ __forceinline__ void pow_pairs(float e1, v2f p[8]) {
    float e2 = e1 * e1;
    v2f p01; p01.x = e1; p01.y = e2;
    v2f e2v; e2v.x = e2; e2v.y = e2;
    v2f e4v = e2v * e2v;
    v2f e8v = e4v * e4v;
    p[0] = p01;
    p[1] = p01 * e2v;
    p[2] = p01 * e4v;
    p[3] = p[1] * e4v;
    p[4] = p01 * e8v;
    p[5] = p[1] * e8v;
    p[6] = p[2] * e8v;
    p[7] = p[3] * e8v;
}

// K0: fold Wx into combined padded weight: wcomb[d][j<38]=fwd fold, wcomb[d][40+j]=rev fold
__global__ __launch_bounds__(256) void k0_foldw(
    const float* __restrict__ Wx, float* __restrict__ wcomb)
{
    int i = blockIdx.x * 256 + threadIdx.x;
    if (i >= 192 * 80) return;
    int d = i / 80, j = i % 80;
    float v = 0.f;
    if (j < 38) v = Wx[d * 38 + j] + Wx[(d + 192) * 38 + j];
    else if (j >= 40 && j < 78) {
        int jj = j - 40;
        v = Wx[(d + 384) * 38 + jj] + Wx[(d + 576) * 38 + jj];
    }
    wcomb[i] = v;
}

// K1: xz = x @ W_in + b_in; first half -> xx (b,192,L), silu(second half) -> zs (b,L,192)
__global__ __launch_bounds__(256) void k1_inproj(
    const float* __restrict__ x, const float* __restrict__ Win,
    const float* __restrict__ bin, float* __restrict__ xx, float* __restrict__ zs)
{
    __shared__ float xs[96][68];
    __shared__ float wsm[96][68];
    int tid = threadIdx.x;
    int gl0 = blockIdx.x * 64;
    int b = gl0 / LL;
    int l0 = gl0 % LL;

    for (int i = tid; i < 96 * 64; i += 256) {
        int k = i >> 6, li = i & 63;
        xs[k][li] = x[(size_t)(b * 96 + k) * LL + l0 + li];
    }
    int lg = tid >> 4;
    int eg = tid & 15;
    for (int ech = 0; ech < 384; ech += 64) {
        __syncthreads();
        for (int i = tid; i < 96 * 64; i += 256) {
            int k = i >> 6, e = i & 63;
            wsm[k][e] = Win[k * 384 + ech + e];
        }
        __syncthreads();
        v2f acc2[4][2];
#pragma unroll
        for (int i = 0; i < 4; i++)
#pragma unroll
            for (int p = 0; p < 2; p++) { acc2[i][p].x = 0.f; acc2[i][p].y = 0.f; }
        for (int k = 0; k < 96; k++) {
            float4 xv = *(const float4*)&xs[k][lg * 4];
            float4 wv = *(const float4*)&wsm[k][eg * 4];
            v2f w0; w0.x = wv.x; w0.y = wv.y;
            v2f w1; w1.x = wv.z; w1.y = wv.w;
            float xa[4] = {xv.x, xv.y, xv.z, xv.w};
#pragma unroll
            for (int i = 0; i < 4; i++) {
                v2f xsp; xsp.x = xa[i]; xsp.y = xa[i];
                acc2[i][0] += xsp * w0;
                acc2[i][1] += xsp * w1;
            }
        }
        int e0 = ech + eg * 4;
        if (e0 < 192) {
#pragma unroll
            for (int j = 0; j < 4; j++) {
                int e = e0 + j;
                float bb = bin[e];
                float4 v = {acc2[0][j >> 1][j & 1] + bb, acc2[1][j >> 1][j & 1] + bb,
                            acc2[2][j >> 1][j & 1] + bb, acc2[3][j >> 1][j & 1] + bb};
                *(float4*)&xx[(size_t)(b * 192 + e) * LL + l0 + lg * 4] = v;
            }
        } else {
#pragma unroll
            for (int i = 0; i < 4; i++) {
                int l = l0 + lg * 4 + i;
                float4 v;
                v.x = silu_f(acc2[i][0][0] + bin[e0 + 0]);
                v.y = silu_f(acc2[i][0][1] + bin[e0 + 1]);
                v.z = silu_f(acc2[i][1][0] + bin[e0 + 2]);
                v.w = silu_f(acc2[i][1][1] + bin[e0 + 3]);
                *(float4*)&zs[((size_t)b * LL + l) * 192 + (e0 - 192)] = v;
            }
        }
    }
}

// K2: depthwise 3x3 conv + bias + silu, fused transpose: xx (b,192,96,96) -> xt (b,L,192)
__global__ __launch_bounds__(192) void k2_conv(
    const float* __restrict__ xx, const float* __restrict__ wdw,
    const float* __restrict__ bdw, float* __restrict__ xt)
{
    __shared__ float tile[32][97];
    __shared__ float wsm[32][9];
    __shared__ float bs[32];
    int tid = threadIdx.x;
    int bid = blockIdx.x;
    int h = bid % 96;
    int r = bid / 96;
    int dg = r % 6;
    int b = r / 6;

    for (int i = tid; i < 288; i += 192) wsm[i / 9][i % 9] = wdw[(dg * 32 + i / 9) * 9 + (i % 9)];
    if (tid < 32) bs[tid] = bdw[dg * 32 + tid];
    __syncthreads();

    int w = tid % 96;
    int dhalf = tid / 96;
    for (int p = 0; p < 16; p++) {
        int dsub = 2 * p + dhalf;
        const float* base = xx + (size_t)(b * 192 + dg * 32 + dsub) * LL;
        float acc = bs[dsub];
#pragma unroll
        for (int kh = 0; kh < 3; kh++) {
            int hh = h + kh - 1;
            if (hh < 0 || hh >= 96) continue;
            const float* row = base + hh * 96;
#pragma unroll
            for (int kw = 0; kw < 3; kw++) {
                int ww = w + kw - 1;
                if (ww < 0 || ww >= 96) continue;
                acc += row[ww] * wsm[dsub][kh * 3 + kw];
            }
        }
        tile[dsub][w] = silu_f(acc);
    }
    __syncthreads();
    for (int i = tid; i < 768; i += 192) {
        int q = i & 7, ls = i >> 3;
        float4 v = {tile[q * 4 + 0][ls], tile[q * 4 + 1][ls], tile[q * 4 + 2][ls], tile[q * 4 + 3][ls]};
        *(float4*)&xt[((size_t)b * LL + h * 96 + ls) * 192 + dg * 32 + q * 4] = v;
    }
}

// K3: GEMM  out[64 rows x 80 cols] = X[64x96(khalf)] @ Wcomb[96x80], K-split over 2 blocks.
__global__ __launch_bounds__(320) void k3_xdbl(
    const float* __restrict__ xt, const float* __restrict__ wcomb,
    float* __restrict__ xa0, float* __restrict__ xa1,
    float* __restrict__ xb0, float* __restrict__ xb1)
{
    __shared__ float xs[16][68];
    __shared__ float wsh[16][80];
    int tid = threadIdx.x;
    int bid = blockIdx.x;
    int kh = bid & 1;
    int rt = (bid >> 1) % 144;
    int b = bid / 288;
    int r0 = rt * 64;
    int k0 = kh * 96;
    float* __restrict__ xa = kh ? xa1 : xa0;
    float* __restrict__ xb = kh ? xb1 : xb0;

    int rg = tid / 20;
    int cg = tid % 20;
    v2f acc[4][2];
#pragma unroll
    for (int i = 0; i < 4; i++)
#pragma unroll
        for (int p = 0; p < 2; p++) { acc[i][p].x = 0.f; acc[i][p].y = 0.f; }

    for (int kc = 0; kc < 96; kc += 16) {
        __syncthreads();
        if (tid < 256) {
            int row = tid >> 2, dq = tid & 3;
            float4 v = *(const float4*)&xt[((size_t)b * LL + r0 + row) * 192 + k0 + kc + dq * 4];
            xs[dq * 4 + 0][row] = v.x;
            xs[dq * 4 + 1][row] = v.y;
            xs[dq * 4 + 2][row] = v.z;
            xs[dq * 4 + 3][row] = v.w;
        }
        for (int i = tid; i < 16 * 80; i += 320) {
            int d = i / 80, j = i - d * 80;
            wsh[d][j] = wcomb[(k0 + kc + d) * 80 + j];
        }
        __syncthreads();
#pragma unroll
        for (int d = 0; d < 16; d++) {
            float4 xv = *(const float4*)&xs[d][rg * 4];
            float4 wv = *(const float4*)&wsh[d][cg * 4];
            v2f w01; w01.x = wv.x; w01.y = wv.y;
            v2f w23; w23.x = wv.z; w23.y = wv.w;
            float xr[4] = {xv.x, xv.y, xv.z, xv.w};
#pragma unroll
            for (int i = 0; i < 4; i++) {
                v2f xi; xi.x = xr[i]; xi.y = xr[i];
                acc[i][0] += xi * w01;
                acc[i][1] += xi * w23;
            }
        }
    }
    int c0 = cg * 4;
#pragma unroll
    for (int i = 0; i < 4; i++) {
        int la = r0 + rg * 4 + i;
#pragma unroll
        for (int j = 0; j < 4; j++) {
            int col = c0 + j;
            float v = acc[i][j >> 1][j & 1];
            if (col < 38) {
                xa[((size_t)b * LL + la) * 38 + col] = v;
            } else if (col >= 40 && col < 78) {
                int lb = LL - 1 - la;
                xb[((size_t)b * LL + lb) * 38 + (col - 40)] = v;
            }
        }
    }
}

// K4 pass1: per-chunk local scan, SINGLE direction per block, h from 0. v2f core; Hbuf bf16.
__global__ __launch_bounds__(192, 4) void k4_pass1(
    const float* __restrict__ xt,
    const float* __restrict__ xa0, const float* __restrict__ xa1,
    const float* __restrict__ xb0, const float* __restrict__ xb1,
    const float* __restrict__ Wd, const float* __restrict__ bdl,
    const float* __restrict__ Alog,
    float* __restrict__ Sbuf, __hip_bfloat16* __restrict__ Hbuf)
{
    __shared__ float Bt[CLEN][16];
    __shared__ float Dt[CLEN][6];
    int tid = threadIdx.x;
    int bid = blockIdx.x;
    int k = bid % NCH;
    int r = bid / NCH;
    int dir = r & 3;
    int b = r >> 2;
    int l0 = k * CLEN;
    for (int i = tid; i < CLEN * 16; i += 192) {
        int t = i >> 4, n = i & 15;
        size_t rb = ((size_t)b * LL + l0 + t) * 38 + 6 + n;
        Bt[t][n] = (xa0[rb] + xa1[rb]) + (xb0[rb] + xb1[rb]);
    }
    for (int i = tid; i < CLEN * 6; i += 192) {
        int t = i / 6, rr = i - 6 * t;
        size_t rb = ((size_t)b * LL + l0 + t) * 38 + rr;
        Dt[t][rr] = (xa0[rb] + xa1[rb]) + (xb0[rb] + xb1[rb]);
    }
    __syncthreads();
    int c = tid;
    int d4 = dir * 192 + c;
    float a0 = -__expf(Alog[d4 * 16]);
    bool fast = true;
    for (int n = 1; n < 16; n++) {
        float an = -__expf(Alog[d4 * 16 + n]);
        float tgt = (n + 1) * a0;
        fast = fast && (fabsf(an - tgt) <= 1e-5f * fabsf(tgt));
    }
    float wd[6];
#pragma unroll
    for (int rr = 0; rr < 6; rr++) wd[rr] = Wd[rr * 768 + d4];
    float bde = bdl[d4];
    float S = 0.f;
    const float* xtp = xt + (size_t)b * LL * 192 + c;
    int bd = b * 4 + dir;
    size_t base = (((size_t)bd * NCH + k) * 192 + c) * 16;
    if (fast) {
        v2f h2[8];
#pragma unroll
        for (int n = 0; n < 8; n++) { h2[n].x = 0.f; h2[n].y = 0.f; }
#pragma unroll 2
        for (int t = 0; t < CLEN; t++) {
            float s = bde;
#pragma unroll
            for (int rr = 0; rr < 6; rr++) s += Dt[t][rr] * wd[rr];
            float dt = (s > 20.f) ? s : __logf(1.f + __expf(s));
            S += dt;
            int lp = (dir < 2) ? (l0 + t) : (LL - 1 - (l0 + t));
            float u = xtp[(size_t)lp * 192];
            float du = dt * u;
            float4 q0 = *(const float4*)&Bt[t][0];
            float4 q1 = *(const float4*)&Bt[t][4];
            float4 q2 = *(const float4*)&Bt[t][8];
            float4 q3 = *(const float4*)&Bt[t][12];
            v2f B2[8];
            B2[0].x = q0.x; B2[0].y = q0.y; B2[1].x = q0.z; B2[1].y = q0.w;
            B2[2].x = q1.x; B2[2].y = q1.y; B2[3].x = q1.z; B2[3].y = q1.w;
            B2[4].x = q2.x; B2[4].y = q2.y; B2[5].x = q2.z; B2[5].y = q2.w;
            B2[6].x = q3.x; B2[6].y = q3.y; B2[7].x = q3.z; B2[7].y = q3.w;
            v2f p2[8];
            pow_pairs(__expf(dt * a0), p2);
            v2f du2; du2.x = du; du2.y = du;
#pragma unroll
            for (int n = 0; n < 8; n++) h2[n] = p2[n] * h2[n] + du2 * B2[n];
        }
        __hip_bfloat16* hb = Hbuf + base;
#pragma unroll
        for (int n = 0; n < 8; n++) {
            hb[2 * n]     = __float2bfloat16(h2[n].x);
            hb[2 * n + 1] = __float2bfloat16(h2[n].y);
        }
    } else {
        float h[16];
#pragma unroll
        for (int n = 0; n < 16; n++) h[n] = 0.f;
        for (int t = 0; t < CLEN; t++) {
            float s = bde;
#pragma unroll
            for (int rr = 0; rr < 6; rr++) s += Dt[t][rr] * wd[rr];
            float dt = (s > 20.f) ? s : __logf(1.f + __expf(s));
            S += dt;
            int lp = (dir < 2) ? (l0 + t) : (LL - 1 - (l0 + t));
            float u = xtp[(size_t)lp * 192];
            float du = dt * u;
#pragma unroll
            for (int n = 0; n < 16; n++) {
                float e = __expf(dt * (-__expf(Alog[d4 * 16 + n])));
                h[n] = e * h[n] + du * Bt[t][n];
            }
        }
#pragma unroll
        for (int n = 0; n < 16; n++) Hbuf[base + n] = __float2bfloat16(h[n]);
    }
    Sbuf[((size_t)bd * NCH + k) * 192 + c] = S;
}

// K4 pass2: scan over chunk summaries; Hbuf[k] := h_start (bf16); P = exp(a*S) on the fly
__global__ __launch_bounds__(256) void k4_pass2(
    const float* __restrict__ Sbuf, const float* __restrict__ Alog,
    __hip_bfloat16* __restrict__ Hbuf)
{
    int lane = blockIdx.x * 256 + threadIdx.x;  // 24576
    int bd = lane / 3072;
    int cn = lane % 3072;
    int c = cn >> 4, n = cn & 15;
    int dir = bd & 3;
    float an = -__expf(Alog[(dir * 192 + c) * 16 + n]);
    float h = 0.f;
#pragma unroll 8
    for (int k = 0; k < NCH; k++) {
        size_t sidx = ((size_t)bd * NCH + k) * 192 + c;
        float S = Sbuf[sidx];
        size_t idx = sidx * 16 + n;
        float hl = __bfloat162float(Hbuf[idx]);
        float P = __expf(an * S);
        Hbuf[idx] = __float2bfloat16(h);
        h = P * h + hl;
    }
}

// K4 pass3: replay chunk from h_start, SINGLE direction per block; y -> bf16 slab. v2f core.
__global__ __launch_bounds__(192, 4) void k4_pass3(
    const float* __restrict__ xt,
    const float* __restrict__ xa0, const float* __restrict__ xa1,
    const float* __restrict__ xb0, const float* __restrict__ xb1,
    const float* __restrict__ Wd, const float* __restrict__ bdl,
    const float* __restrict__ Alog, const float* __restrict__ Dp,
    const __hip_bfloat16* __restrict__ Hbuf, __hip_bfloat16* __restrict__ y4)
{
    __shared__ float Bt[CLEN][16];
    __shared__ float Ct[CLEN][16];
    __shared__ float Dt[CLEN][6];
    int tid = threadIdx.x;
    int bid = blockIdx.x;
    int k = bid % NCH;
    int r = bid / NCH;
    int dir = r & 3;
    int b = r >> 2;
    int l0 = k * CLEN;
    for (int i = tid; i < CLEN * 16; i += 192) {
        int t = i >> 4, n = i & 15;
        size_t rb = ((size_t)b * LL + l0 + t) * 38;
        size_t r1 = rb + 6 + n, r2 = rb + 22 + n;
        Bt[t][n] = (xa0[r1] + xa1[r1]) + (xb0[r1] + xb1[r1]);
        Ct[t][n] = (xa0[r2] + xa1[r2]) + (xb0[r2] + xb1[r2]);
    }
    for (int i = tid; i < CLEN * 6; i += 192) {
        int t = i / 6, rr = i - 6 * t;
        size_t rb = ((size_t)b * LL + l0 + t) * 38 + rr;
        Dt[t][rr] = (xa0[rb] + xa1[rb]) + (xb0[rb] + xb1[rb]);
    }
    __syncthreads();
    int c = tid;
    int d4 = dir * 192 + c;
    float a0 = -__expf(Alog[d4 * 16]);
    bool fast = true;
    for (int n = 1; n < 16; n++) {
        float an = -__expf(Alog[d4 * 16 + n]);
        float tgt = (n + 1) * a0;
        fast = fast && (fabsf(an - tgt) <= 1e-5f * fabsf(tgt));
    }
    float wd[6];
#pragma unroll
    for (int rr = 0; rr < 6; rr++) wd[rr] = Wd[rr * 768 + d4];
    float bde = bdl[d4];
    float Dv = Dp[d4];
    int bd = b * 4 + dir;
    size_t base = (((size_t)bd * NCH + k) * 192 + c) * 16;
    const float* xtp = xt + (size_t)b * LL * 192 + c;
    __hip_bfloat16* yp = y4 + (size_t)bd * LL * 192 + c;
    if (fast) {
        v2f h2[8];
        const __hip_bfloat16* hb = Hbuf + base;
#pragma unroll
        for (int n = 0; n < 8; n++) {
            h2[n].x = __bfloat162float(hb[2 * n]);
            h2[n].y = __bfloat162float(hb[2 * n + 1]);
        }
#pragma unroll 2
        for (int t = 0; t < CLEN; t++) {
            float s = bde;
#pragma unroll
            for (int rr = 0; rr < 6; rr++) s += Dt[t][rr] * wd[rr];
            float dt = (s > 20.f) ? s : __logf(1.f + __expf(s));
            int lp = (dir < 2) ? (l0 + t) : (LL - 1 - (l0 + t));
            float u = xtp[(size_t)lp * 192];
            float du = dt * u;
            float4 q0 = *(const float4*)&Bt[t][0];
            float4 q1 = *(const float4*)&Bt[t][4];
            float4 q2 = *(const float4*)&Bt[t][8];
            float4 q3 = *(const float4*)&Bt[t][12];
            v2f B2[8];
            B2[0].x = q0.x; B2[0].y = q0.y; B2[1].x = q0.z; B2[1].y = q0.w;
            B2[2].x = q1.x; B2[2].y = q1.y; B2[3].x = q1.z; B2[3].y = q1.w;
            B2[4].x = q2.x; B2[4].y = q2.y; B2[5].x = q2.z; B2[5].y = q2.w;
            B2[6].x = q3.x; B2[6].y = q3.y; B2[7].x = q3.z; B2[7].y = q3.w;
            float4 r0 = *(const float4*)&Ct[t][0];
            float4 r1 = *(const float4*)&Ct[t][4];
            float4 r2 = *(const float4*)&Ct[t][8];
            float4 r3 = *(const float4*)&Ct[t][12];
            v2f C2[8];
            C2[0].x = r0.x; C2[0].y = r0.y; C2[1].x = r0.z; C2[1].y = r0.w;
            C2[2].x = r1.x; C2[2].y = r1.y; C2[3].x = r1.z; C2[3].y = r1.w;
            C2[4].x = r2.x; C2[4].y = r2.y; C2[5].x = r2.z; C2[5].y = r2.w;
            C2[6].x = r3.x; C2[6].y = r3.y; C2[7].x = r3.z; C2[7].y = r3.w;
            v2f p2[8];
            pow_pairs(__expf(dt * a0), p2);
            v2f du2; du2.x = du; du2.y = du;
            v2f ya; ya.x = 0.f; ya.y = 0.f;
            v2f yb; yb.x = 0.f; yb.y = 0.f;
#pragma unroll
            for (int n = 0; n < 8; n += 2) {
                h2[n] = p2[n] * h2[n] + du2 * B2[n];
                ya += h2[n] * C2[n];
                h2[n + 1] = p2[n + 1] * h2[n + 1] + du2 * B2[n + 1];
                yb += h2[n + 1] * C2[n + 1];
            }
            float yv = (ya.x + ya.y) + (yb.x + yb.y) + Dv * u;
            yp[(size_t)lp * 192] = __float2bfloat16(yv);
        }
    } else {
        float h[16];
#pragma unroll
        for (int n = 0; n < 16; n++) h[n] = __bfloat162float(Hbuf[base + n]);
        for (int t = 0; t < CLEN; t++) {
            float s = bde;
#pragma unroll
            for (int rr = 0; rr < 6; rr++) s += Dt[t][rr] * wd[rr];
            float dt = (s > 20.f) ? s : __logf(1.f + __expf(s));
            int lp = (dir < 2) ? (l0 + t) : (LL - 1 - (l0 + t));
            float u = xtp[(size_t)lp * 192];
            float du = dt * u;
            float yv = Dv * u;
#pragma unroll
            for (int n = 0; n < 16; n++) {
                float e = __expf(dt * (-__expf(Alog[d4 * 16 + n])));
                h[n] = e * h[n] + du * Bt[t][n];
                yv += h[n] * Ct[t][n];
            }
            yp[(size_t)lp * 192] = __float2bfloat16(yv);
        }
    }
}

// K5: yh = sum of 4 bf16 slabs; LayerNorm(192); * silu(z); @ W_out -> out (b,96,H,W)
// 32 rows/block, 31.5KB LDS -> 5 blocks/CU.
__global__ __launch_bounds__(256) void k5_out(
    const __hip_bfloat16* __restrict__ y4, const float* __restrict__ zs,
    const float* __restrict__ lng, const float* __restrict__ lnb,
    const float* __restrict__ Wout, float* __restrict__ out)
{
    __shared__ float acts[32][196];
    __shared__ float wsh[16][100];
    int tid = threadIdx.x;
    int wv = tid >> 6;
    int lane = tid & 63;
    int gl0 = blockIdx.x * 32;
    int b = gl0 / LL;
    int l0 = gl0 % LL;
    const size_t ds = (size_t)LL * 192;

    for (int i = 0; i < 8; i++) {
        int rrow = wv * 8 + i;
        int l = l0 + rrow;
        float yv[3], zv[3];
        float s1 = 0.f, s2 = 0.f;
#pragma unroll
        for (int kk = 0; kk < 3; kk++) {
            int c = lane + kk * 64;
            size_t off = ((size_t)(b * 4) * LL + l) * 192 + c;
            float y = __bfloat162float(y4[off]) + __bfloat162float(y4[off + ds])
                    + __bfloat162float(y4[off + 2 * ds]) + __bfloat162float(y4[off + 3 * ds]);
            yv[kk] = y;
            zv[kk] = zs[((size_t)b * LL + l) * 192 + c];
            s1 += y; s2 += y * y;
        }
#pragma unroll
        for (int o = 32; o; o >>= 1) {
            s1 += __shfl_xor(s1, o, 64);
            s2 += __shfl_xor(s2, o, 64);
        }
        float mean = s1 * (1.f / 192.f);
        float var = s2 * (1.f / 192.f) - mean * mean;
        float rs = rsqrtf(var + 1e-5f);
#pragma unroll
        for (int kk = 0; kk < 3; kk++) {
            int c = lane + kk * 64;
            float yn = (yv[kk] - mean) * rs * lng[c] + lnb[c];
            acts[rrow][c] = yn * zv[kk];
        }
    }

    int ty = tid >> 4;   // 0..15 -> rows ty*2..+1
    int tx = tid & 15;   // cols tx*6..+5
    v2f o2[2][3];
#pragma unroll
    for (int i = 0; i < 2; i++)
#pragma unroll
        for (int p = 0; p < 3; p++) { o2[i][p].x = 0.f; o2[i][p].y = 0.f; }

    for (int kc = 0; kc < 192; kc += 16) {
        __syncthreads();
        for (int i = tid; i < 16 * 96; i += 256) {
            int d = i / 96, j = i - d * 96;
            wsh[d][j] = Wout[(kc + d) * 96 + j];
        }
        __syncthreads();
#pragma unroll
        for (int kk = 0; kk < 16; kk++) {
            float a0v = acts[ty * 2][kc + kk];
            float a1v = acts[ty * 2 + 1][kc + kk];
            const v2f* wp = (const v2f*)&wsh[kk][tx * 6];
            v2f w0 = wp[0], w1 = wp[1], w2 = wp[2];
            v2f s0; s0.x = a0v; s0.y = a0v;
            v2f s1v; s1v.x = a1v; s1v.y = a1v;
            o2[0][0] += s0 * w0;  o2[0][1] += s0 * w1;  o2[0][2] += s0 * w2;
            o2[1][0] += s1v * w0; o2[1][1] += s1v * w1; o2[1][2] += s1v * w2;
        }
    }
#pragma unroll
    for (int i = 0; i < 2; i++) {
        int l = l0 + ty * 2 + i;
#pragma unroll
        for (int j = 0; j < 6; j++) {
            int n = tx * 6 + j;
            out[((size_t)(b * 96) + n) * LL + l] = o2[i][j >> 1][j & 1];
        }
    }
}

extern "C" void kernel_launch(void* const* d_in, const int* in_sizes, int n_in,
                              void* d_out, int out_size, void* d_ws, size_t ws_size,
                              hipStream_t stream)
{
    const float* x    = (const float*)d_in[0];
    const float* Win  = (const float*)d_in[1];
    const float* bin  = (const float*)d_in[2];
    const float* wdw  = (const float*)d_in[3];
    const float* bdw  = (const float*)d_in[4];
    const float* Alog = (const float*)d_in[5];
    const float* Dp   = (const float*)d_in[6];
    const float* Wx   = (const float*)d_in[7];
    const float* Wd   = (const float*)d_in[8];
    const float* bdl  = (const float*)d_in[9];
    const float* lng  = (const float*)d_in[10];
    const float* lnb  = (const float*)d_in[11];
    const float* Wout = (const float*)d_in[12];
    float* out = (float*)d_out;

    float* ws    = (float*)d_ws;
    __hip_bfloat16* y4 = (__hip_bfloat16*)(ws + F_Y4);
    float* xx    = ws + F_XX;    // aliases y4 slab region (dead before y4 written)
    float* zs    = ws + F_ZS;
    float* xt    = ws + F_XT;
    float* xd0   = ws + F_XD0;
    float* xd1   = ws + F_XD1;
    float* xd2   = ws + F_XD2;
    float* xd3   = ws + F_XD3;
    float* Sbuf  = ws + F_SBUF;
    __hip_bfloat16* Hbuf = (__hip_bfloat16*)(ws + F_HBUF);
    float* wcomb = ws + F_WCOMB;

    k0_foldw<<<60, 256, 0, stream>>>(Wx, wcomb);
    k1_inproj<<<288, 256, 0, stream>>>(x, Win, bin, xx, zs);
    k2_conv<<<1152, 192, 0, stream>>>(xx, wdw, bdw, xt);
    k3_xdbl<<<576, 320, 0, stream>>>(xt, wcomb, xd0, xd1, xd2, xd3);
    k4_pass1<<<2304, 192, 0, stream>>>(xt, xd0, xd1, xd2, xd3, Wd, bdl, Alog, Sbuf, Hbuf);
    k4_pass2<<<96, 256, 0, stream>>>(Sbuf, Alog, Hbuf);
    k4_pass3<<<2304, 192, 0, stream>>>(xt, xd0, xd1, xd2, xd3, Wd, bdl, Alog, Dp, Hbuf, y4);
    k5_out<<<576, 256, 0, stream>>>(y4, zs, lng, lnb, Wout, out);
}

// Round 8
// 306.524 us; speedup vs baseline: 1.1844x; 1.0006x over previous
//
#include <hip/hip_runtime.h>
#include <hip/hip_bf16.h>
#include <math.h>

#define CIN 96
#define D2 192
#define D4 768
#define LL 9216
#define NN 16
#define NCH 288      /* chunks per direction */
#define CLEN 32      /* steps per chunk */

typedef float v2f __attribute__((ext_vector_type(2)));

// ---- workspace layout (float-slot offsets) ----
#define SZ_Y4SLOT (2u*2u*9216u*192u)     //  7,077,888 float slots (bf16 x2)
#define SZ_BL    (2u*9216u*192u)         //  3,538,944
#define SZ_XDBL  (2u*9216u*38u)          //    700,416
#define SZ_S     (2u*4u*288u*192u)       //    442,368
#define SZ_HSLOT (2u*4u*288u*192u*8u)    //  3,538,944 float slots (bf16 x2)
#define F_Y4     0u
#define F_XX     0u                       /* alias: xx dead before y4 written */
#define F_ZS     (F_Y4 + SZ_Y4SLOT)
#define F_XT     (F_ZS + SZ_BL)
#define F_XD0    (F_XT + SZ_BL)
#define F_XD1    (F_XD0 + SZ_XDBL)
#define F_XD2    (F_XD1 + SZ_XDBL)
#define F_XD3    (F_XD2 + SZ_XDBL)
#define F_SBUF   (F_XD3 + SZ_XDBL)
#define F_HBUF   (F_SBUF + SZ_S)
#define F_WCOMB  (F_HBUF + SZ_HSLOT)     /* 192*80 floats */

__device__ __forceinline__ float silu_f(float z) {
    return z / (1.0f + __expf(-z));
}

// pairs p[k] = {e1^(2k+1), e1^(2k+2)}, depth <= 4
__device__ __forceinline__ void pow_pairs(float e1, v2f p[8]) {
    float e2 = e1 * e1;
    v2f p01; p01.x = e1; p01.y = e2;
    v2f e2v; e2v.x = e2; e2v.y = e2;
    v2f e4v = e2v * e2v;
    v2f e8v = e4v * e4v;
    p[0] = p01;
    p[1] = p01 * e2v;
    p[2] = p01 * e4v;
    p[3] = p[1] * e4v;
    p[4] = p01 * e8v;
    p[5] = p[1] * e8v;
    p[6] = p[2] * e8v;
    p[7] = p[3] * e8v;
}

// K0: fold Wx into combined padded weight
__global__ __launch_bounds__(256) void k0_foldw(
    const float* __restrict__ Wx, float* __restrict__ wcomb)
{
    int i = blockIdx.x * 256 + threadIdx.x;
    if (i >= 192 * 80) return;
    int d = i / 80, j = i % 80;
    float v = 0.f;
    if (j < 38) v = Wx[d * 38 + j] + Wx[(d + 192) * 38 + j];
    else if (j >= 40 && j < 78) {
        int jj = j - 40;
        v = Wx[(d + 384) * 38 + jj] + Wx[(d + 576) * 38 + jj];
    }
    wcomb[i] = v;
}

// K1: xz = x @ W_in + b_in. Block = 32 l-rows x 192-col e-half; grid 1152.
// eh=0 -> xx (b,192,L); eh=1 -> silu -> zs (b,L,192). Thread tile 2lx4e.
__global__ __launch_bounds__(256) void k1_inproj(
    const float* __restrict__ x, const float* __restrict__ Win,
    const float* __restrict__ bin, float* __restrict__ xx, float* __restrict__ zs)
{
    __shared__ float xs[96][36];
    __shared__ float wsh[96][68];
    int tid = threadIdx.x;
    int bid = blockIdx.x;
    int eh = bid & 1;
    int lt = bid >> 1;           // 0..575
    int gl0 = lt * 32;
    int b = gl0 / LL;
    int l0 = gl0 % LL;

    for (int i = tid; i < 96 * 32; i += 256) {
        int k = i >> 5, li = i & 31;
        xs[k][li] = x[(size_t)(b * 96 + k) * LL + l0 + li];
    }
    int lg = tid & 15;   // rows lg*2, lg*2+1
    int eg = tid >> 4;   // cols eg*4..+3 within chunk
    for (int ch = 0; ch < 3; ch++) {
        int ecol0 = eh * 192 + ch * 64;
        __syncthreads();
        for (int i = tid; i < 96 * 64; i += 256) {
            int k = i >> 6, e = i & 63;
            wsh[k][e] = Win[k * 384 + ecol0 + e];
        }
        __syncthreads();
        v2f acc[4];
#pragma unroll
        for (int j = 0; j < 4; j++) { acc[j].x = 0.f; acc[j].y = 0.f; }
        for (int k = 0; k < 96; k++) {
            v2f x2 = *(const v2f*)&xs[k][lg * 2];
            float4 wv = *(const float4*)&wsh[k][eg * 4];
            float wa[4] = {wv.x, wv.y, wv.z, wv.w};
#pragma unroll
            for (int j = 0; j < 4; j++) {
                v2f wsp; wsp.x = wa[j]; wsp.y = wa[j];
                acc[j] += x2 * wsp;
            }
        }
        if (eh == 0) {
#pragma unroll
            for (int j = 0; j < 4; j++) {
                int e = ecol0 + eg * 4 + j;
                float bb = bin[e];
                float2 v = {acc[j].x + bb, acc[j].y + bb};
                *(float2*)&xx[(size_t)(b * 192 + e) * LL + l0 + lg * 2] = v;
            }
        } else {
            int rel0 = ch * 64 + eg * 4;
            float bb0 = bin[ecol0 + eg * 4 + 0];
            float bb1 = bin[ecol0 + eg * 4 + 1];
            float bb2 = bin[ecol0 + eg * 4 + 2];
            float bb3 = bin[ecol0 + eg * 4 + 3];
#pragma unroll
            for (int r = 0; r < 2; r++) {
                int l = l0 + lg * 2 + r;
                float4 v;
                v.x = silu_f(acc[0][r] + bb0);
                v.y = silu_f(acc[1][r] + bb1);
                v.z = silu_f(acc[2][r] + bb2);
                v.w = silu_f(acc[3][r] + bb3);
                *(float4*)&zs[((size_t)b * LL + l) * 192 + rel0] = v;
            }
        }
    }
}

// K2: depthwise 3x3 conv + bias + silu, fused transpose: xx (b,192,96,96) -> xt (b,L,192)
__global__ __launch_bounds__(192) void k2_conv(
    const float* __restrict__ xx, const float* __restrict__ wdw,
    const float* __restrict__ bdw, float* __restrict__ xt)
{
    __shared__ float tile[32][97];
    __shared__ float wsm[32][9];
    __shared__ float bs[32];
    int tid = threadIdx.x;
    int bid = blockIdx.x;
    int h = bid % 96;
    int r = bid / 96;
    int dg = r % 6;
    int b = r / 6;

    for (int i = tid; i < 288; i += 192) wsm[i / 9][i % 9] = wdw[(dg * 32 + i / 9) * 9 + (i % 9)];
    if (tid < 32) bs[tid] = bdw[dg * 32 + tid];
    __syncthreads();

    int w = tid % 96;
    int dhalf = tid / 96;
    for (int p = 0; p < 16; p++) {
        int dsub = 2 * p + dhalf;
        const float* base = xx + (size_t)(b * 192 + dg * 32 + dsub) * LL;
        float acc = bs[dsub];
#pragma unroll
        for (int kh = 0; kh < 3; kh++) {
            int hh = h + kh - 1;
            if (hh < 0 || hh >= 96) continue;
            const float* row = base + hh * 96;
#pragma unroll
            for (int kw = 0; kw < 3; kw++) {
                int ww = w + kw - 1;
                if (ww < 0 || ww >= 96) continue;
                acc += row[ww] * wsm[dsub][kh * 3 + kw];
            }
        }
        tile[dsub][w] = silu_f(acc);
    }
    __syncthreads();
    for (int i = tid; i < 768; i += 192) {
        int q = i & 7, ls = i >> 3;
        float4 v = {tile[q * 4 + 0][ls], tile[q * 4 + 1][ls], tile[q * 4 + 2][ls], tile[q * 4 + 3][ls]};
        *(float4*)&xt[((size_t)b * LL + h * 96 + ls) * 192 + dg * 32 + q * 4] = v;
    }
}

// K3: GEMM  out[64 rows x 80 cols] = X[64x96(khalf)] @ Wcomb[96x80], K-split over 2 blocks.
__global__ __launch_bounds__(320) void k3_xdbl(
    const float* __restrict__ xt, const float* __restrict__ wcomb,
    float* __restrict__ xa0, float* __restrict__ xa1,
    float* __restrict__ xb0, float* __restrict__ xb1)
{
    __shared__ float xs[16][68];
    __shared__ float wsh[16][80];
    int tid = threadIdx.x;
    int bid = blockIdx.x;
    int kh = bid & 1;
    int rt = (bid >> 1) % 144;
    int b = bid / 288;
    int r0 = rt * 64;
    int k0 = kh * 96;
    float* __restrict__ xa = kh ? xa1 : xa0;
    float* __restrict__ xb = kh ? xb1 : xb0;

    int rg = tid / 20;
    int cg = tid % 20;
    v2f acc[4][2];
#pragma unroll
    for (int i = 0; i < 4; i++)
#pragma unroll
        for (int p = 0; p < 2; p++) { acc[i][p].x = 0.f; acc[i][p].y = 0.f; }

    for (int kc = 0; kc < 96; kc += 16) {
        __syncthreads();
        if (tid < 256) {
            int row = tid >> 2, dq = tid & 3;
            float4 v = *(const float4*)&xt[((size_t)b * LL + r0 + row) * 192 + k0 + kc + dq * 4];
            xs[dq * 4 + 0][row] = v.x;
            xs[dq * 4 + 1][row] = v.y;
            xs[dq * 4 + 2][row] = v.z;
            xs[dq * 4 + 3][row] = v.w;
        }
        for (int i = tid; i < 16 * 80; i += 320) {
            int d = i / 80, j = i - d * 80;
            wsh[d][j] = wcomb[(k0 + kc + d) * 80 + j];
        }
        __syncthreads();
#pragma unroll
        for (int d = 0; d < 16; d++) {
            float4 xv = *(const float4*)&xs[d][rg * 4];
            float4 wv = *(const float4*)&wsh[d][cg * 4];
            v2f w01; w01.x = wv.x; w01.y = wv.y;
            v2f w23; w23.x = wv.z; w23.y = wv.w;
            float xr[4] = {xv.x, xv.y, xv.z, xv.w};
#pragma unroll
            for (int i = 0; i < 4; i++) {
                v2f xi; xi.x = xr[i]; xi.y = xr[i];
                acc[i][0] += xi * w01;
                acc[i][1] += xi * w23;
            }
        }
    }
    int c0 = cg * 4;
#pragma unroll
    for (int i = 0; i < 4; i++) {
        int la = r0 + rg * 4 + i;
#pragma unroll
        for (int j = 0; j < 4; j++) {
            int col = c0 + j;
            float v = acc[i][j >> 1][j & 1];
            if (col < 38) {
                xa[((size_t)b * LL + la) * 38 + col] = v;
            } else if (col >= 40 && col < 78) {
                int lb = LL - 1 - la;
                xb[((size_t)b * LL + lb) * 38 + (col - 40)] = v;
            }
        }
    }
}

// K4 pass1: per-chunk local scan, SINGLE direction per block, h from 0. v2f core; Hbuf bf16.
__global__ __launch_bounds__(192, 4) void k4_pass1(
    const float* __restrict__ xt,
    const float* __restrict__ xa0, const float* __restrict__ xa1,
    const float* __restrict__ xb0, const float* __restrict__ xb1,
    const float* __restrict__ Wd, const float* __restrict__ bdl,
    const float* __restrict__ Alog,
    float* __restrict__ Sbuf, __hip_bfloat16* __restrict__ Hbuf)
{
    __shared__ float Bt[CLEN][16];
    __shared__ float Dt[CLEN][6];
    int tid = threadIdx.x;
    int bid = blockIdx.x;
    int k = bid % NCH;
    int r = bid / NCH;
    int dir = r & 3;
    int b = r >> 2;
    int l0 = k * CLEN;
    for (int i = tid; i < CLEN * 16; i += 192) {
        int t = i >> 4, n = i & 15;
        size_t rb = ((size_t)b * LL + l0 + t) * 38 + 6 + n;
        Bt[t][n] = (xa0[rb] + xa1[rb]) + (xb0[rb] + xb1[rb]);
    }
    for (int i = tid; i < CLEN * 6; i += 192) {
        int t = i / 6, rr = i - 6 * t;
        size_t rb = ((size_t)b * LL + l0 + t) * 38 + rr;
        Dt[t][rr] = (xa0[rb] + xa1[rb]) + (xb0[rb] + xb1[rb]);
    }
    __syncthreads();
    int c = tid;
    int d4 = dir * 192 + c;
    float a0 = -__expf(Alog[d4 * 16]);
    bool fast = true;
    for (int n = 1; n < 16; n++) {
        float an = -__expf(Alog[d4 * 16 + n]);
        float tgt = (n + 1) * a0;
        fast = fast && (fabsf(an - tgt) <= 1e-5f * fabsf(tgt));
    }
    float wd[6];
#pragma unroll
    for (int rr = 0; rr < 6; rr++) wd[rr] = Wd[rr * 768 + d4];
    float bde = bdl[d4];
    float S = 0.f;
    const float* xtp = xt + (size_t)b * LL * 192 + c;
    int bd = b * 4 + dir;
    size_t base = (((size_t)bd * NCH + k) * 192 + c) * 16;
    if (fast) {
        v2f h2[8];
#pragma unroll
        for (int n = 0; n < 8; n++) { h2[n].x = 0.f; h2[n].y = 0.f; }
#pragma unroll 2
        for (int t = 0; t < CLEN; t++) {
            float s = bde;
#pragma unroll
            for (int rr = 0; rr < 6; rr++) s += Dt[t][rr] * wd[rr];
            float dt = (s > 20.f) ? s : __logf(1.f + __expf(s));
            S += dt;
            int lp = (dir < 2) ? (l0 + t) : (LL - 1 - (l0 + t));
            float u = xtp[(size_t)lp * 192];
            float du = dt * u;
            float4 q0 = *(const float4*)&Bt[t][0];
            float4 q1 = *(const float4*)&Bt[t][4];
            float4 q2 = *(const float4*)&Bt[t][8];
            float4 q3 = *(const float4*)&Bt[t][12];
            v2f B2[8];
            B2[0].x = q0.x; B2[0].y = q0.y; B2[1].x = q0.z; B2[1].y = q0.w;
            B2[2].x = q1.x; B2[2].y = q1.y; B2[3].x = q1.z; B2[3].y = q1.w;
            B2[4].x = q2.x; B2[4].y = q2.y; B2[5].x = q2.z; B2[5].y = q2.w;
            B2[6].x = q3.x; B2[6].y = q3.y; B2[7].x = q3.z; B2[7].y = q3.w;
            v2f p2[8];
            pow_pairs(__expf(dt * a0), p2);
            v2f du2; du2.x = du; du2.y = du;
#pragma unroll
            for (int n = 0; n < 8; n++) h2[n] = p2[n] * h2[n] + du2 * B2[n];
        }
        __hip_bfloat16* hb = Hbuf + base;
#pragma unroll
        for (int n = 0; n < 8; n++) {
            hb[2 * n]     = __float2bfloat16(h2[n].x);
            hb[2 * n + 1] = __float2bfloat16(h2[n].y);
        }
    } else {
        float h[16];
#pragma unroll
        for (int n = 0; n < 16; n++) h[n] = 0.f;
        for (int t = 0; t < CLEN; t++) {
            float s = bde;
#pragma unroll
            for (int rr = 0; rr < 6; rr++) s += Dt[t][rr] * wd[rr];
            float dt = (s > 20.f) ? s : __logf(1.f + __expf(s));
            S += dt;
            int lp = (dir < 2) ? (l0 + t) : (LL - 1 - (l0 + t));
            float u = xtp[(size_t)lp * 192];
            float du = dt * u;
#pragma unroll
            for (int n = 0; n < 16; n++) {
                float e = __expf(dt * (-__expf(Alog[d4 * 16 + n])));
                h[n] = e * h[n] + du * Bt[t][n];
            }
        }
#pragma unroll
        for (int n = 0; n < 16; n++) Hbuf[base + n] = __float2bfloat16(h[n]);
    }
    Sbuf[((size_t)bd * NCH + k) * 192 + c] = S;
}

// K4 pass2: scan over chunk summaries; Hbuf[k] := h_start (bf16); P = exp(a*S) on the fly
__global__ __launch_bounds__(256) void k4_pass2(
    const float* __restrict__ Sbuf, const float* __restrict__ Alog,
    __hip_bfloat16* __restrict__ Hbuf)
{
    int lane = blockIdx.x * 256 + threadIdx.x;  // 24576
    int bd = lane / 3072;
    int cn = lane % 3072;
    int c = cn >> 4, n = cn & 15;
    int dir = bd & 3;
    float an = -__expf(Alog[(dir * 192 + c) * 16 + n]);
    float h = 0.f;
#pragma unroll 8
    for (int k = 0; k < NCH; k++) {
        size_t sidx = ((size_t)bd * NCH + k) * 192 + c;
        float S = Sbuf[sidx];
        size_t idx = sidx * 16 + n;
        float hl = __bfloat162float(Hbuf[idx]);
        float P = __expf(an * S);
        Hbuf[idx] = __float2bfloat16(h);
        h = P * h + hl;
    }
}

// K4 pass3: replay chunk from h_start, SINGLE direction per block; y -> bf16 slab. v2f core.
__global__ __launch_bounds__(192, 4) void k4_pass3(
    const float* __restrict__ xt,
    const float* __restrict__ xa0, const float* __restrict__ xa1,
    const float* __restrict__ xb0, const float* __restrict__ xb1,
    const float* __restrict__ Wd, const float* __restrict__ bdl,
    const float* __restrict__ Alog, const float* __restrict__ Dp,
    const __hip_bfloat16* __restrict__ Hbuf, __hip_bfloat16* __restrict__ y4)
{
    __shared__ float Bt[CLEN][16];
    __shared__ float Ct[CLEN][16];
    __shared__ float Dt[CLEN][6];
    int tid = threadIdx.x;
    int bid = blockIdx.x;
    int k = bid % NCH;
    int r = bid / NCH;
    int dir = r & 3;
    int b = r >> 2;
    int l0 = k * CLEN;
    for (int i = tid; i < CLEN * 16; i += 192) {
        int t = i >> 4, n = i & 15;
        size_t rb = ((size_t)b * LL + l0 + t) * 38;
        size_t r1 = rb + 6 + n, r2 = rb + 22 + n;
        Bt[t][n] = (xa0[r1] + xa1[r1]) + (xb0[r1] + xb1[r1]);
        Ct[t][n] = (xa0[r2] + xa1[r2]) + (xb0[r2] + xb1[r2]);
    }
    for (int i = tid; i < CLEN * 6; i += 192) {
        int t = i / 6, rr = i - 6 * t;
        size_t rb = ((size_t)b * LL + l0 + t) * 38 + rr;
        Dt[t][rr] = (xa0[rb] + xa1[rb]) + (xb0[rb] + xb1[rb]);
    }
    __syncthreads();
    int c = tid;
    int d4 = dir * 192 + c;
    float a0 = -__expf(Alog[d4 * 16]);
    bool fast = true;
    for (int n = 1; n < 16; n++) {
        float an = -__expf(Alog[d4 * 16 + n]);
        float tgt = (n + 1) * a0;
        fast = fast && (fabsf(an - tgt) <= 1e-5f * fabsf(tgt));
    }
    float wd[6];
#pragma unroll
    for (int rr = 0; rr < 6; rr++) wd[rr] = Wd[rr * 768 + d4];
    float bde = bdl[d4];
    float Dv = Dp[d4];
    int bd = b * 4 + dir;
    size_t base = (((size_t)bd * NCH + k) * 192 + c) * 16;
    const float* xtp = xt + (size_t)b * LL * 192 + c;
    __hip_bfloat16* yp = y4 + (size_t)bd * LL * 192 + c;
    if (fast) {
        v2f h2[8];
        const __hip_bfloat16* hb = Hbuf + base;
#pragma unroll
        for (int n = 0; n < 8; n++) {
            h2[n].x = __bfloat162float(hb[2 * n]);
            h2[n].y = __bfloat162float(hb[2 * n + 1]);
        }
#pragma unroll 2
        for (int t = 0; t < CLEN; t++) {
            float s = bde;
#pragma unroll
            for (int rr = 0; rr < 6; rr++) s += Dt[t][rr] * wd[rr];
            float dt = (s > 20.f) ? s : __logf(1.f + __expf(s));
            int lp = (dir < 2) ? (l0 + t) : (LL - 1 - (l0 + t));
            float u = xtp[(size_t)lp * 192];
            float du = dt * u;
            float4 q0 = *(const float4*)&Bt[t][0];
            float4 q1 = *(const float4*)&Bt[t][4];
            float4 q2 = *(const float4*)&Bt[t][8];
            float4 q3 = *(const float4*)&Bt[t][12];
            v2f B2[8];
            B2[0].x = q0.x; B2[0].y = q0.y; B2[1].x = q0.z; B2[1].y = q0.w;
            B2[2].x = q1.x; B2[2].y = q1.y; B2[3].x = q1.z; B2[3].y = q1.w;
            B2[4].x = q2.x; B2[4].y = q2.y; B2[5].x = q2.z; B2[5].y = q2.w;
            B2[6].x = q3.x; B2[6].y = q3.y; B2[7].x = q3.z; B2[7].y = q3.w;
            float4 r0 = *(const float4*)&Ct[t][0];
            float4 r1 = *(const float4*)&Ct[t][4];
            float4 r2 = *(const float4*)&Ct[t][8];
            float4 r3 = *(const float4*)&Ct[t][12];
            v2f C2[8];
            C2[0].x = r0.x; C2[0].y = r0.y; C2[1].x = r0.z; C2[1].y = r0.w;
            C2[2].x = r1.x; C2[2].y = r1.y; C2[3].x = r1.z; C2[3].y = r1.w;
            C2[4].x = r2.x; C2[4].y = r2.y; C2[5].x = r2.z; C2[5].y = r2.w;
            C2[6].x = r3.x; C2[6].y = r3.y; C2[7].x = r3.z; C2[7].y = r3.w;
            v2f p2[8];
            pow_pairs(__expf(dt * a0), p2);
            v2f du2; du2.x = du; du2.y = du;
            v2f ya; ya.x = 0.f; ya.y = 0.f;
            v2f yb; yb.x = 0.f; yb.y = 0.f;
#pragma unroll
            for (int n = 0; n < 8; n += 2) {
                h2[n] = p2[n] * h2[n] + du2 * B2[n];
                ya += h2[n] * C2[n];
                h2[n + 1] = p2[n + 1] * h2[n + 1] + du2 * B2[n + 1];
                yb += h2[n + 1] * C2[n + 1];
            }
            float yv = (ya.x + ya.y) + (yb.x + yb.y) + Dv * u;
            yp[(size_t)lp * 192] = __float2bfloat16(yv);
        }
    } else {
        float h[16];
#pragma unroll
        for (int n = 0; n < 16; n++) h[n] = __bfloat162float(Hbuf[base + n]);
        for (int t = 0; t < CLEN; t++) {
            float s = bde;
#pragma unroll
            for (int rr = 0; rr < 6; rr++) s += Dt[t][rr] * wd[rr];
            float dt = (s > 20.f) ? s : __logf(1.f + __expf(s));
            int lp = (dir < 2) ? (l0 + t) : (LL - 1 - (l0 + t));
            float u = xtp[(size_t)lp * 192];
            float du = dt * u;
            float yv = Dv * u;
#pragma unroll
            for (int n = 0; n < 16; n++) {
                float e = __expf(dt * (-__expf(Alog[d4 * 16 + n])));
                h[n] = e * h[n] + du * Bt[t][n];
                yv += h[n] * Ct[t][n];
            }
            yp[(size_t)lp * 192] = __float2bfloat16(yv);
        }
    }
}

// K5: yh = sum of 4 bf16 slabs; LayerNorm(192); * silu(z); @ W_out -> out (b,96,H,W)
// 16 rows/block -> grid 1152; LDS ~19KB.
__global__ __launch_bounds__(256) void k5_out(
    const __hip_bfloat16* __restrict__ y4, const float* __restrict__ zs,
    const float* __restrict__ lng, const float* __restrict__ lnb,
    const float* __restrict__ Wout, float* __restrict__ out)
{
    __shared__ float acts[16][196];
    __shared__ float wsh[16][100];
    int tid = threadIdx.x;
    int wv = tid >> 6;
    int lane = tid & 63;
    int gl0 = blockIdx.x * 16;
    int b = gl0 / LL;
    int l0 = gl0 % LL;
    const size_t ds = (size_t)LL * 192;

    for (int i = 0; i < 4; i++) {
        int rrow = wv * 4 + i;
        int l = l0 + rrow;
        float yv[3], zv[3];
        float s1 = 0.f, s2 = 0.f;
#pragma unroll
        for (int kk = 0; kk < 3; kk++) {
            int c = lane + kk * 64;
            size_t off = ((size_t)(b * 4) * LL + l) * 192 + c;
            float y = __bfloat162float(y4[off]) + __bfloat162float(y4[off + ds])
                    + __bfloat162float(y4[off + 2 * ds]) + __bfloat162float(y4[off + 3 * ds]);
            yv[kk] = y;
            zv[kk] = zs[((size_t)b * LL + l) * 192 + c];
            s1 += y; s2 += y * y;
        }
#pragma unroll
        for (int o = 32; o; o >>= 1) {
            s1 += __shfl_xor(s1, o, 64);
            s2 += __shfl_xor(s2, o, 64);
        }
        float mean = s1 * (1.f / 192.f);
        float var = s2 * (1.f / 192.f) - mean * mean;
        float rs = rsqrtf(var + 1e-5f);
#pragma unroll
        for (int kk = 0; kk < 3; kk++) {
            int c = lane + kk * 64;
            float yn = (yv[kk] - mean) * rs * lng[c] + lnb[c];
            acts[rrow][c] = yn * zv[kk];
        }
    }

    int ty = tid & 15;   // row
    int tx = tid >> 4;   // cols tx*6..+5
    v2f o2[3];
    o2[0].x = 0.f; o2[0].y = 0.f;
    o2[1].x = 0.f; o2[1].y = 0.f;
    o2[2].x = 0.f; o2[2].y = 0.f;

    for (int kc = 0; kc < 192; kc += 16) {
        __syncthreads();
        for (int i = tid; i < 16 * 96; i += 256) {
            int d = i / 96, j = i - d * 96;
            wsh[d][j] = Wout[(kc + d) * 96 + j];
        }
        __syncthreads();
#pragma unroll
        for (int kk = 0; kk < 16; kk++) {
            float av = acts[ty][kc + kk];
            const v2f* wp = (const v2f*)&wsh[kk][tx * 6];
            v2f w0 = wp[0], w1 = wp[1], w2 = wp[2];
            v2f sp; sp.x = av; sp.y = av;
            o2[0] += sp * w0;
            o2[1] += sp * w1;
            o2[2] += sp * w2;
        }
    }
    int l = l0 + ty;
#pragma unroll
    for (int j = 0; j < 6; j++) {
        int n = tx * 6 + j;
        out[((size_t)(b * 96) + n) * LL + l] = o2[j >> 1][j & 1];
    }
}

extern "C" void kernel_launch(void* const* d_in, const int* in_sizes, int n_in,
                              void* d_out, int out_size, void* d_ws, size_t ws_size,
                              hipStream_t stream)
{
    const float* x    = (const float*)d_in[0];
    const float* Win  = (const float*)d_in[1];
    const float* bin  = (const float*)d_in[2];
    const float* wdw  = (const float*)d_in[3];
    const float* bdw  = (const float*)d_in[4];
    const float* Alog = (const float*)d_in[5];
    const float* Dp   = (const float*)d_in[6];
    const float* Wx   = (const float*)d_in[7];
    const float* Wd   = (const float*)d_in[8];
    const float* bdl  = (const float*)d_in[9];
    const float* lng  = (const float*)d_in[10];
    const float* lnb  = (const float*)d_in[11];
    const float* Wout = (const float*)d_in[12];
    float* out = (float*)d_out;

    float* ws    = (float*)d_ws;
    __hip_bfloat16* y4 = (__hip_bfloat16*)(ws + F_Y4);
    float* xx    = ws + F_XX;    // aliases y4 slab region (dead before y4 written)
    float* zs    = ws + F_ZS;
    float* xt    = ws + F_XT;
    float* xd0   = ws + F_XD0;
    float* xd1   = ws + F_XD1;
    float* xd2   = ws + F_XD2;
    float* xd3   = ws + F_XD3;
    float* Sbuf  = ws + F_SBUF;
    __hip_bfloat16* Hbuf = (__hip_bfloat16*)(ws + F_HBUF);
    float* wcomb = ws + F_WCOMB;

    k0_foldw<<<60, 256, 0, stream>>>(Wx, wcomb);
    k1_inproj<<<1152, 256, 0, stream>>>(x, Win, bin, xx, zs);
    k2_conv<<<1152, 192, 0, stream>>>(xx, wdw, bdw, xt);
    k3_xdbl<<<576, 320, 0, stream>>>(xt, wcomb, xd0, xd1, xd2, xd3);
    k4_pass1<<<2304, 192, 0, stream>>>(xt, xd0, xd1, xd2, xd3, Wd, bdl, Alog, Sbuf, Hbuf);
    k4_pass2<<<96, 256, 0, stream>>>(Sbuf, Alog, Hbuf);
    k4_pass3<<<2304, 192, 0, stream>>>(xt, xd0, xd1, xd2, xd3, Wd, bdl, Alog, Dp, Hbuf, y4);
    k5_out<<<1152, 256, 0, stream>>>(y4, zs, lng, lnb, Wout, out);
}

// Round 9
// 294.136 us; speedup vs baseline: 1.2343x; 1.0421x over previous
//
#include <hip/hip_runtime.h>
#include <hip/hip_bf16.h>
#include <math.h>

#define CIN 96
#define D2 192
#define D4 768
#define LL 9216
#define NN 16
#define NCH 288      /* chunks per direction */
#define CLEN 32      /* steps per chunk */

typedef float v2f __attribute__((ext_vector_type(2)));

// ---- workspace layout (float-slot offsets) ----
#define SZ_Y4SLOT (2u*2u*9216u*192u)     //  7,077,888 float slots (bf16 x2)
#define SZ_BL    (2u*9216u*192u)         //  3,538,944
#define SZ_XDBL  (2u*9216u*38u)          //    700,416
#define SZ_S     (2u*4u*288u*192u)       //    442,368
#define SZ_HSLOT (2u*4u*288u*192u*8u)    //  3,538,944 float slots (bf16 x2)
#define F_Y4     0u
#define F_XX     0u                       /* alias: xx dead before y4 written */
#define F_ZS     (F_Y4 + SZ_Y4SLOT)
#define F_XT     (F_ZS + SZ_BL)
#define F_XD0    (F_XT + SZ_BL)
#define F_XD1    (F_XD0 + SZ_XDBL)
#define F_XD2    (F_XD1 + SZ_XDBL)
#define F_XD3    (F_XD2 + SZ_XDBL)
#define F_SBUF   (F_XD3 + SZ_XDBL)
#define F_HBUF   (F_SBUF + SZ_S)
#define F_WCOMB  (F_HBUF + SZ_HSLOT)     /* 192*80 floats */
#define F_A0     (F_WCOMB + 15360u)      /* 768 floats */
#define F_FF     (F_A0 + 768u)           /* 768 floats */

__device__ __forceinline__ float silu_f(float z) {
    return z / (1.0f + __expf(-z));
}

// K0: fold Wx into combined padded weight; precompute a0 and fast-flag per d4
__global__ __launch_bounds__(256) void k0_foldw(
    const float* __restrict__ Wx, const float* __restrict__ Alog,
    float* __restrict__ wcomb, float* __restrict__ A0f, float* __restrict__ Ffl)
{
    int i = blockIdx.x * 256 + threadIdx.x;
    if (i < 768) {
        float a0 = -__expf(Alog[i * 16]);
        bool fast = true;
        for (int n = 1; n < 16; n++) {
            float an = -__expf(Alog[i * 16 + n]);
            float tgt = (n + 1) * a0;
            fast = fast && (fabsf(an - tgt) <= 1e-5f * fabsf(tgt));
        }
        A0f[i] = a0;
        Ffl[i] = fast ? 1.f : 0.f;
    }
    if (i >= 192 * 80) return;
    int d = i / 80, j = i % 80;
    float v = 0.f;
    if (j < 38) v = Wx[d * 38 + j] + Wx[(d + 192) * 38 + j];
    else if (j >= 40 && j < 78) {
        int jj = j - 40;
        v = Wx[(d + 384) * 38 + jj] + Wx[(d + 576) * 38 + jj];
    }
    wcomb[i] = v;
}

// K1: xz = x @ W_in + b_in. Block = 32 l-rows x 192-col e-half; grid 1152.
__global__ __launch_bounds__(256) void k1_inproj(
    const float* __restrict__ x, const float* __restrict__ Win,
    const float* __restrict__ bin, float* __restrict__ xx, float* __restrict__ zs)
{
    __shared__ float xs[96][36];
    __shared__ float wsh[96][68];
    int tid = threadIdx.x;
    int bid = blockIdx.x;
    int eh = bid & 1;
    int lt = bid >> 1;
    int gl0 = lt * 32;
    int b = gl0 / LL;
    int l0 = gl0 % LL;

    for (int i = tid; i < 96 * 32; i += 256) {
        int k = i >> 5, li = i & 31;
        xs[k][li] = x[(size_t)(b * 96 + k) * LL + l0 + li];
    }
    int lg = tid & 15;
    int eg = tid >> 4;
    for (int ch = 0; ch < 3; ch++) {
        int ecol0 = eh * 192 + ch * 64;
        __syncthreads();
        for (int i = tid; i < 96 * 64; i += 256) {
            int k = i >> 6, e = i & 63;
            wsh[k][e] = Win[k * 384 + ecol0 + e];
        }
        __syncthreads();
        v2f acc[4];
#pragma unroll
        for (int j = 0; j < 4; j++) { acc[j].x = 0.f; acc[j].y = 0.f; }
        for (int k = 0; k < 96; k++) {
            v2f x2 = *(const v2f*)&xs[k][lg * 2];
            float4 wv = *(const float4*)&wsh[k][eg * 4];
            float wa[4] = {wv.x, wv.y, wv.z, wv.w};
#pragma unroll
            for (int j = 0; j < 4; j++) {
                v2f wsp; wsp.x = wa[j]; wsp.y = wa[j];
                acc[j] += x2 * wsp;
            }
        }
        if (eh == 0) {
#pragma unroll
            for (int j = 0; j < 4; j++) {
                int e = ecol0 + eg * 4 + j;
                float bb = bin[e];
                float2 v = {acc[j].x + bb, acc[j].y + bb};
                *(float2*)&xx[(size_t)(b * 192 + e) * LL + l0 + lg * 2] = v;
            }
        } else {
            int rel0 = ch * 64 + eg * 4;
            float bb0 = bin[ecol0 + eg * 4 + 0];
            float bb1 = bin[ecol0 + eg * 4 + 1];
            float bb2 = bin[ecol0 + eg * 4 + 2];
            float bb3 = bin[ecol0 + eg * 4 + 3];
#pragma unroll
            for (int r = 0; r < 2; r++) {
                int l = l0 + lg * 2 + r;
                float4 v;
                v.x = silu_f(acc[0][r] + bb0);
                v.y = silu_f(acc[1][r] + bb1);
                v.z = silu_f(acc[2][r] + bb2);
                v.w = silu_f(acc[3][r] + bb3);
                *(float4*)&zs[((size_t)b * LL + l) * 192 + rel0] = v;
            }
        }
    }
}

// K2: depthwise 3x3 conv + bias + silu, fused transpose: xx (b,192,96,96) -> xt (b,L,192)
__global__ __launch_bounds__(192) void k2_conv(
    const float* __restrict__ xx, const float* __restrict__ wdw,
    const float* __restrict__ bdw, float* __restrict__ xt)
{
    __shared__ float tile[32][97];
    __shared__ float wsm[32][9];
    __shared__ float bs[32];
    int tid = threadIdx.x;
    int bid = blockIdx.x;
    int h = bid % 96;
    int r = bid / 96;
    int dg = r % 6;
    int b = r / 6;

    for (int i = tid; i < 288; i += 192) wsm[i / 9][i % 9] = wdw[(dg * 32 + i / 9) * 9 + (i % 9)];
    if (tid < 32) bs[tid] = bdw[dg * 32 + tid];
    __syncthreads();

    int w = tid % 96;
    int dhalf = tid / 96;
    for (int p = 0; p < 16; p++) {
        int dsub = 2 * p + dhalf;
        const float* base = xx + (size_t)(b * 192 + dg * 32 + dsub) * LL;
        float acc = bs[dsub];
#pragma unroll
        for (int kh = 0; kh < 3; kh++) {
            int hh = h + kh - 1;
            if (hh < 0 || hh >= 96) continue;
            const float* row = base + hh * 96;
#pragma unroll
            for (int kw = 0; kw < 3; kw++) {
                int ww = w + kw - 1;
                if (ww < 0 || ww >= 96) continue;
                acc += row[ww] * wsm[dsub][kh * 3 + kw];
            }
        }
        tile[dsub][w] = silu_f(acc);
    }
    __syncthreads();
    for (int i = tid; i < 768; i += 192) {
        int q = i & 7, ls = i >> 3;
        float4 v = {tile[q * 4 + 0][ls], tile[q * 4 + 1][ls], tile[q * 4 + 2][ls], tile[q * 4 + 3][ls]};
        *(float4*)&xt[((size_t)b * LL + h * 96 + ls) * 192 + dg * 32 + q * 4] = v;
    }
}

// K3: GEMM  out[64 rows x 80 cols] = X[64x96(khalf)] @ Wcomb[96x80], K-split over 2 blocks.
__global__ __launch_bounds__(320) void k3_xdbl(
    const float* __restrict__ xt, const float* __restrict__ wcomb,
    float* __restrict__ xa0, float* __restrict__ xa1,
    float* __restrict__ xb0, float* __restrict__ xb1)
{
    __shared__ float xs[16][68];
    __shared__ float wsh[16][80];
    int tid = threadIdx.x;
    int bid = blockIdx.x;
    int kh = bid & 1;
    int rt = (bid >> 1) % 144;
    int b = bid / 288;
    int r0 = rt * 64;
    int k0 = kh * 96;
    float* __restrict__ xa = kh ? xa1 : xa0;
    float* __restrict__ xb = kh ? xb1 : xb0;

    int rg = tid / 20;
    int cg = tid % 20;
    v2f acc[4][2];
#pragma unroll
    for (int i = 0; i < 4; i++)
#pragma unroll
        for (int p = 0; p < 2; p++) { acc[i][p].x = 0.f; acc[i][p].y = 0.f; }

    for (int kc = 0; kc < 96; kc += 16) {
        __syncthreads();
        if (tid < 256) {
            int row = tid >> 2, dq = tid & 3;
            float4 v = *(const float4*)&xt[((size_t)b * LL + r0 + row) * 192 + k0 + kc + dq * 4];
            xs[dq * 4 + 0][row] = v.x;
            xs[dq * 4 + 1][row] = v.y;
            xs[dq * 4 + 2][row] = v.z;
            xs[dq * 4 + 3][row] = v.w;
        }
        for (int i = tid; i < 16 * 80; i += 320) {
            int d = i / 80, j = i - d * 80;
            wsh[d][j] = wcomb[(k0 + kc + d) * 80 + j];
        }
        __syncthreads();
#pragma unroll
        for (int d = 0; d < 16; d++) {
            float4 xv = *(const float4*)&xs[d][rg * 4];
            float4 wv = *(const float4*)&wsh[d][cg * 4];
            v2f w01; w01.x = wv.x; w01.y = wv.y;
            v2f w23; w23.x = wv.z; w23.y = wv.w;
            float xr[4] = {xv.x, xv.y, xv.z, xv.w};
#pragma unroll
            for (int i = 0; i < 4; i++) {
                v2f xi; xi.x = xr[i]; xi.y = xr[i];
                acc[i][0] += xi * w01;
                acc[i][1] += xi * w23;
            }
        }
    }
    int c0 = cg * 4;
#pragma unroll
    for (int i = 0; i < 4; i++) {
        int la = r0 + rg * 4 + i;
#pragma unroll
        for (int j = 0; j < 4; j++) {
            int col = c0 + j;
            float v = acc[i][j >> 1][j & 1];
            if (col < 38) {
                xa[((size_t)b * LL + la) * 38 + col] = v;
            } else if (col >= 40 && col < 78) {
                int lb = LL - 1 - la;
                xb[((size_t)b * LL + lb) * 38 + (col - 40)] = v;
            }
        }
    }
}

// K4 pass1: per-chunk local scan, SINGLE direction per block, h from 0.
// Fast path: running pair-multipliers, no p/B named arrays -> low register footprint.
__global__ __launch_bounds__(192, 4) void k4_pass1(
    const float* __restrict__ xt,
    const float* __restrict__ xa0, const float* __restrict__ xa1,
    const float* __restrict__ xb0, const float* __restrict__ xb1,
    const float* __restrict__ Wd, const float* __restrict__ bdl,
    const float* __restrict__ Alog, const float* __restrict__ A0f,
    const float* __restrict__ Ffl,
    float* __restrict__ Sbuf, __hip_bfloat16* __restrict__ Hbuf)
{
    __shared__ float Bt[CLEN][16];
    __shared__ float Dt[CLEN][6];
    int tid = threadIdx.x;
    int bid = blockIdx.x;
    int k = bid % NCH;
    int r = bid / NCH;
    int dir = r & 3;
    int b = r >> 2;
    int l0 = k * CLEN;
    for (int i = tid; i < CLEN * 16; i += 192) {
        int t = i >> 4, n = i & 15;
        size_t rb = ((size_t)b * LL + l0 + t) * 38 + 6 + n;
        Bt[t][n] = (xa0[rb] + xa1[rb]) + (xb0[rb] + xb1[rb]);
    }
    for (int i = tid; i < CLEN * 6; i += 192) {
        int t = i / 6, rr = i - 6 * t;
        size_t rb = ((size_t)b * LL + l0 + t) * 38 + rr;
        Dt[t][rr] = (xa0[rb] + xa1[rb]) + (xb0[rb] + xb1[rb]);
    }
    __syncthreads();
    int c = tid;
    int d4 = dir * 192 + c;
    float a0 = A0f[d4];
    bool fast = (Ffl[d4] != 0.f);
    float wd[6];
#pragma unroll
    for (int rr = 0; rr < 6; rr++) wd[rr] = Wd[rr * 768 + d4];
    float bde = bdl[d4];
    float S = 0.f;
    const float* xtp = xt + (size_t)b * LL * 192 + c;
    int bd = b * 4 + dir;
    size_t base = (((size_t)bd * NCH + k) * 192 + c) * 16;
    if (fast) {
        v2f h2[8];
#pragma unroll
        for (int n = 0; n < 8; n++) { h2[n].x = 0.f; h2[n].y = 0.f; }
#pragma unroll 2
        for (int t = 0; t < CLEN; t++) {
            float2 d01 = *(const float2*)&Dt[t][0];
            float2 d23 = *(const float2*)&Dt[t][2];
            float2 d45 = *(const float2*)&Dt[t][4];
            float s = bde + d01.x * wd[0] + d01.y * wd[1] + d23.x * wd[2]
                          + d23.y * wd[3] + d45.x * wd[4] + d45.y * wd[5];
            float dt = (s > 20.f) ? s : __logf(1.f + __expf(s));
            S += dt;
            int lp = (dir < 2) ? (l0 + t) : (LL - 1 - (l0 + t));
            float u = xtp[(size_t)lp * 192];
            float du = dt * u;
            float e1 = __expf(dt * a0);
            float e2 = e1 * e1;
            v2f q; q.x = e1; q.y = e2;
            v2f e2v; e2v.x = e2; e2v.y = e2;
            v2f e4v = e2v * e2v;
            v2f q2 = q * e2v;
            v2f du2; du2.x = du; du2.y = du;
#pragma unroll
            for (int g = 0; g < 4; g++) {
                float4 bq = *(const float4*)&Bt[t][4 * g];
                v2f b0; b0.x = bq.x; b0.y = bq.y;
                v2f b1; b1.x = bq.z; b1.y = bq.w;
                h2[2 * g]     = q  * h2[2 * g]     + du2 * b0;
                h2[2 * g + 1] = q2 * h2[2 * g + 1] + du2 * b1;
                if (g < 3) { q *= e4v; q2 *= e4v; }
            }
        }
        __hip_bfloat16* hb = Hbuf + base;
#pragma unroll
        for (int n = 0; n < 8; n++) {
            hb[2 * n]     = __float2bfloat16(h2[n].x);
            hb[2 * n + 1] = __float2bfloat16(h2[n].y);
        }
    } else {
        float h[16];
#pragma unroll
        for (int n = 0; n < 16; n++) h[n] = 0.f;
        for (int t = 0; t < CLEN; t++) {
            float s = bde;
#pragma unroll
            for (int rr = 0; rr < 6; rr++) s += Dt[t][rr] * wd[rr];
            float dt = (s > 20.f) ? s : __logf(1.f + __expf(s));
            S += dt;
            int lp = (dir < 2) ? (l0 + t) : (LL - 1 - (l0 + t));
            float u = xtp[(size_t)lp * 192];
            float du = dt * u;
#pragma unroll
            for (int n = 0; n < 16; n++) {
                float e = __expf(dt * (-__expf(Alog[d4 * 16 + n])));
                h[n] = e * h[n] + du * Bt[t][n];
            }
        }
#pragma unroll
        for (int n = 0; n < 16; n++) Hbuf[base + n] = __float2bfloat16(h[n]);
    }
    Sbuf[((size_t)bd * NCH + k) * 192 + c] = S;
}

// K4 pass2: scan over chunk summaries; Hbuf[k] := h_start (bf16); P = exp(a*S) on the fly
__global__ __launch_bounds__(256) void k4_pass2(
    const float* __restrict__ Sbuf, const float* __restrict__ Alog,
    __hip_bfloat16* __restrict__ Hbuf)
{
    int lane = blockIdx.x * 256 + threadIdx.x;  // 24576
    int bd = lane / 3072;
    int cn = lane % 3072;
    int c = cn >> 4, n = cn & 15;
    int dir = bd & 3;
    float an = -__expf(Alog[(dir * 192 + c) * 16 + n]);
    float h = 0.f;
#pragma unroll 8
    for (int k = 0; k < NCH; k++) {
        size_t sidx = ((size_t)bd * NCH + k) * 192 + c;
        float S = Sbuf[sidx];
        size_t idx = sidx * 16 + n;
        float hl = __bfloat162float(Hbuf[idx]);
        float P = __expf(an * S);
        Hbuf[idx] = __float2bfloat16(h);
        h = P * h + hl;
    }
}

// K4 pass3: replay chunk from h_start; y -> bf16 slab. Running-multiplier fast path.
__global__ __launch_bounds__(192, 4) void k4_pass3(
    const float* __restrict__ xt,
    const float* __restrict__ xa0, const float* __restrict__ xa1,
    const float* __restrict__ xb0, const float* __restrict__ xb1,
    const float* __restrict__ Wd, const float* __restrict__ bdl,
    const float* __restrict__ Alog, const float* __restrict__ A0f,
    const float* __restrict__ Ffl, const float* __restrict__ Dp,
    const __hip_bfloat16* __restrict__ Hbuf, __hip_bfloat16* __restrict__ y4)
{
    __shared__ float Bt[CLEN][16];
    __shared__ float Ct[CLEN][16];
    __shared__ float Dt[CLEN][6];
    int tid = threadIdx.x;
    int bid = blockIdx.x;
    int k = bid % NCH;
    int r = bid / NCH;
    int dir = r & 3;
    int b = r >> 2;
    int l0 = k * CLEN;
    for (int i = tid; i < CLEN * 16; i += 192) {
        int t = i >> 4, n = i & 15;
        size_t rb = ((size_t)b * LL + l0 + t) * 38;
        size_t r1 = rb + 6 + n, r2 = rb + 22 + n;
        Bt[t][n] = (xa0[r1] + xa1[r1]) + (xb0[r1] + xb1[r1]);
        Ct[t][n] = (xa0[r2] + xa1[r2]) + (xb0[r2] + xb1[r2]);
    }
    for (int i = tid; i < CLEN * 6; i += 192) {
        int t = i / 6, rr = i - 6 * t;
        size_t rb = ((size_t)b * LL + l0 + t) * 38 + rr;
        Dt[t][rr] = (xa0[rb] + xa1[rb]) + (xb0[rb] + xb1[rb]);
    }
    __syncthreads();
    int c = tid;
    int d4 = dir * 192 + c;
    float a0 = A0f[d4];
    bool fast = (Ffl[d4] != 0.f);
    float wd[6];
#pragma unroll
    for (int rr = 0; rr < 6; rr++) wd[rr] = Wd[rr * 768 + d4];
    float bde = bdl[d4];
    float Dv = Dp[d4];
    int bd = b * 4 + dir;
    size_t base = (((size_t)bd * NCH + k) * 192 + c) * 16;
    const float* xtp = xt + (size_t)b * LL * 192 + c;
    __hip_bfloat16* yp = y4 + (size_t)bd * LL * 192 + c;
    if (fast) {
        v2f h2[8];
        const __hip_bfloat16* hb = Hbuf + base;
#pragma unroll
        for (int n = 0; n < 8; n++) {
            h2[n].x = __bfloat162float(hb[2 * n]);
            h2[n].y = __bfloat162float(hb[2 * n + 1]);
        }
#pragma unroll 2
        for (int t = 0; t < CLEN; t++) {
            float2 d01 = *(const float2*)&Dt[t][0];
            float2 d23 = *(const float2*)&Dt[t][2];
            float2 d45 = *(const float2*)&Dt[t][4];
            float s = bde + d01.x * wd[0] + d01.y * wd[1] + d23.x * wd[2]
                          + d23.y * wd[3] + d45.x * wd[4] + d45.y * wd[5];
            float dt = (s > 20.f) ? s : __logf(1.f + __expf(s));
            int lp = (dir < 2) ? (l0 + t) : (LL - 1 - (l0 + t));
            float u = xtp[(size_t)lp * 192];
            float du = dt * u;
            float e1 = __expf(dt * a0);
            float e2 = e1 * e1;
            v2f q; q.x = e1; q.y = e2;
            v2f e2v; e2v.x = e2; e2v.y = e2;
            v2f e4v = e2v * e2v;
            v2f q2 = q * e2v;
            v2f du2; du2.x = du; du2.y = du;
            v2f ya; ya.x = 0.f; ya.y = 0.f;
            v2f yb; yb.x = 0.f; yb.y = 0.f;
#pragma unroll
            for (int g = 0; g < 4; g++) {
                float4 bq = *(const float4*)&Bt[t][4 * g];
                float4 cq = *(const float4*)&Ct[t][4 * g];
                v2f b0; b0.x = bq.x; b0.y = bq.y;
                v2f b1; b1.x = bq.z; b1.y = bq.w;
                v2f c0v; c0v.x = cq.x; c0v.y = cq.y;
                v2f c1v; c1v.x = cq.z; c1v.y = cq.w;
                h2[2 * g]     = q  * h2[2 * g]     + du2 * b0;
                ya += h2[2 * g] * c0v;
                h2[2 * g + 1] = q2 * h2[2 * g + 1] + du2 * b1;
                yb += h2[2 * g + 1] * c1v;
                if (g < 3) { q *= e4v; q2 *= e4v; }
            }
            float yv = (ya.x + ya.y) + (yb.x + yb.y) + Dv * u;
            yp[(size_t)lp * 192] = __float2bfloat16(yv);
        }
    } else {
        float h[16];
#pragma unroll
        for (int n = 0; n < 16; n++) h[n] = __bfloat162float(Hbuf[base + n]);
        for (int t = 0; t < CLEN; t++) {
            float s = bde;
#pragma unroll
            for (int rr = 0; rr < 6; rr++) s += Dt[t][rr] * wd[rr];
            float dt = (s > 20.f) ? s : __logf(1.f + __expf(s));
            int lp = (dir < 2) ? (l0 + t) : (LL - 1 - (l0 + t));
            float u = xtp[(size_t)lp * 192];
            float du = dt * u;
            float yv = Dv * u;
#pragma unroll
            for (int n = 0; n < 16; n++) {
                float e = __expf(dt * (-__expf(Alog[d4 * 16 + n])));
                h[n] = e * h[n] + du * Bt[t][n];
                yv += h[n] * Ct[t][n];
            }
            yp[(size_t)lp * 192] = __float2bfloat16(yv);
        }
    }
}

// K5: yh = sum of 4 bf16 slabs; LayerNorm(192); * silu(z); @ W_out -> out (b,96,H,W)
// 16 rows/block, grid 1152; 32-wide k-chunks (12 barriers), float4 staging.
__global__ __launch_bounds__(256) void k5_out(
    const __hip_bfloat16* __restrict__ y4, const float* __restrict__ zs,
    const float* __restrict__ lng, const float* __restrict__ lnb,
    const float* __restrict__ Wout, float* __restrict__ out)
{
    __shared__ float acts[16][196];
    __shared__ float wsh[32][100];
    int tid = threadIdx.x;
    int wv = tid >> 6;
    int lane = tid & 63;
    int gl0 = blockIdx.x * 16;
    int b = gl0 / LL;
    int l0 = gl0 % LL;
    const size_t ds = (size_t)LL * 192;

    for (int i = 0; i < 4; i++) {
        int rrow = wv * 4 + i;
        int l = l0 + rrow;
        float yv[3], zv[3];
        float s1 = 0.f, s2 = 0.f;
#pragma unroll
        for (int kk = 0; kk < 3; kk++) {
            int c = lane + kk * 64;
            size_t off = ((size_t)(b * 4) * LL + l) * 192 + c;
            float y = __bfloat162float(y4[off]) + __bfloat162float(y4[off + ds])
                    + __bfloat162float(y4[off + 2 * ds]) + __bfloat162float(y4[off + 3 * ds]);
            yv[kk] = y;
            zv[kk] = zs[((size_t)b * LL + l) * 192 + c];
            s1 += y; s2 += y * y;
        }
#pragma unroll
        for (int o = 32; o; o >>= 1) {
            s1 += __shfl_xor(s1, o, 64);
            s2 += __shfl_xor(s2, o, 64);
        }
        float mean = s1 * (1.f / 192.f);
        float var = s2 * (1.f / 192.f) - mean * mean;
        float rs = rsqrtf(var + 1e-5f);
#pragma unroll
        for (int kk = 0; kk < 3; kk++) {
            int c = lane + kk * 64;
            float yn = (yv[kk] - mean) * rs * lng[c] + lnb[c];
            acts[rrow][c] = yn * zv[kk];
        }
    }

    int ty = tid & 15;   // row
    int tx = tid >> 4;   // cols tx*6..+5
    v2f o2[3];
    o2[0].x = 0.f; o2[0].y = 0.f;
    o2[1].x = 0.f; o2[1].y = 0.f;
    o2[2].x = 0.f; o2[2].y = 0.f;

    for (int kc = 0; kc < 192; kc += 32) {
        __syncthreads();
        for (int i = tid; i < 32 * 24; i += 256) {
            int d = i / 24, q = i - d * 24;
            *(float4*)&wsh[d][q * 4] = *(const float4*)&Wout[(kc + d) * 96 + q * 4];
        }
        __syncthreads();
#pragma unroll
        for (int kk = 0; kk < 32; kk++) {
            float av = acts[ty][kc + kk];
            const v2f* wp = (const v2f*)&wsh[kk][tx * 6];
            v2f w0 = wp[0], w1 = wp[1], w2 = wp[2];
            v2f sp; sp.x = av; sp.y = av;
            o2[0] += sp * w0;
            o2[1] += sp * w1;
            o2[2] += sp * w2;
        }
    }
    int l = l0 + ty;
#pragma unroll
    for (int j = 0; j < 6; j++) {
        int n = tx * 6 + j;
        out[((size_t)(b * 96) + n) * LL + l] = o2[j >> 1][j & 1];
    }
}

extern "C" void kernel_launch(void* const* d_in, const int* in_sizes, int n_in,
                              void* d_out, int out_size, void* d_ws, size_t ws_size,
                              hipStream_t stream)
{
    const float* x    = (const float*)d_in[0];
    const float* Win  = (const float*)d_in[1];
    const float* bin  = (const float*)d_in[2];
    const float* wdw  = (const float*)d_in[3];
    const float* bdw  = (const float*)d_in[4];
    const float* Alog = (const float*)d_in[5];
    const float* Dp   = (const float*)d_in[6];
    const float* Wx   = (const float*)d_in[7];
    const float* Wd   = (const float*)d_in[8];
    const float* bdl  = (const float*)d_in[9];
    const float* lng  = (const float*)d_in[10];
    const float* lnb  = (const float*)d_in[11];
    const float* Wout = (const float*)d_in[12];
    float* out = (float*)d_out;

    float* ws    = (float*)d_ws;
    __hip_bfloat16* y4 = (__hip_bfloat16*)(ws + F_Y4);
    float* xx    = ws + F_XX;    // aliases y4 slab region (dead before y4 written)
    float* zs    = ws + F_ZS;
    float* xt    = ws + F_XT;
    float* xd0   = ws + F_XD0;
    float* xd1   = ws + F_XD1;
    float* xd2   = ws + F_XD2;
    float* xd3   = ws + F_XD3;
    float* Sbuf  = ws + F_SBUF;
    __hip_bfloat16* Hbuf = (__hip_bfloat16*)(ws + F_HBUF);
    float* wcomb = ws + F_WCOMB;
    float* A0f   = ws + F_A0;
    float* Ffl   = ws + F_FF;

    k0_foldw<<<60, 256, 0, stream>>>(Wx, Alog, wcomb, A0f, Ffl);
    k1_inproj<<<1152, 256, 0, stream>>>(x, Win, bin, xx, zs);
    k2_conv<<<1152, 192, 0, stream>>>(xx, wdw, bdw, xt);
    k3_xdbl<<<576, 320, 0, stream>>>(xt, wcomb, xd0, xd1, xd2, xd3);
    k4_pass1<<<2304, 192, 0, stream>>>(xt, xd0, xd1, xd2, xd3, Wd, bdl, Alog, A0f, Ffl, Sbuf, Hbuf);
    k4_pass2<<<96, 256, 0, stream>>>(Sbuf, Alog, Hbuf);
    k4_pass3<<<2304, 192, 0, stream>>>(xt, xd0, xd1, xd2, xd3, Wd, bdl, Alog, A0f, Ffl, Dp, Hbuf, y4);
    k5_out<<<1152, 256, 0, stream>>>(y4, zs, lng, lnb, Wout, out);
}

// Round 10
// 293.348 us; speedup vs baseline: 1.2376x; 1.0027x over previous
//
#include <hip/hip_runtime.h>
#include <hip/hip_bf16.h>
#include <math.h>

#define CIN 96
#define D2 192
#define D4 768
#define LL 9216
#define NN 16
#define NCH 288      /* chunks per direction */
#define CLEN 32      /* steps per chunk */

typedef float v2f __attribute__((ext_vector_type(2)));

// ---- workspace layout (float-slot offsets) ----
#define SZ_Y4SLOT (2u*2u*9216u*192u)     //  7,077,888 float slots (bf16 x2)
#define SZ_BL    (2u*9216u*192u)         //  3,538,944
#define SZ_XDBL  (2u*9216u*38u)          //    700,416
#define SZ_S     (2u*4u*288u*192u)       //    442,368
#define SZ_HSLOT (2u*4u*288u*192u*8u)    //  3,538,944 float slots (bf16 x2)
#define F_Y4     0u
#define F_XX     0u                       /* alias: xx dead before y4 written */
#define F_ZS     (F_Y4 + SZ_Y4SLOT)
#define F_XT     (F_ZS + SZ_BL)
#define F_XD0    (F_XT + SZ_BL)
#define F_XD1    (F_XD0 + SZ_XDBL)
#define F_XD2    (F_XD1 + SZ_XDBL)
#define F_XD3    (F_XD2 + SZ_XDBL)
#define F_SBUF   (F_XD3 + SZ_XDBL)
#define F_HBUF   (F_SBUF + SZ_S)
#define F_WCOMB  (F_HBUF + SZ_HSLOT)     /* 192*80 floats */
#define F_A0     (F_WCOMB + 15360u)      /* 768 floats */
#define F_FF     (F_A0 + 768u)           /* 768 floats */

__device__ __forceinline__ float silu_f(float z) {
    return z / (1.0f + __expf(-z));
}

// K0: fold Wx into combined padded weight; precompute a0 and fast-flag per d4
__global__ __launch_bounds__(256) void k0_foldw(
    const float* __restrict__ Wx, const float* __restrict__ Alog,
    float* __restrict__ wcomb, float* __restrict__ A0f, float* __restrict__ Ffl)
{
    int i = blockIdx.x * 256 + threadIdx.x;
    if (i < 768) {
        float a0 = -__expf(Alog[i * 16]);
        bool fast = true;
        for (int n = 1; n < 16; n++) {
            float an = -__expf(Alog[i * 16 + n]);
            float tgt = (n + 1) * a0;
            fast = fast && (fabsf(an - tgt) <= 1e-5f * fabsf(tgt));
        }
        A0f[i] = a0;
        Ffl[i] = fast ? 1.f : 0.f;
    }
    if (i >= 192 * 80) return;
    int d = i / 80, j = i % 80;
    float v = 0.f;
    if (j < 38) v = Wx[d * 38 + j] + Wx[(d + 192) * 38 + j];
    else if (j >= 40 && j < 78) {
        int jj = j - 40;
        v = Wx[(d + 384) * 38 + jj] + Wx[(d + 576) * 38 + jj];
    }
    wcomb[i] = v;
}

// K1: xz = x @ W_in + b_in. Block = 64 l x 96 e-quarter; grid 1152 (2b x 144lt x 4eq).
// Thread tile 4l x 6e; k-chunked LDS staging (32 k at a time).
// eq 0,1 -> xx (b,192,L); eq 2,3 -> silu -> zs (b,L,192).
__global__ __launch_bounds__(256) void k1_inproj(
    const float* __restrict__ x, const float* __restrict__ Win,
    const float* __restrict__ bin, float* __restrict__ xx, float* __restrict__ zs)
{
    __shared__ float xs[32][68];
    __shared__ float wsh[32][100];
    int tid = threadIdx.x;
    int bid = blockIdx.x;
    int eq = bid & 3;
    int lt = (bid >> 2) % 144;
    int b = bid / 576;
    int l0 = lt * 64;
    int e0 = eq * 96;

    int lg = tid & 15;   // l-quad: rows l0 + lg*4 .. +3
    int cg = tid >> 4;   // e-group: cols e0 + cg*6 .. +5
    v2f acc[4][3];
#pragma unroll
    for (int i = 0; i < 4; i++)
#pragma unroll
        for (int p = 0; p < 3; p++) { acc[i][p].x = 0.f; acc[i][p].y = 0.f; }

    for (int kc = 0; kc < 96; kc += 32) {
        __syncthreads();
        for (int i = tid; i < 512; i += 256) {
            int kk = i >> 4, q = i & 15;
            float4 v = *(const float4*)&x[(size_t)(b * 96 + kc + kk) * LL + l0 + q * 4];
            *(float4*)&xs[kk][q * 4] = v;
        }
        for (int i = tid; i < 768; i += 256) {
            int kk = i / 24, q = i - kk * 24;
            float4 v = *(const float4*)&Win[(kc + kk) * 384 + e0 + q * 4];
            *(float4*)&wsh[kk][q * 4] = v;
        }
        __syncthreads();
#pragma unroll 4
        for (int k = 0; k < 32; k++) {
            float4 xv = *(const float4*)&xs[k][lg * 4];
            const v2f* wp = (const v2f*)&wsh[k][cg * 6];
            v2f w0 = wp[0], w1 = wp[1], w2 = wp[2];
            float xa[4] = {xv.x, xv.y, xv.z, xv.w};
#pragma unroll
            for (int i = 0; i < 4; i++) {
                v2f xi; xi.x = xa[i]; xi.y = xa[i];
                acc[i][0] += xi * w0;
                acc[i][1] += xi * w1;
                acc[i][2] += xi * w2;
            }
        }
    }
    if (eq < 2) {
#pragma unroll
        for (int j = 0; j < 6; j++) {
            int e = e0 + cg * 6 + j;
            float bb = bin[e];
            float4 v = {acc[0][j >> 1][j & 1] + bb, acc[1][j >> 1][j & 1] + bb,
                        acc[2][j >> 1][j & 1] + bb, acc[3][j >> 1][j & 1] + bb};
            *(float4*)&xx[(size_t)(b * 192 + e) * LL + l0 + lg * 4] = v;
        }
    } else {
        int zc0 = e0 - 192 + cg * 6;
        float bb[6];
#pragma unroll
        for (int j = 0; j < 6; j++) bb[j] = bin[e0 + cg * 6 + j];
#pragma unroll
        for (int i = 0; i < 4; i++) {
            int l = l0 + lg * 4 + i;
            float* zp = &zs[((size_t)b * LL + l) * 192 + zc0];
#pragma unroll
            for (int p = 0; p < 3; p++) {
                float2 v;
                v.x = silu_f(acc[i][p].x + bb[2 * p]);
                v.y = silu_f(acc[i][p].y + bb[2 * p + 1]);
                *(float2*)&zp[2 * p] = v;
            }
        }
    }
}

// K2: depthwise 3x3 conv + bias + silu, fused transpose: xx (b,192,96,96) -> xt (b,L,192)
__global__ __launch_bounds__(192) void k2_conv(
    const float* __restrict__ xx, const float* __restrict__ wdw,
    const float* __restrict__ bdw, float* __restrict__ xt)
{
    __shared__ float tile[32][97];
    __shared__ float wsm[32][9];
    __shared__ float bs[32];
    int tid = threadIdx.x;
    int bid = blockIdx.x;
    int h = bid % 96;
    int r = bid / 96;
    int dg = r % 6;
    int b = r / 6;

    for (int i = tid; i < 288; i += 192) wsm[i / 9][i % 9] = wdw[(dg * 32 + i / 9) * 9 + (i % 9)];
    if (tid < 32) bs[tid] = bdw[dg * 32 + tid];
    __syncthreads();

    int w = tid % 96;
    int dhalf = tid / 96;
    for (int p = 0; p < 16; p++) {
        int dsub = 2 * p + dhalf;
        const float* base = xx + (size_t)(b * 192 + dg * 32 + dsub) * LL;
        float acc = bs[dsub];
#pragma unroll
        for (int kh = 0; kh < 3; kh++) {
            int hh = h + kh - 1;
            if (hh < 0 || hh >= 96) continue;
            const float* row = base + hh * 96;
#pragma unroll
            for (int kw = 0; kw < 3; kw++) {
                int ww = w + kw - 1;
                if (ww < 0 || ww >= 96) continue;
                acc += row[ww] * wsm[dsub][kh * 3 + kw];
            }
        }
        tile[dsub][w] = silu_f(acc);
    }
    __syncthreads();
    for (int i = tid; i < 768; i += 192) {
        int q = i & 7, ls = i >> 3;
        float4 v = {tile[q * 4 + 0][ls], tile[q * 4 + 1][ls], tile[q * 4 + 2][ls], tile[q * 4 + 3][ls]};
        *(float4*)&xt[((size_t)b * LL + h * 96 + ls) * 192 + dg * 32 + q * 4] = v;
    }
}

// K3: GEMM  out[64 rows x 80 cols] = X[64x96(khalf)] @ Wcomb[96x80], K-split over 2 blocks.
__global__ __launch_bounds__(320) void k3_xdbl(
    const float* __restrict__ xt, const float* __restrict__ wcomb,
    float* __restrict__ xa0, float* __restrict__ xa1,
    float* __restrict__ xb0, float* __restrict__ xb1)
{
    __shared__ float xs[16][68];
    __shared__ float wsh[16][80];
    int tid = threadIdx.x;
    int bid = blockIdx.x;
    int kh = bid & 1;
    int rt = (bid >> 1) % 144;
    int b = bid / 288;
    int r0 = rt * 64;
    int k0 = kh * 96;
    float* __restrict__ xa = kh ? xa1 : xa0;
    float* __restrict__ xb = kh ? xb1 : xb0;

    int rg = tid / 20;
    int cg = tid % 20;
    v2f acc[4][2];
#pragma unroll
    for (int i = 0; i < 4; i++)
#pragma unroll
        for (int p = 0; p < 2; p++) { acc[i][p].x = 0.f; acc[i][p].y = 0.f; }

    for (int kc = 0; kc < 96; kc += 16) {
        __syncthreads();
        if (tid < 256) {
            int row = tid >> 2, dq = tid & 3;
            float4 v = *(const float4*)&xt[((size_t)b * LL + r0 + row) * 192 + k0 + kc + dq * 4];
            xs[dq * 4 + 0][row] = v.x;
            xs[dq * 4 + 1][row] = v.y;
            xs[dq * 4 + 2][row] = v.z;
            xs[dq * 4 + 3][row] = v.w;
        }
        for (int i = tid; i < 16 * 80; i += 320) {
            int d = i / 80, j = i - d * 80;
            wsh[d][j] = wcomb[(k0 + kc + d) * 80 + j];
        }
        __syncthreads();
#pragma unroll
        for (int d = 0; d < 16; d++) {
            float4 xv = *(const float4*)&xs[d][rg * 4];
            float4 wv = *(const float4*)&wsh[d][cg * 4];
            v2f w01; w01.x = wv.x; w01.y = wv.y;
            v2f w23; w23.x = wv.z; w23.y = wv.w;
            float xr[4] = {xv.x, xv.y, xv.z, xv.w};
#pragma unroll
            for (int i = 0; i < 4; i++) {
                v2f xi; xi.x = xr[i]; xi.y = xr[i];
                acc[i][0] += xi * w01;
                acc[i][1] += xi * w23;
            }
        }
    }
    int c0 = cg * 4;
#pragma unroll
    for (int i = 0; i < 4; i++) {
        int la = r0 + rg * 4 + i;
#pragma unroll
        for (int j = 0; j < 4; j++) {
            int col = c0 + j;
            float v = acc[i][j >> 1][j & 1];
            if (col < 38) {
                xa[((size_t)b * LL + la) * 38 + col] = v;
            } else if (col >= 40 && col < 78) {
                int lb = LL - 1 - la;
                xb[((size_t)b * LL + lb) * 38 + (col - 40)] = v;
            }
        }
    }
}

// K4 pass1: per-chunk local scan, SINGLE direction per block, h from 0.
__global__ __launch_bounds__(192) __attribute__((amdgpu_waves_per_eu(2, 4))) void k4_pass1(
    const float* __restrict__ xt,
    const float* __restrict__ xa0, const float* __restrict__ xa1,
    const float* __restrict__ xb0, const float* __restrict__ xb1,
    const float* __restrict__ Wd, const float* __restrict__ bdl,
    const float* __restrict__ Alog, const float* __restrict__ A0f,
    const float* __restrict__ Ffl,
    float* __restrict__ Sbuf, __hip_bfloat16* __restrict__ Hbuf)
{
    __shared__ float Bt[CLEN][16];
    __shared__ float Dt[CLEN][6];
    int tid = threadIdx.x;
    int bid = blockIdx.x;
    int k = bid % NCH;
    int r = bid / NCH;
    int dir = r & 3;
    int b = r >> 2;
    int l0 = k * CLEN;
    for (int i = tid; i < CLEN * 16; i += 192) {
        int t = i >> 4, n = i & 15;
        size_t rb = ((size_t)b * LL + l0 + t) * 38 + 6 + n;
        Bt[t][n] = (xa0[rb] + xa1[rb]) + (xb0[rb] + xb1[rb]);
    }
    for (int i = tid; i < CLEN * 6; i += 192) {
        int t = i / 6, rr = i - 6 * t;
        size_t rb = ((size_t)b * LL + l0 + t) * 38 + rr;
        Dt[t][rr] = (xa0[rb] + xa1[rb]) + (xb0[rb] + xb1[rb]);
    }
    __syncthreads();
    int c = tid;
    int d4 = dir * 192 + c;
    float a0 = A0f[d4];
    bool fast = (Ffl[d4] != 0.f);
    float wd[6];
#pragma unroll
    for (int rr = 0; rr < 6; rr++) wd[rr] = Wd[rr * 768 + d4];
    float bde = bdl[d4];
    float S = 0.f;
    const float* xtp = xt + (size_t)b * LL * 192 + c;
    int bd = b * 4 + dir;
    size_t base = (((size_t)bd * NCH + k) * 192 + c) * 16;
    if (fast) {
        v2f h2[8];
#pragma unroll
        for (int n = 0; n < 8; n++) { h2[n].x = 0.f; h2[n].y = 0.f; }
#pragma unroll 2
        for (int t = 0; t < CLEN; t++) {
            float2 d01 = *(const float2*)&Dt[t][0];
            float2 d23 = *(const float2*)&Dt[t][2];
            float2 d45 = *(const float2*)&Dt[t][4];
            float s = bde + d01.x * wd[0] + d01.y * wd[1] + d23.x * wd[2]
                          + d23.y * wd[3] + d45.x * wd[4] + d45.y * wd[5];
            float dt = (s > 20.f) ? s : __logf(1.f + __expf(s));
            S += dt;
            int lp = (dir < 2) ? (l0 + t) : (LL - 1 - (l0 + t));
            float u = xtp[(size_t)lp * 192];
            float du = dt * u;
            float e1 = __expf(dt * a0);
            float e2 = e1 * e1;
            v2f q; q.x = e1; q.y = e2;
            v2f e2v; e2v.x = e2; e2v.y = e2;
            v2f e4v = e2v * e2v;
            v2f q2 = q * e2v;
            v2f du2; du2.x = du; du2.y = du;
#pragma unroll
            for (int g = 0; g < 4; g++) {
                float4 bq = *(const float4*)&Bt[t][4 * g];
                v2f b0; b0.x = bq.x; b0.y = bq.y;
                v2f b1; b1.x = bq.z; b1.y = bq.w;
                h2[2 * g]     = q  * h2[2 * g]     + du2 * b0;
                h2[2 * g + 1] = q2 * h2[2 * g + 1] + du2 * b1;
                if (g < 3) { q *= e4v; q2 *= e4v; }
            }
        }
        __hip_bfloat16* hb = Hbuf + base;
#pragma unroll
        for (int n = 0; n < 8; n++) {
            hb[2 * n]     = __float2bfloat16(h2[n].x);
            hb[2 * n + 1] = __float2bfloat16(h2[n].y);
        }
    } else {
        float h[16];
#pragma unroll
        for (int n = 0; n < 16; n++) h[n] = 0.f;
        for (int t = 0; t < CLEN; t++) {
            float s = bde;
#pragma unroll
            for (int rr = 0; rr < 6; rr++) s += Dt[t][rr] * wd[rr];
            float dt = (s > 20.f) ? s : __logf(1.f + __expf(s));
            S += dt;
            int lp = (dir < 2) ? (l0 + t) : (LL - 1 - (l0 + t));
            float u = xtp[(size_t)lp * 192];
            float du = dt * u;
#pragma unroll
            for (int n = 0; n < 16; n++) {
                float e = __expf(dt * (-__expf(Alog[d4 * 16 + n])));
                h[n] = e * h[n] + du * Bt[t][n];
            }
        }
#pragma unroll
        for (int n = 0; n < 16; n++) Hbuf[base + n] = __float2bfloat16(h[n]);
    }
    Sbuf[((size_t)bd * NCH + k) * 192 + c] = S;
}

// K4 pass2: scan over chunk summaries; Hbuf[k] := h_start (bf16); P = exp(a*S) on the fly
__global__ __launch_bounds__(256) void k4_pass2(
    const float* __restrict__ Sbuf, const float* __restrict__ Alog,
    __hip_bfloat16* __restrict__ Hbuf)
{
    int lane = blockIdx.x * 256 + threadIdx.x;  // 24576
    int bd = lane / 3072;
    int cn = lane % 3072;
    int c = cn >> 4, n = cn & 15;
    int dir = bd & 3;
    float an = -__expf(Alog[(dir * 192 + c) * 16 + n]);
    float h = 0.f;
#pragma unroll 8
    for (int k = 0; k < NCH; k++) {
        size_t sidx = ((size_t)bd * NCH + k) * 192 + c;
        float S = Sbuf[sidx];
        size_t idx = sidx * 16 + n;
        float hl = __bfloat162float(Hbuf[idx]);
        float P = __expf(an * S);
        Hbuf[idx] = __float2bfloat16(h);
        h = P * h + hl;
    }
}

// K4 pass3: replay chunk from h_start; y -> bf16 slab. Running-multiplier fast path.
__global__ __launch_bounds__(192) __attribute__((amdgpu_waves_per_eu(2, 4))) void k4_pass3(
    const float* __restrict__ xt,
    const float* __restrict__ xa0, const float* __restrict__ xa1,
    const float* __restrict__ xb0, const float* __restrict__ xb1,
    const float* __restrict__ Wd, const float* __restrict__ bdl,
    const float* __restrict__ Alog, const float* __restrict__ A0f,
    const float* __restrict__ Ffl, const float* __restrict__ Dp,
    const __hip_bfloat16* __restrict__ Hbuf, __hip_bfloat16* __restrict__ y4)
{
    __shared__ float Bt[CLEN][16];
    __shared__ float Ct[CLEN][16];
    __shared__ float Dt[CLEN][6];
    int tid = threadIdx.x;
    int bid = blockIdx.x;
    int k = bid % NCH;
    int r = bid / NCH;
    int dir = r & 3;
    int b = r >> 2;
    int l0 = k * CLEN;
    for (int i = tid; i < CLEN * 16; i += 192) {
        int t = i >> 4, n = i & 15;
        size_t rb = ((size_t)b * LL + l0 + t) * 38;
        size_t r1 = rb + 6 + n, r2 = rb + 22 + n;
        Bt[t][n] = (xa0[r1] + xa1[r1]) + (xb0[r1] + xb1[r1]);
        Ct[t][n] = (xa0[r2] + xa1[r2]) + (xb0[r2] + xb1[r2]);
    }
    for (int i = tid; i < CLEN * 6; i += 192) {
        int t = i / 6, rr = i - 6 * t;
        size_t rb = ((size_t)b * LL + l0 + t) * 38 + rr;
        Dt[t][rr] = (xa0[rb] + xa1[rb]) + (xb0[rb] + xb1[rb]);
    }
    __syncthreads();
    int c = tid;
    int d4 = dir * 192 + c;
    float a0 = A0f[d4];
    bool fast = (Ffl[d4] != 0.f);
    float wd[6];
#pragma unroll
    for (int rr = 0; rr < 6; rr++) wd[rr] = Wd[rr * 768 + d4];
    float bde = bdl[d4];
    float Dv = Dp[d4];
    int bd = b * 4 + dir;
    size_t base = (((size_t)bd * NCH + k) * 192 + c) * 16;
    const float* xtp = xt + (size_t)b * LL * 192 + c;
    __hip_bfloat16* yp = y4 + (size_t)bd * LL * 192 + c;
    if (fast) {
        v2f h2[8];
        const __hip_bfloat16* hb = Hbuf + base;
#pragma unroll
        for (int n = 0; n < 8; n++) {
            h2[n].x = __bfloat162float(hb[2 * n]);
            h2[n].y = __bfloat162float(hb[2 * n + 1]);
        }
#pragma unroll 2
        for (int t = 0; t < CLEN; t++) {
            float2 d01 = *(const float2*)&Dt[t][0];
            float2 d23 = *(const float2*)&Dt[t][2];
            float2 d45 = *(const float2*)&Dt[t][4];
            float s = bde + d01.x * wd[0] + d01.y * wd[1] + d23.x * wd[2]
                          + d23.y * wd[3] + d45.x * wd[4] + d45.y * wd[5];
            float dt = (s > 20.f) ? s : __logf(1.f + __expf(s));
            int lp = (dir < 2) ? (l0 + t) : (LL - 1 - (l0 + t));
            float u = xtp[(size_t)lp * 192];
            float du = dt * u;
            float e1 = __expf(dt * a0);
            float e2 = e1 * e1;
            v2f q; q.x = e1; q.y = e2;
            v2f e2v; e2v.x = e2; e2v.y = e2;
            v2f e4v = e2v * e2v;
            v2f q2 = q * e2v;
            v2f du2; du2.x = du; du2.y = du;
            v2f ya; ya.x = 0.f; ya.y = 0.f;
            v2f yb; yb.x = 0.f; yb.y = 0.f;
#pragma unroll
            for (int g = 0; g < 4; g++) {
                float4 bq = *(const float4*)&Bt[t][4 * g];
                float4 cq = *(const float4*)&Ct[t][4 * g];
                v2f b0; b0.x = bq.x; b0.y = bq.y;
                v2f b1; b1.x = bq.z; b1.y = bq.w;
                v2f c0v; c0v.x = cq.x; c0v.y = cq.y;
                v2f c1v; c1v.x = cq.z; c1v.y = cq.w;
                h2[2 * g]     = q  * h2[2 * g]     + du2 * b0;
                ya += h2[2 * g] * c0v;
                h2[2 * g + 1] = q2 * h2[2 * g + 1] + du2 * b1;
                yb += h2[2 * g + 1] * c1v;
                if (g < 3) { q *= e4v; q2 *= e4v; }
            }
            float yv = (ya.x + ya.y) + (yb.x + yb.y) + Dv * u;
            yp[(size_t)lp * 192] = __float2bfloat16(yv);
        }
    } else {
        float h[16];
#pragma unroll
        for (int n = 0; n < 16; n++) h[n] = __bfloat162float(Hbuf[base + n]);
        for (int t = 0; t < CLEN; t++) {
            float s = bde;
#pragma unroll
            for (int rr = 0; rr < 6; rr++) s += Dt[t][rr] * wd[rr];
            float dt = (s > 20.f) ? s : __logf(1.f + __expf(s));
            int lp = (dir < 2) ? (l0 + t) : (LL - 1 - (l0 + t));
            float u = xtp[(size_t)lp * 192];
            float du = dt * u;
            float yv = Dv * u;
#pragma unroll
            for (int n = 0; n < 16; n++) {
                float e = __expf(dt * (-__expf(Alog[d4 * 16 + n])));
                h[n] = e * h[n] + du * Bt[t][n];
                yv += h[n] * Ct[t][n];
            }
            yp[(size_t)lp * 192] = __float2bfloat16(yv);
        }
    }
}

// K5: yh = sum of 4 bf16 slabs; LayerNorm(192); * silu(z); @ W_out -> out (b,96,H,W)
__global__ __launch_bounds__(256) void k5_out(
    const __hip_bfloat16* __restrict__ y4, const float* __restrict__ zs,
    const float* __restrict__ lng, const float* __restrict__ lnb,
    const float* __restrict__ Wout, float* __restrict__ out)
{
    __shared__ float acts[16][196];
    __shared__ float wsh[32][100];
    int tid = threadIdx.x;
    int wv = tid >> 6;
    int lane = tid & 63;
    int gl0 = blockIdx.x * 16;
    int b = gl0 / LL;
    int l0 = gl0 % LL;
    const size_t ds = (size_t)LL * 192;

    for (int i = 0; i < 4; i++) {
        int rrow = wv * 4 + i;
        int l = l0 + rrow;
        float yv[3], zv[3];
        float s1 = 0.f, s2 = 0.f;
#pragma unroll
        for (int kk = 0; kk < 3; kk++) {
            int c = lane + kk * 64;
            size_t off = ((size_t)(b * 4) * LL + l) * 192 + c;
            float y = __bfloat162float(y4[off]) + __bfloat162float(y4[off + ds])
                    + __bfloat162float(y4[off + 2 * ds]) + __bfloat162float(y4[off + 3 * ds]);
            yv[kk] = y;
            zv[kk] = zs[((size_t)b * LL + l) * 192 + c];
            s1 += y; s2 += y * y;
        }
#pragma unroll
        for (int o = 32; o; o >>= 1) {
            s1 += __shfl_xor(s1, o, 64);
            s2 += __shfl_xor(s2, o, 64);
        }
        float mean = s1 * (1.f / 192.f);
        float var = s2 * (1.f / 192.f) - mean * mean;
        float rs = rsqrtf(var + 1e-5f);
#pragma unroll
        for (int kk = 0; kk < 3; kk++) {
            int c = lane + kk * 64;
            float yn = (yv[kk] - mean) * rs * lng[c] + lnb[c];
            acts[rrow][c] = yn * zv[kk];
        }
    }

    int ty = tid & 15;   // row
    int tx = tid >> 4;   // cols tx*6..+5
    v2f o2[3];
    o2[0].x = 0.f; o2[0].y = 0.f;
    o2[1].x = 0.f; o2[1].y = 0.f;
    o2[2].x = 0.f; o2[2].y = 0.f;

    for (int kc = 0; kc < 192; kc += 32) {
        __syncthreads();
        for (int i = tid; i < 32 * 24; i += 256) {
            int d = i / 24, q = i - d * 24;
            *(float4*)&wsh[d][q * 4] = *(const float4*)&Wout[(kc + d) * 96 + q * 4];
        }
        __syncthreads();
#pragma unroll
        for (int kk = 0; kk < 32; kk++) {
            float av = acts[ty][kc + kk];
            const v2f* wp = (const v2f*)&wsh[kk][tx * 6];
            v2f w0 = wp[0], w1 = wp[1], w2 = wp[2];
            v2f sp; sp.x = av; sp.y = av;
            o2[0] += sp * w0;
            o2[1] += sp * w1;
            o2[2] += sp * w2;
        }
    }
    int l = l0 + ty;
#pragma unroll
    for (int j = 0; j < 6; j++) {
        int n = tx * 6 + j;
        out[((size_t)(b * 96) + n) * LL + l] = o2[j >> 1][j & 1];
    }
}

extern "C" void kernel_launch(void* const* d_in, const int* in_sizes, int n_in,
                              void* d_out, int out_size, void* d_ws, size_t ws_size,
                              hipStream_t stream)
{
    const float* x    = (const float*)d_in[0];
    const float* Win  = (const float*)d_in[1];
    const float* bin  = (const float*)d_in[2];
    const float* wdw  = (const float*)d_in[3];
    const float* bdw  = (const float*)d_in[4];
    const float* Alog = (const float*)d_in[5];
    const float* Dp   = (const float*)d_in[6];
    const float* Wx   = (const float*)d_in[7];
    const float* Wd   = (const float*)d_in[8];
    const float* bdl  = (const float*)d_in[9];
    const float* lng  = (const float*)d_in[10];
    const float* lnb  = (const float*)d_in[11];
    const float* Wout = (const float*)d_in[12];
    float* out = (float*)d_out;

    float* ws    = (float*)d_ws;
    __hip_bfloat16* y4 = (__hip_bfloat16*)(ws + F_Y4);
    float* xx    = ws + F_XX;    // aliases y4 slab region (dead before y4 written)
    float* zs    = ws + F_ZS;
    float* xt    = ws + F_XT;
    float* xd0   = ws + F_XD0;
    float* xd1   = ws + F_XD1;
    float* xd2   = ws + F_XD2;
    float* xd3   = ws + F_XD3;
    float* Sbuf  = ws + F_SBUF;
    __hip_bfloat16* Hbuf = (__hip_bfloat16*)(ws + F_HBUF);
    float* wcomb = ws + F_WCOMB;
    float* A0f   = ws + F_A0;
    float* Ffl   = ws + F_FF;

    k0_foldw<<<60, 256, 0, stream>>>(Wx, Alog, wcomb, A0f, Ffl);
    k1_inproj<<<1152, 256, 0, stream>>>(x, Win, bin, xx, zs);
    k2_conv<<<1152, 192, 0, stream>>>(xx, wdw, bdw, xt);
    k3_xdbl<<<576, 320, 0, stream>>>(xt, wcomb, xd0, xd1, xd2, xd3);
    k4_pass1<<<2304, 192, 0, stream>>>(xt, xd0, xd1, xd2, xd3, Wd, bdl, Alog, A0f, Ffl, Sbuf, Hbuf);
    k4_pass2<<<96, 256, 0, stream>>>(Sbuf, Alog, Hbuf);
    k4_pass3<<<2304, 192, 0, stream>>>(xt, xd0, xd1, xd2, xd3, Wd, bdl, Alog, A0f, Ffl, Dp, Hbuf, y4);
    k5_out<<<1152, 256, 0, stream>>>(y4, zs, lng, lnb, Wout, out);
}

// Round 11
// 287.527 us; speedup vs baseline: 1.2627x; 1.0202x over previous
//
#include <hip/hip_runtime.h>
#include <hip/hip_bf16.h>
#include <math.h>

#define CIN 96
#define D2 192
#define D4 768
#define LL 9216
#define NN 16
#define NCH 288      /* chunks per direction */
#define CLEN 32      /* steps per chunk */

typedef float v2f __attribute__((ext_vector_type(2)));

// ---- workspace layout (float-slot offsets) ----
#define SZ_Y4SLOT (2u*2u*9216u*192u)     //  7,077,888 float slots (bf16 x2)
#define SZ_BL    (2u*9216u*192u)         //  3,538,944
#define SZ_XDBL  (2u*9216u*38u)          //    700,416
#define SZ_S     (2u*4u*288u*192u)       //    442,368
#define SZ_HSLOT (2u*4u*288u*192u*8u)    //  3,538,944 float slots (bf16 x2)
#define F_Y4     0u
#define F_XX     0u                       /* alias: xx dead before y4 written */
#define F_ZS     (F_Y4 + SZ_Y4SLOT)
#define F_XT     (F_ZS + SZ_BL)
#define F_XD0    (F_XT + SZ_BL)
#define F_XD1    (F_XD0 + SZ_XDBL)
#define F_XD2    (F_XD1 + SZ_XDBL)
#define F_XD3    (F_XD2 + SZ_XDBL)
#define F_SBUF   (F_XD3 + SZ_XDBL)
#define F_HBUF   (F_SBUF + SZ_S)
#define F_WCOMB  (F_HBUF + SZ_HSLOT)     /* 192*80 floats */
#define F_A0     (F_WCOMB + 15360u)      /* 768 floats */
#define F_FF     (F_A0 + 768u)           /* 768 floats */

__device__ __forceinline__ float silu_f(float z) {
    return z / (1.0f + __expf(-z));
}

// K0: fold Wx into combined padded weight; precompute a0 and fast-flag per d4
__global__ __launch_bounds__(256) void k0_foldw(
    const float* __restrict__ Wx, const float* __restrict__ Alog,
    float* __restrict__ wcomb, float* __restrict__ A0f, float* __restrict__ Ffl)
{
    int i = blockIdx.x * 256 + threadIdx.x;
    if (i < 768) {
        float a0 = -__expf(Alog[i * 16]);
        bool fast = true;
        for (int n = 1; n < 16; n++) {
            float an = -__expf(Alog[i * 16 + n]);
            float tgt = (n + 1) * a0;
            fast = fast && (fabsf(an - tgt) <= 1e-5f * fabsf(tgt));
        }
        A0f[i] = a0;
        Ffl[i] = fast ? 1.f : 0.f;
    }
    if (i >= 192 * 80) return;
    int d = i / 80, j = i % 80;
    float v = 0.f;
    if (j < 38) v = Wx[d * 38 + j] + Wx[(d + 192) * 38 + j];
    else if (j >= 40 && j < 78) {
        int jj = j - 40;
        v = Wx[(d + 384) * 38 + jj] + Wx[(d + 576) * 38 + jj];
    }
    wcomb[i] = v;
}

// K1: xz = x @ W_in + b_in. Block = 64 l x 96 e-quarter; grid 1152.
__global__ __launch_bounds__(256) void k1_inproj(
    const float* __restrict__ x, const float* __restrict__ Win,
    const float* __restrict__ bin, float* __restrict__ xx, float* __restrict__ zs)
{
    __shared__ float xs[32][68];
    __shared__ float wsh[32][100];
    int tid = threadIdx.x;
    int bid = blockIdx.x;
    int eq = bid & 3;
    int lt = (bid >> 2) % 144;
    int b = bid / 576;
    int l0 = lt * 64;
    int e0 = eq * 96;

    int lg = tid & 15;
    int cg = tid >> 4;
    v2f acc[4][3];
#pragma unroll
    for (int i = 0; i < 4; i++)
#pragma unroll
        for (int p = 0; p < 3; p++) { acc[i][p].x = 0.f; acc[i][p].y = 0.f; }

    for (int kc = 0; kc < 96; kc += 32) {
        __syncthreads();
        for (int i = tid; i < 512; i += 256) {
            int kk = i >> 4, q = i & 15;
            float4 v = *(const float4*)&x[(size_t)(b * 96 + kc + kk) * LL + l0 + q * 4];
            *(float4*)&xs[kk][q * 4] = v;
        }
        for (int i = tid; i < 768; i += 256) {
            int kk = i / 24, q = i - kk * 24;
            float4 v = *(const float4*)&Win[(kc + kk) * 384 + e0 + q * 4];
            *(float4*)&wsh[kk][q * 4] = v;
        }
        __syncthreads();
#pragma unroll 4
        for (int k = 0; k < 32; k++) {
            float4 xv = *(const float4*)&xs[k][lg * 4];
            const v2f* wp = (const v2f*)&wsh[k][cg * 6];
            v2f w0 = wp[0], w1 = wp[1], w2 = wp[2];
            float xa[4] = {xv.x, xv.y, xv.z, xv.w};
#pragma unroll
            for (int i = 0; i < 4; i++) {
                v2f xi; xi.x = xa[i]; xi.y = xa[i];
                acc[i][0] += xi * w0;
                acc[i][1] += xi * w1;
                acc[i][2] += xi * w2;
            }
        }
    }
    if (eq < 2) {
#pragma unroll
        for (int j = 0; j < 6; j++) {
            int e = e0 + cg * 6 + j;
            float bb = bin[e];
            float4 v = {acc[0][j >> 1][j & 1] + bb, acc[1][j >> 1][j & 1] + bb,
                        acc[2][j >> 1][j & 1] + bb, acc[3][j >> 1][j & 1] + bb};
            *(float4*)&xx[(size_t)(b * 192 + e) * LL + l0 + lg * 4] = v;
        }
    } else {
        int zc0 = e0 - 192 + cg * 6;
        float bb[6];
#pragma unroll
        for (int j = 0; j < 6; j++) bb[j] = bin[e0 + cg * 6 + j];
#pragma unroll
        for (int i = 0; i < 4; i++) {
            int l = l0 + lg * 4 + i;
            float* zp = &zs[((size_t)b * LL + l) * 192 + zc0];
#pragma unroll
            for (int p = 0; p < 3; p++) {
                float2 v;
                v.x = silu_f(acc[i][p].x + bb[2 * p]);
                v.y = silu_f(acc[i][p].y + bb[2 * p + 1]);
                *(float2*)&zp[2 * p] = v;
            }
        }
    }
}

// K2: depthwise 3x3 conv + bias + silu, fused transpose: xx (b,192,96,96) -> xt (b,L,192)
__global__ __launch_bounds__(192) void k2_conv(
    const float* __restrict__ xx, const float* __restrict__ wdw,
    const float* __restrict__ bdw, float* __restrict__ xt)
{
    __shared__ float tile[32][97];
    __shared__ float wsm[32][9];
    __shared__ float bs[32];
    int tid = threadIdx.x;
    int bid = blockIdx.x;
    int h = bid % 96;
    int r = bid / 96;
    int dg = r % 6;
    int b = r / 6;

    for (int i = tid; i < 288; i += 192) wsm[i / 9][i % 9] = wdw[(dg * 32 + i / 9) * 9 + (i % 9)];
    if (tid < 32) bs[tid] = bdw[dg * 32 + tid];
    __syncthreads();

    int w = tid % 96;
    int dhalf = tid / 96;
    for (int p = 0; p < 16; p++) {
        int dsub = 2 * p + dhalf;
        const float* base = xx + (size_t)(b * 192 + dg * 32 + dsub) * LL;
        float acc = bs[dsub];
#pragma unroll
        for (int kh = 0; kh < 3; kh++) {
            int hh = h + kh - 1;
            if (hh < 0 || hh >= 96) continue;
            const float* row = base + hh * 96;
#pragma unroll
            for (int kw = 0; kw < 3; kw++) {
                int ww = w + kw - 1;
                if (ww < 0 || ww >= 96) continue;
                acc += row[ww] * wsm[dsub][kh * 3 + kw];
            }
        }
        tile[dsub][w] = silu_f(acc);
    }
    __syncthreads();
    for (int i = tid; i < 768; i += 192) {
        int q = i & 7, ls = i >> 3;
        float4 v = {tile[q * 4 + 0][ls], tile[q * 4 + 1][ls], tile[q * 4 + 2][ls], tile[q * 4 + 3][ls]};
        *(float4*)&xt[((size_t)b * LL + h * 96 + ls) * 192 + dg * 32 + q * 4] = v;
    }
}

// K3: GEMM  out[64 rows x 80 cols] = X[64x96(khalf)] @ Wcomb[96x80], K-split over 2 blocks.
__global__ __launch_bounds__(320) void k3_xdbl(
    const float* __restrict__ xt, const float* __restrict__ wcomb,
    float* __restrict__ xa0, float* __restrict__ xa1,
    float* __restrict__ xb0, float* __restrict__ xb1)
{
    __shared__ float xs[16][68];
    __shared__ float wsh[16][80];
    int tid = threadIdx.x;
    int bid = blockIdx.x;
    int kh = bid & 1;
    int rt = (bid >> 1) % 144;
    int b = bid / 288;
    int r0 = rt * 64;
    int k0 = kh * 96;
    float* __restrict__ xa = kh ? xa1 : xa0;
    float* __restrict__ xb = kh ? xb1 : xb0;

    int rg = tid / 20;
    int cg = tid % 20;
    v2f acc[4][2];
#pragma unroll
    for (int i = 0; i < 4; i++)
#pragma unroll
        for (int p = 0; p < 2; p++) { acc[i][p].x = 0.f; acc[i][p].y = 0.f; }

    for (int kc = 0; kc < 96; kc += 16) {
        __syncthreads();
        if (tid < 256) {
            int row = tid >> 2, dq = tid & 3;
            float4 v = *(const float4*)&xt[((size_t)b * LL + r0 + row) * 192 + k0 + kc + dq * 4];
            xs[dq * 4 + 0][row] = v.x;
            xs[dq * 4 + 1][row] = v.y;
            xs[dq * 4 + 2][row] = v.z;
            xs[dq * 4 + 3][row] = v.w;
        }
        for (int i = tid; i < 16 * 80; i += 320) {
            int d = i / 80, j = i - d * 80;
            wsh[d][j] = wcomb[(k0 + kc + d) * 80 + j];
        }
        __syncthreads();
#pragma unroll
        for (int d = 0; d < 16; d++) {
            float4 xv = *(const float4*)&xs[d][rg * 4];
            float4 wv = *(const float4*)&wsh[d][cg * 4];
            v2f w01; w01.x = wv.x; w01.y = wv.y;
            v2f w23; w23.x = wv.z; w23.y = wv.w;
            float xr[4] = {xv.x, xv.y, xv.z, xv.w};
#pragma unroll
            for (int i = 0; i < 4; i++) {
                v2f xi; xi.x = xr[i]; xi.y = xr[i];
                acc[i][0] += xi * w01;
                acc[i][1] += xi * w23;
            }
        }
    }
    int c0 = cg * 4;
#pragma unroll
    for (int i = 0; i < 4; i++) {
        int la = r0 + rg * 4 + i;
#pragma unroll
        for (int j = 0; j < 4; j++) {
            int col = c0 + j;
            float v = acc[i][j >> 1][j & 1];
            if (col < 38) {
                xa[((size_t)b * LL + la) * 38 + col] = v;
            } else if (col >= 40 && col < 78) {
                int lb = LL - 1 - la;
                xb[((size_t)b * LL + lb) * 38 + (col - 40)] = v;
            }
        }
    }
}

// K4 pass1: per-chunk local scan, SINGLE direction per block, h from 0.
__global__ __launch_bounds__(192, 4) void k4_pass1(
    const float* __restrict__ xt,
    const float* __restrict__ xa0, const float* __restrict__ xa1,
    const float* __restrict__ xb0, const float* __restrict__ xb1,
    const float* __restrict__ Wd, const float* __restrict__ bdl,
    const float* __restrict__ Alog, const float* __restrict__ A0f,
    const float* __restrict__ Ffl,
    float* __restrict__ Sbuf, __hip_bfloat16* __restrict__ Hbuf)
{
    __shared__ float Bt[CLEN][16];
    __shared__ float Dt[CLEN][6];
    int tid = threadIdx.x;
    int bid = blockIdx.x;
    int k = bid % NCH;
    int r = bid / NCH;
    int dir = r & 3;
    int b = r >> 2;
    int l0 = k * CLEN;
    for (int i = tid; i < CLEN * 16; i += 192) {
        int t = i >> 4, n = i & 15;
        size_t rb = ((size_t)b * LL + l0 + t) * 38 + 6 + n;
        Bt[t][n] = (xa0[rb] + xa1[rb]) + (xb0[rb] + xb1[rb]);
    }
    for (int i = tid; i < CLEN * 6; i += 192) {
        int t = i / 6, rr = i - 6 * t;
        size_t rb = ((size_t)b * LL + l0 + t) * 38 + rr;
        Dt[t][rr] = (xa0[rb] + xa1[rb]) + (xb0[rb] + xb1[rb]);
    }
    __syncthreads();
    int c = tid;
    int d4 = dir * 192 + c;
    float a0 = A0f[d4];
    bool fast = (Ffl[d4] != 0.f);
    float wd[6];
#pragma unroll
    for (int rr = 0; rr < 6; rr++) wd[rr] = Wd[rr * 768 + d4];
    float bde = bdl[d4];
    float S = 0.f;
    int start = (dir < 2) ? l0 : (LL - 1 - l0);
    ptrdiff_t stp = (dir < 2) ? 192 : -192;
    const float* up = xt + (size_t)b * LL * 192 + (size_t)start * 192 + c;
    int bd = b * 4 + dir;
    size_t base = (((size_t)bd * NCH + k) * 192 + c) * 16;
    if (fast) {
        v2f h2[8];
#pragma unroll
        for (int n = 0; n < 8; n++) { h2[n].x = 0.f; h2[n].y = 0.f; }
#pragma unroll 2
        for (int t = 0; t < CLEN; t++) {
            float2 d01 = *(const float2*)&Dt[t][0];
            float2 d23 = *(const float2*)&Dt[t][2];
            float2 d45 = *(const float2*)&Dt[t][4];
            float s = bde + d01.x * wd[0] + d01.y * wd[1] + d23.x * wd[2]
                          + d23.y * wd[3] + d45.x * wd[4] + d45.y * wd[5];
            float dt = (s > 20.f) ? s : __logf(1.f + __expf(s));
            S += dt;
            float u = *up; up += stp;
            float du = dt * u;
            float e1 = __expf(dt * a0);
            float e2 = e1 * e1;
            v2f q; q.x = e1; q.y = e2;
            v2f e2v; e2v.x = e2; e2v.y = e2;
            v2f e4v = e2v * e2v;
            v2f q2 = q * e2v;
            v2f du2; du2.x = du; du2.y = du;
#pragma unroll
            for (int g = 0; g < 4; g++) {
                float4 bq = *(const float4*)&Bt[t][4 * g];
                v2f b0; b0.x = bq.x; b0.y = bq.y;
                v2f b1; b1.x = bq.z; b1.y = bq.w;
                h2[2 * g]     = q  * h2[2 * g]     + du2 * b0;
                h2[2 * g + 1] = q2 * h2[2 * g + 1] + du2 * b1;
                if (g < 3) { q *= e4v; q2 *= e4v; }
            }
        }
        __hip_bfloat16* hb = Hbuf + base;
#pragma unroll
        for (int n = 0; n < 8; n++) {
            hb[2 * n]     = __float2bfloat16(h2[n].x);
            hb[2 * n + 1] = __float2bfloat16(h2[n].y);
        }
    } else {
        float h[16];
#pragma unroll
        for (int n = 0; n < 16; n++) h[n] = 0.f;
        for (int t = 0; t < CLEN; t++) {
            float s = bde;
#pragma unroll
            for (int rr = 0; rr < 6; rr++) s += Dt[t][rr] * wd[rr];
            float dt = (s > 20.f) ? s : __logf(1.f + __expf(s));
            S += dt;
            float u = *up; up += stp;
            float du = dt * u;
#pragma unroll
            for (int n = 0; n < 16; n++) {
                float e = __expf(dt * (-__expf(Alog[d4 * 16 + n])));
                h[n] = e * h[n] + du * Bt[t][n];
            }
        }
#pragma unroll
        for (int n = 0; n < 16; n++) Hbuf[base + n] = __float2bfloat16(h[n]);
    }
    Sbuf[((size_t)bd * NCH + k) * 192 + c] = S;
}

// K4 pass2: scan over chunk summaries; Hbuf[k] := h_start (bf16); P = exp(a*S) on the fly
__global__ __launch_bounds__(256) void k4_pass2(
    const float* __restrict__ Sbuf, const float* __restrict__ Alog,
    __hip_bfloat16* __restrict__ Hbuf)
{
    int lane = blockIdx.x * 256 + threadIdx.x;  // 24576
    int bd = lane / 3072;
    int cn = lane % 3072;
    int c = cn >> 4, n = cn & 15;
    int dir = bd & 3;
    float an = -__expf(Alog[(dir * 192 + c) * 16 + n]);
    float h = 0.f;
#pragma unroll 8
    for (int k = 0; k < NCH; k++) {
        size_t sidx = ((size_t)bd * NCH + k) * 192 + c;
        float S = Sbuf[sidx];
        size_t idx = sidx * 16 + n;
        float hl = __bfloat162float(Hbuf[idx]);
        float P = __expf(an * S);
        Hbuf[idx] = __float2bfloat16(h);
        h = P * h + hl;
    }
}

// K4 pass3: replay chunk from h_start; y -> bf16 slab. Running-multiplier fast path.
__global__ __launch_bounds__(192, 4) void k4_pass3(
    const float* __restrict__ xt,
    const float* __restrict__ xa0, const float* __restrict__ xa1,
    const float* __restrict__ xb0, const float* __restrict__ xb1,
    const float* __restrict__ Wd, const float* __restrict__ bdl,
    const float* __restrict__ Alog, const float* __restrict__ A0f,
    const float* __restrict__ Ffl, const float* __restrict__ Dp,
    const __hip_bfloat16* __restrict__ Hbuf, __hip_bfloat16* __restrict__ y4)
{
    __shared__ float Bt[CLEN][16];
    __shared__ float Ct[CLEN][16];
    __shared__ float Dt[CLEN][6];
    int tid = threadIdx.x;
    int bid = blockIdx.x;
    int k = bid % NCH;
    int r = bid / NCH;
    int dir = r & 3;
    int b = r >> 2;
    int l0 = k * CLEN;
    for (int i = tid; i < CLEN * 16; i += 192) {
        int t = i >> 4, n = i & 15;
        size_t rb = ((size_t)b * LL + l0 + t) * 38;
        size_t r1 = rb + 6 + n, r2 = rb + 22 + n;
        Bt[t][n] = (xa0[r1] + xa1[r1]) + (xb0[r1] + xb1[r1]);
        Ct[t][n] = (xa0[r2] + xa1[r2]) + (xb0[r2] + xb1[r2]);
    }
    for (int i = tid; i < CLEN * 6; i += 192) {
        int t = i / 6, rr = i - 6 * t;
        size_t rb = ((size_t)b * LL + l0 + t) * 38 + rr;
        Dt[t][rr] = (xa0[rb] + xa1[rb]) + (xb0[rb] + xb1[rb]);
    }
    __syncthreads();
    int c = tid;
    int d4 = dir * 192 + c;
    float a0 = A0f[d4];
    bool fast = (Ffl[d4] != 0.f);
    float wd[6];
#pragma unroll
    for (int rr = 0; rr < 6; rr++) wd[rr] = Wd[rr * 768 + d4];
    float bde = bdl[d4];
    float Dv = Dp[d4];
    int bd = b * 4 + dir;
    size_t base = (((size_t)bd * NCH + k) * 192 + c) * 16;
    int start = (dir < 2) ? l0 : (LL - 1 - l0);
    ptrdiff_t stp = (dir < 2) ? 192 : -192;
    const float* up = xt + (size_t)b * LL * 192 + (size_t)start * 192 + c;
    __hip_bfloat16* yp = y4 + (size_t)bd * LL * 192 + (size_t)start * 192 + c;
    ptrdiff_t ystp = stp;
    if (fast) {
        v2f h2[8];
        const __hip_bfloat16* hb = Hbuf + base;
#pragma unroll
        for (int n = 0; n < 8; n++) {
            h2[n].x = __bfloat162float(hb[2 * n]);
            h2[n].y = __bfloat162float(hb[2 * n + 1]);
        }
#pragma unroll 2
        for (int t = 0; t < CLEN; t++) {
            float2 d01 = *(const float2*)&Dt[t][0];
            float2 d23 = *(const float2*)&Dt[t][2];
            float2 d45 = *(const float2*)&Dt[t][4];
            float s = bde + d01.x * wd[0] + d01.y * wd[1] + d23.x * wd[2]
                          + d23.y * wd[3] + d45.x * wd[4] + d45.y * wd[5];
            float dt = (s > 20.f) ? s : __logf(1.f + __expf(s));
            float u = *up; up += stp;
            float du = dt * u;
            float e1 = __expf(dt * a0);
            float e2 = e1 * e1;
            v2f q; q.x = e1; q.y = e2;
            v2f e2v; e2v.x = e2; e2v.y = e2;
            v2f e4v = e2v * e2v;
            v2f q2 = q * e2v;
            v2f du2; du2.x = du; du2.y = du;
            v2f ya; ya.x = 0.f; ya.y = 0.f;
            v2f yb; yb.x = 0.f; yb.y = 0.f;
#pragma unroll
            for (int g = 0; g < 4; g++) {
                float4 bq = *(const float4*)&Bt[t][4 * g];
                float4 cq = *(const float4*)&Ct[t][4 * g];
                v2f b0; b0.x = bq.x; b0.y = bq.y;
                v2f b1; b1.x = bq.z; b1.y = bq.w;
                v2f c0v; c0v.x = cq.x; c0v.y = cq.y;
                v2f c1v; c1v.x = cq.z; c1v.y = cq.w;
                h2[2 * g]     = q  * h2[2 * g]     + du2 * b0;
                ya += h2[2 * g] * c0v;
                h2[2 * g + 1] = q2 * h2[2 * g + 1] + du2 * b1;
                yb += h2[2 * g + 1] * c1v;
                if (g < 3) { q *= e4v; q2 *= e4v; }
            }
            float yv = (ya.x + ya.y) + (yb.x + yb.y) + Dv * u;
            *yp = __float2bfloat16(yv); yp += ystp;
        }
    } else {
        float h[16];
#pragma unroll
        for (int n = 0; n < 16; n++) h[n] = __bfloat162float(Hbuf[base + n]);
        for (int t = 0; t < CLEN; t++) {
            float s = bde;
#pragma unroll
            for (int rr = 0; rr < 6; rr++) s += Dt[t][rr] * wd[rr];
            float dt = (s > 20.f) ? s : __logf(1.f + __expf(s));
            float u = *up; up += stp;
            float du = dt * u;
            float yv = Dv * u;
#pragma unroll
            for (int n = 0; n < 16; n++) {
                float e = __expf(dt * (-__expf(Alog[d4 * 16 + n])));
                h[n] = e * h[n] + du * Bt[t][n];
                yv += h[n] * Ct[t][n];
            }
            *yp = __float2bfloat16(yv); yp += ystp;
        }
    }
}

// K5: yh = sum of 4 bf16 slabs; LayerNorm(192); * silu(z); @ W_out -> out (b,96,H,W)
__global__ __launch_bounds__(256) void k5_out(
    const __hip_bfloat16* __restrict__ y4, const float* __restrict__ zs,
    const float* __restrict__ lng, const float* __restrict__ lnb,
    const float* __restrict__ Wout, float* __restrict__ out)
{
    __shared__ float acts[16][196];
    __shared__ float wsh[32][100];
    int tid = threadIdx.x;
    int wv = tid >> 6;
    int lane = tid & 63;
    int gl0 = blockIdx.x * 16;
    int b = gl0 / LL;
    int l0 = gl0 % LL;
    const size_t ds = (size_t)LL * 192;

    for (int i = 0; i < 4; i++) {
        int rrow = wv * 4 + i;
        int l = l0 + rrow;
        float yv[3], zv[3];
        float s1 = 0.f, s2 = 0.f;
#pragma unroll
        for (int kk = 0; kk < 3; kk++) {
            int c = lane + kk * 64;
            size_t off = ((size_t)(b * 4) * LL + l) * 192 + c;
            float y = __bfloat162float(y4[off]) + __bfloat162float(y4[off + ds])
                    + __bfloat162float(y4[off + 2 * ds]) + __bfloat162float(y4[off + 3 * ds]);
            yv[kk] = y;
            zv[kk] = zs[((size_t)b * LL + l) * 192 + c];
            s1 += y; s2 += y * y;
        }
#pragma unroll
        for (int o = 32; o; o >>= 1) {
            s1 += __shfl_xor(s1, o, 64);
            s2 += __shfl_xor(s2, o, 64);
        }
        float mean = s1 * (1.f / 192.f);
        float var = s2 * (1.f / 192.f) - mean * mean;
        float rs = rsqrtf(var + 1e-5f);
#pragma unroll
        for (int kk = 0; kk < 3; kk++) {
            int c = lane + kk * 64;
            float yn = (yv[kk] - mean) * rs * lng[c] + lnb[c];
            acts[rrow][c] = yn * zv[kk];
        }
    }

    int ty = tid & 15;
    int tx = tid >> 4;
    v2f o2[3];
    o2[0].x = 0.f; o2[0].y = 0.f;
    o2[1].x = 0.f; o2[1].y = 0.f;
    o2[2].x = 0.f; o2[2].y = 0.f;

    for (int kc = 0; kc < 192; kc += 32) {
        __syncthreads();
        for (int i = tid; i < 32 * 24; i += 256) {
            int d = i / 24, q = i - d * 24;
            *(float4*)&wsh[d][q * 4] = *(const float4*)&Wout[(kc + d) * 96 + q * 4];
        }
        __syncthreads();
#pragma unroll
        for (int kk = 0; kk < 32; kk++) {
            float av = acts[ty][kc + kk];
            const v2f* wp = (const v2f*)&wsh[kk][tx * 6];
            v2f w0 = wp[0], w1 = wp[1], w2 = wp[2];
            v2f sp; sp.x = av; sp.y = av;
            o2[0] += sp * w0;
            o2[1] += sp * w1;
            o2[2] += sp * w2;
        }
    }
    int l = l0 + ty;
#pragma unroll
    for (int j = 0; j < 6; j++) {
        int n = tx * 6 + j;
        out[((size_t)(b * 96) + n) * LL + l] = o2[j >> 1][j & 1];
    }
}

extern "C" void kernel_launch(void* const* d_in, const int* in_sizes, int n_in,
                              void* d_out, int out_size, void* d_ws, size_t ws_size,
                              hipStream_t stream)
{
    const float* x    = (const float*)d_in[0];
    const float* Win  = (const float*)d_in[1];
    const float* bin  = (const float*)d_in[2];
    const float* wdw  = (const float*)d_in[3];
    const float* bdw  = (const float*)d_in[4];
    const float* Alog = (const float*)d_in[5];
    const float* Dp   = (const float*)d_in[6];
    const float* Wx   = (const float*)d_in[7];
    const float* Wd   = (const float*)d_in[8];
    const float* bdl  = (const float*)d_in[9];
    const float* lng  = (const float*)d_in[10];
    const float* lnb  = (const float*)d_in[11];
    const float* Wout = (const float*)d_in[12];
    float* out = (float*)d_out;

    float* ws    = (float*)d_ws;
    __hip_bfloat16* y4 = (__hip_bfloat16*)(ws + F_Y4);
    float* xx    = ws + F_XX;    // aliases y4 slab region (dead before y4 written)
    float* zs    = ws + F_ZS;
    float* xt    = ws + F_XT;
    float* xd0   = ws + F_XD0;
    float* xd1   = ws + F_XD1;
    float* xd2   = ws + F_XD2;
    float* xd3   = ws + F_XD3;
    float* Sbuf  = ws + F_SBUF;
    __hip_bfloat16* Hbuf = (__hip_bfloat16*)(ws + F_HBUF);
    float* wcomb = ws + F_WCOMB;
    float* A0f   = ws + F_A0;
    float* Ffl   = ws + F_FF;

    k0_foldw<<<60, 256, 0, stream>>>(Wx, Alog, wcomb, A0f, Ffl);
    k1_inproj<<<1152, 256, 0, stream>>>(x, Win, bin, xx, zs);
    k2_conv<<<1152, 192, 0, stream>>>(xx, wdw, bdw, xt);
    k3_xdbl<<<576, 320, 0, stream>>>(xt, wcomb, xd0, xd1, xd2, xd3);
    k4_pass1<<<2304, 192, 0, stream>>>(xt, xd0, xd1, xd2, xd3, Wd, bdl, Alog, A0f, Ffl, Sbuf, Hbuf);
    k4_pass2<<<96, 256, 0, stream>>>(Sbuf, Alog, Hbuf);
    k4_pass3<<<2304, 192, 0, stream>>>(xt, xd0, xd1, xd2, xd3, Wd, bdl, Alog, A0f, Ffl, Dp, Hbuf, y4);
    k5_out<<<1152, 256, 0, stream>>>(y4, zs, lng, lnb, Wout, out);
}